// Round 3
// baseline (407.776 us; speedup 1.0000x reference)
//
#include <hip/hip_runtime.h>

#define B_   4
#define T_   2048
#define C_   1024
#define H_   16
#define HS_  64
#define BT_  (B_*T_)
#define EPS_ 1e-5f

typedef unsigned short u16;
typedef unsigned int   u32;
typedef __attribute__((ext_vector_type(8))) __bf16 bf16x8;
typedef __attribute__((ext_vector_type(4))) float  f32x4;
typedef __attribute__((ext_vector_type(8))) u16    u16x8;
typedef __attribute__((ext_vector_type(4))) u16    u16x4;
typedef __attribute__((ext_vector_type(4))) u32    u32x4;

__device__ __forceinline__ u16 f2bf(float f) {
  unsigned x = __builtin_bit_cast(unsigned, f);
  x += 0x7fffu + ((x >> 16) & 1u);
  return (u16)(x >> 16);
}
__device__ __forceinline__ float bf2f(u16 v) {
  return __builtin_bit_cast(float, (u32)v << 16);
}

__device__ __forceinline__ float fast_exp2(float x) {
  float y;
  asm("v_exp_f32 %0, %1" : "=v"(y) : "v"(x));
  return y;
}
__device__ __forceinline__ float fast_rcp(float x) {
  float y;
  asm("v_rcp_f32 %0, %1" : "=v"(y) : "v"(x));
  return y;
}

#define GLD_LDS16(src, dst) \
  __builtin_amdgcn_global_load_lds((__attribute__((address_space(1))) void*)(src), \
                                   (__attribute__((address_space(3))) void*)(dst), 16, 0, 0)

// ---------------- LayerNorm over time axis (axis=1, ddof=1) ----------------
__global__ __launch_bounds__(256) void ln_partial(const float* __restrict__ x,
                                                  float* __restrict__ ps,
                                                  float* __restrict__ psq) {
  int col = blockIdx.x * 256 + threadIdx.x;      // 0..B*C-1
  int b = col >> 10, c = col & (C_ - 1);
  int t0 = blockIdx.y * (T_ / 16);
  const float* p = x + (size_t)b * T_ * C_ + (size_t)t0 * C_ + c;
  float s = 0.f, sq = 0.f;
  #pragma unroll 4
  for (int i = 0; i < T_ / 16; ++i) { float v = p[(size_t)i * C_]; s += v; sq += v * v; }
  ps [blockIdx.y * (B_ * C_) + col] = s;
  psq[blockIdx.y * (B_ * C_) + col] = sq;
}

// bf16-input variant (x1 residual stream)
__global__ __launch_bounds__(256) void ln_partial_bf(const u16* __restrict__ x,
                                                     float* __restrict__ ps,
                                                     float* __restrict__ psq) {
  int col = blockIdx.x * 256 + threadIdx.x;
  int b = col >> 10, c = col & (C_ - 1);
  int t0 = blockIdx.y * (T_ / 16);
  const u16* p = x + (size_t)b * T_ * C_ + (size_t)t0 * C_ + c;
  float s = 0.f, sq = 0.f;
  #pragma unroll 4
  for (int i = 0; i < T_ / 16; ++i) { float v = bf2f(p[(size_t)i * C_]); s += v; sq += v * v; }
  ps [blockIdx.y * (B_ * C_) + col] = s;
  psq[blockIdx.y * (B_ * C_) + col] = sq;
}

__global__ __launch_bounds__(256) void ln_final(const float* __restrict__ ps,
                                                const float* __restrict__ psq,
                                                float* __restrict__ mean,
                                                float* __restrict__ rstd) {
  int col = blockIdx.x * 256 + threadIdx.x;
  float s = 0.f, sq = 0.f;
  #pragma unroll
  for (int i = 0; i < 16; ++i) { s += ps[i * (B_ * C_) + col]; sq += psq[i * (B_ * C_) + col]; }
  float m = s * (1.f / T_);
  float var = (sq - (float)T_ * m * m) * (1.f / (T_ - 1));   // ddof=1
  mean[col] = m;
  rstd[col] = rsqrtf(var + EPS_);
}

__global__ __launch_bounds__(256) void ln_norm(const float* __restrict__ x,
                                               const float* __restrict__ mean,
                                               const float* __restrict__ rstd,
                                               const float* __restrict__ gam,
                                               const float* __restrict__ bet,
                                               u16* __restrict__ out) {
  size_t i = ((size_t)blockIdx.x * 256 + threadIdx.x) * 4;
  int c  = (int)(i & (C_ - 1));
  int b  = (int)(i >> 21);
  int bc = (b << 10) + c;
  float4 v = *(const float4*)(x + i);
  float vv[4] = {v.x, v.y, v.z, v.w};
  u16x4 o;
  #pragma unroll
  for (int j = 0; j < 4; ++j)
    o[j] = f2bf(gam[c + j] * (vv[j] - mean[bc + j]) * rstd[bc + j] + bet[c + j]);
  *(u16x4*)(out + i) = o;
}

// bf16-input variant
__global__ __launch_bounds__(256) void ln_norm_bf(const u16* __restrict__ x,
                                                  const float* __restrict__ mean,
                                                  const float* __restrict__ rstd,
                                                  const float* __restrict__ gam,
                                                  const float* __restrict__ bet,
                                                  u16* __restrict__ out) {
  size_t i = ((size_t)blockIdx.x * 256 + threadIdx.x) * 4;
  int c  = (int)(i & (C_ - 1));
  int b  = (int)(i >> 21);
  int bc = (b << 10) + c;
  u16x4 v = *(const u16x4*)(x + i);
  u16x4 o;
  #pragma unroll
  for (int j = 0; j < 4; ++j)
    o[j] = f2bf(gam[c + j] * (bf2f(v[j]) - mean[bc + j]) * rstd[bc + j] + bet[c + j]);
  *(u16x4*)(out + i) = o;
}

// ---------------- weight pack: transpose + cast f32 -> bf16 ----------------
__global__ __launch_bounds__(256) void transpose_cast(const float* __restrict__ in,
                                                      u16* __restrict__ out,
                                                      int cols_in, int ld_out,
                                                      size_t batch_in, size_t batch_out) {
  __shared__ float tile[32][33];
  const float* I = in + (size_t)blockIdx.z * batch_in;
  u16* Ou = out + (size_t)blockIdx.z * batch_out;
  int r0 = blockIdx.y << 5, c0 = blockIdx.x << 5;
  int tx = threadIdx.x & 31, ty = threadIdx.x >> 5;
  #pragma unroll
  for (int rr = 0; rr < 32; rr += 8)
    tile[ty + rr][tx] = I[(size_t)(r0 + ty + rr) * cols_in + c0 + tx];
  __syncthreads();
  #pragma unroll
  for (int rr = 0; rr < 32; rr += 8)
    Ou[(size_t)(c0 + ty + rr) * ld_out + r0 + tx] = f2bf(tile[tx][ty + rr]);
}

__global__ __launch_bounds__(256) void concat_bias(const float* __restrict__ bq,
                                                   const float* __restrict__ bk,
                                                   const float* __restrict__ bv,
                                                   float* __restrict__ out) {
  int i = blockIdx.x * 256 + threadIdx.x;
  float v = (i < 1024) ? bq[i] : (i < 2048 ? bk[i - 1024] : bv[i - 2048]);
  out[i] = v;
}

// ---------------- V transpose: qkv V block -> Vt[bh][hs][T] bf16 -----------
__global__ __launch_bounds__(256) void v_transpose(const u16* __restrict__ qkv,
                                                   u16* __restrict__ Vt) {
  __shared__ u16 tile[32][33];
  int bh = blockIdx.z; int b = bh >> 4, h = bh & 15;
  int t0 = blockIdx.x << 5, hs0 = blockIdx.y << 5;
  int tx = threadIdx.x & 31, ty = threadIdx.x >> 5;
  const u16* src = qkv + (size_t)(b * T_ + t0) * 3072 + 2048 + h * 64 + hs0;
  #pragma unroll
  for (int rr = 0; rr < 32; rr += 8)
    tile[ty + rr][tx] = src[(size_t)(ty + rr) * 3072 + tx];
  __syncthreads();
  u16* dst = Vt + ((size_t)bh * 64 + hs0) * T_ + t0;
  #pragma unroll
  for (int rr = 0; rr < 32; rr += 8)
    dst[(size_t)(ty + rr) * T_ + tx] = tile[tx][ty + rr];
}

// ---------------- 128x256 bf16 NT GEMM, 4 waves, per-wave 64x128 -----------
// r12-proven counted ring: depth 3, prefetch distance 2, boundary vmcnt(6).
// PROVEN 881 TF on FFN1 (r1) — restored as FFN1/QKV workhorse.
template<int RELU, int QSCALE>
__global__ __launch_bounds__(256, 2)
void gemm_128x256(const u16* __restrict__ A,
                  const u16* __restrict__ Bt,
                  const float* __restrict__ bias,
                  u16* __restrict__ outp,
                  int M, int N, int K) {
  constexpr int BK = 32;
  __shared__ u16 sA[3][128 * BK];   // 24 KB
  __shared__ u16 sB[3][256 * BK];   // 48 KB

  const int tid = threadIdx.x;
  const int wave = tid >> 6, lane = tid & 63;
  const int g = lane >> 4, r16 = lane & 15;

  const int nbx = N >> 8;
  const int nwg = gridDim.x;
  const int bid = blockIdx.x;
  const int swz = ((bid & 7) * (nwg >> 3)) + (bid >> 3);
  const int bx = swz % nbx, by = swz / nbx;
  const int row0 = by << 7, col0 = bx << 8;

  const u16* aS[2];
  const u16* bS[4];
  #pragma unroll
  for (int j = 0; j < 2; ++j) {
    const int ci = tid + 256 * j, row = ci >> 2, cc = ci & 3;
    aS[j] = A + (size_t)(row0 + row) * K + ((cc ^ ((row >> 1) & 3)) * 8);
  }
  #pragma unroll
  for (int j = 0; j < 4; ++j) {
    const int ci = tid + 256 * j, row = ci >> 2, cc = ci & 3;
    bS[j] = Bt + (size_t)(col0 + row) * K + ((cc ^ ((row >> 1) & 3)) * 8);
  }
  const int ldsOff = wave * 512;   // u16: 64 lanes x 8 u16 per gld_lds call

  auto stage = [&](int t, int buf) {
    const int ko = t * BK;
    #pragma unroll
    for (int j = 0; j < 2; ++j)
      GLD_LDS16(aS[j] + ko, &sA[buf][ldsOff + j * 2048]);
    #pragma unroll
    for (int j = 0; j < 4; ++j)
      GLD_LDS16(bS[j] + ko, &sB[buf][ldsOff + j * 2048]);
  };

  const int wrow = (wave >> 1) * 64;    // 2 waves along M
  const int wcol = (wave & 1) * 128;    // 2 waves along N
  f32x4 acc[4][8] = {};

  const int NT = K / BK;

  stage(0, 0); stage(1, 1);
  asm volatile("s_waitcnt vmcnt(6)" ::: "memory");   // tile 0 resident
  __builtin_amdgcn_s_barrier();
  __builtin_amdgcn_sched_barrier(0);

  for (int t = 0; t < NT; ++t) {
    const u16* As = sA[t % 3];
    const u16* Bs = sB[t % 3];
    bf16x8 af[4], bf[8];
    #pragma unroll
    for (int m = 0; m < 4; ++m) {
      const int lr = wrow + m * 16 + r16;
      af[m] = *(const bf16x8*)&As[lr * 32 + ((g ^ ((lr >> 1) & 3)) * 8)];
    }
    #pragma unroll
    for (int n = 0; n < 8; ++n) {
      const int lr = wcol + n * 16 + r16;
      bf[n] = *(const bf16x8*)&Bs[lr * 32 + ((g ^ ((lr >> 1) & 3)) * 8)];
    }
    if (t + 2 < NT) stage(t + 2, (t + 2) % 3);

    __builtin_amdgcn_s_setprio(1);
    #pragma unroll
    for (int m = 0; m < 4; ++m)
      #pragma unroll
      for (int n = 0; n < 8; ++n)
        acc[m][n] = __builtin_amdgcn_mfma_f32_16x16x32_bf16(af[m], bf[n], acc[m][n], 0, 0, 0);
    __builtin_amdgcn_s_setprio(0);

    if (t + 1 < NT) {
      if (t + 2 < NT) asm volatile("s_waitcnt vmcnt(6)" ::: "memory");
      else            asm volatile("s_waitcnt vmcnt(0)" ::: "memory");
      __builtin_amdgcn_s_barrier();
      __builtin_amdgcn_sched_barrier(0);
    }
  }

  #pragma unroll
  for (int m = 0; m < 4; ++m) {
    #pragma unroll
    for (int n = 0; n < 8; ++n) {
      const int col = col0 + wcol + n * 16 + r16;
      const float bv = bias[col];
      const float sc = (QSCALE && col < 1024) ? 0.04508422003f : 1.f;
      const int rowb = row0 + wrow + m * 16 + g * 4;
      #pragma unroll
      for (int r = 0; r < 4; ++r) {
        float v = acc[m][n][r] + bv;
        if (RELU) v = fmaxf(v, 0.f);
        if (QSCALE) v *= sc;
        outp[(size_t)(rowb + r) * N + col] = f2bf(v);
      }
    }
  }
}

// ---------------- 256x256 bf16 NT GEMM, 8 waves, per-wave 128x64 -----------
// PHASED=0: r12-proven counted ring (depth 4, prefetch 2, boundary vmcnt(4)).
// PHASED=1 (FFN2 experiment, full T3 discipline this time): iteration = 2
//   K-tiles, 4 phases of 16 MFMA each:
//     P1 {8 ds_read (af0-3,bf0-3 of t) | stage t+2 | bar | lgkm0 | MFMA | bar}
//     P2 {4 ds_read (af4-7 of t)       |           | bar | lgkm0 | MFMA }
//        boundary: vmcnt(4) (t+1 resident, t+2 in flight) + bar
//     P3 {8 ds_read of t+1             | stage t+3 | bar | lgkm0 | MFMA | bar}
//     P4 {4 ds_read of t+1             |           | bar | lgkm0 | MFMA }
//        boundary: vmcnt(4) (t+2 resident, t+3 in flight) + bar
//   Counted waits NEVER drain mid-loop (m218 lever). Race-safety: slot
//   (t+2)&3 was last read in the PREVIOUS iteration's P1/P2, separated from
//   this stage by that iteration's boundary barrier. Requires NT even.
// RAW=1: split-K over gridDim.y; y==0 -> raw f32, y==1 -> +bias+res fused.
template<int RELU, int RAW, int QSCALE, int PHASED>
__global__ __launch_bounds__(512, 2)
void gemm_256(const u16* __restrict__ A,
              const u16* __restrict__ Bt,
              const float* __restrict__ bias,
              const u16* __restrict__ resb,
              void* __restrict__ outp,
              void* __restrict__ outp_b,
              int M, int N, int K) {
  constexpr int BK = 32;
  __shared__ u16 sA[4][256 * BK];   // 64 KB
  __shared__ u16 sB[4][256 * BK];   // 64 KB

  const int tid = threadIdx.x;
  const int wave = tid >> 6, lane = tid & 63;
  const int g = lane >> 4, r16 = lane & 15;

  const int nbx = N >> 8;
  const int nwg = gridDim.x;
  const int bid = blockIdx.x;
  const int swz = ((bid & 7) * (nwg >> 3)) + (bid >> 3);
  const int bx = swz % nbx, by = swz / nbx;
  const int row0 = by << 8, col0 = bx << 8;

  const int kspan = RAW ? (K >> 1) : K;
  const int kbase = RAW ? ((int)blockIdx.y * kspan) : 0;

  const u16* aS[2];
  const u16* bS[2];
  #pragma unroll
  for (int j = 0; j < 2; ++j) {
    const int ci = tid + 512 * j, row = ci >> 2, cc = ci & 3;
    aS[j] = A  + (size_t)(row0 + row) * K + ((cc ^ ((row >> 1) & 3)) * 8) + kbase;
    bS[j] = Bt + (size_t)(col0 + row) * K + ((cc ^ ((row >> 1) & 3)) * 8) + kbase;
  }
  const int ldsOff = wave * 512;

  auto stage = [&](int t, int buf) {
    const int ko = t * BK;
    #pragma unroll
    for (int j = 0; j < 2; ++j)
      GLD_LDS16(aS[j] + ko, &sA[buf][ldsOff + j * 4096]);
    #pragma unroll
    for (int j = 0; j < 2; ++j)
      GLD_LDS16(bS[j] + ko, &sB[buf][ldsOff + j * 4096]);
  };

  const int wrow = (wave >> 2) * 128;
  const int wcol = (wave & 3) * 64;
  f32x4 acc[8][4] = {};

  const int NT = kspan / BK;

  if constexpr (!PHASED) {
    stage(0, 0); stage(1, 1);
    asm volatile("s_waitcnt vmcnt(4)" ::: "memory");
    __builtin_amdgcn_s_barrier();
    __builtin_amdgcn_sched_barrier(0);

    for (int t = 0; t < NT; ++t) {
      const u16* As = sA[t & 3];
      const u16* Bs = sB[t & 3];
      bf16x8 af[8], bf[4];
      #pragma unroll
      for (int m = 0; m < 8; ++m) {
        const int lr = wrow + m * 16 + r16;
        af[m] = *(const bf16x8*)&As[lr * 32 + ((g ^ ((lr >> 1) & 3)) * 8)];
      }
      #pragma unroll
      for (int n = 0; n < 4; ++n) {
        const int lr = wcol + n * 16 + r16;
        bf[n] = *(const bf16x8*)&Bs[lr * 32 + ((g ^ ((lr >> 1) & 3)) * 8)];
      }
      if (t + 2 < NT) stage(t + 2, (t + 2) & 3);

      __builtin_amdgcn_s_setprio(1);
      #pragma unroll
      for (int m = 0; m < 8; ++m)
        #pragma unroll
        for (int n = 0; n < 4; ++n)
          acc[m][n] = __builtin_amdgcn_mfma_f32_16x16x32_bf16(af[m], bf[n], acc[m][n], 0, 0, 0);
      __builtin_amdgcn_s_setprio(0);

      if (t + 1 < NT) {
        if (t + 2 < NT) asm volatile("s_waitcnt vmcnt(4)" ::: "memory");
        else            asm volatile("s_waitcnt vmcnt(0)" ::: "memory");
        __builtin_amdgcn_s_barrier();
        __builtin_amdgcn_sched_barrier(0);
      }
    }
  } else {
    // ---------------- PHASED loop (NT must be even) ----------------
    stage(0, 0); stage(1, 1);
    asm volatile("s_waitcnt vmcnt(4)" ::: "memory");   // tile0 resident, tile1 in flight
    __builtin_amdgcn_s_barrier();
    __builtin_amdgcn_sched_barrier(0);

    for (int t = 0; t < NT; t += 2) {
      const u16* As0 = sA[t & 3];
      const u16* Bs0 = sB[t & 3];
      const u16* As1 = sA[(t + 1) & 3];
      const u16* Bs1 = sB[(t + 1) & 3];
      bf16x8 af[8], bf[4];

      // ---- P1: tile t, rows m0-3 ----
      #pragma unroll
      for (int m = 0; m < 4; ++m) {
        const int lr = wrow + m * 16 + r16;
        af[m] = *(const bf16x8*)&As0[lr * 32 + ((g ^ ((lr >> 1) & 3)) * 8)];
      }
      #pragma unroll
      for (int n = 0; n < 4; ++n) {
        const int lr = wcol + n * 16 + r16;
        bf[n] = *(const bf16x8*)&Bs0[lr * 32 + ((g ^ ((lr >> 1) & 3)) * 8)];
      }
      if (t + 2 < NT) stage(t + 2, (t + 2) & 3);
      __builtin_amdgcn_s_barrier();
      asm volatile("s_waitcnt lgkmcnt(0)" ::: "memory");
      __builtin_amdgcn_sched_barrier(0);
      __builtin_amdgcn_s_setprio(1);
      #pragma unroll
      for (int m = 0; m < 4; ++m)
        #pragma unroll
        for (int n = 0; n < 4; ++n)
          acc[m][n] = __builtin_amdgcn_mfma_f32_16x16x32_bf16(af[m], bf[n], acc[m][n], 0, 0, 0);
      __builtin_amdgcn_s_setprio(0);
      __builtin_amdgcn_s_barrier();
      __builtin_amdgcn_sched_barrier(0);

      // ---- P2: tile t, rows m4-7 ----
      #pragma unroll
      for (int m = 4; m < 8; ++m) {
        const int lr = wrow + m * 16 + r16;
        af[m] = *(const bf16x8*)&As0[lr * 32 + ((g ^ ((lr >> 1) & 3)) * 8)];
      }
      __builtin_amdgcn_s_barrier();
      asm volatile("s_waitcnt lgkmcnt(0)" ::: "memory");
      __builtin_amdgcn_sched_barrier(0);
      __builtin_amdgcn_s_setprio(1);
      #pragma unroll
      for (int m = 4; m < 8; ++m)
        #pragma unroll
        for (int n = 0; n < 4; ++n)
          acc[m][n] = __builtin_amdgcn_mfma_f32_16x16x32_bf16(af[m], bf[n], acc[m][n], 0, 0, 0);
      __builtin_amdgcn_s_setprio(0);
      // boundary 1: tile t+1 must be resident (t+2's 4 loads stay in flight)
      if (t + 2 < NT) asm volatile("s_waitcnt vmcnt(4)" ::: "memory");
      else            asm volatile("s_waitcnt vmcnt(0)" ::: "memory");
      __builtin_amdgcn_s_barrier();
      __builtin_amdgcn_sched_barrier(0);

      // ---- P3: tile t+1, rows m0-3 ----
      #pragma unroll
      for (int m = 0; m < 4; ++m) {
        const int lr = wrow + m * 16 + r16;
        af[m] = *(const bf16x8*)&As1[lr * 32 + ((g ^ ((lr >> 1) & 3)) * 8)];
      }
      #pragma unroll
      for (int n = 0; n < 4; ++n) {
        const int lr = wcol + n * 16 + r16;
        bf[n] = *(const bf16x8*)&Bs1[lr * 32 + ((g ^ ((lr >> 1) & 3)) * 8)];
      }
      if (t + 3 < NT) stage(t + 3, (t + 3) & 3);
      __builtin_amdgcn_s_barrier();
      asm volatile("s_waitcnt lgkmcnt(0)" ::: "memory");
      __builtin_amdgcn_sched_barrier(0);
      __builtin_amdgcn_s_setprio(1);
      #pragma unroll
      for (int m = 0; m < 4; ++m)
        #pragma unroll
        for (int n = 0; n < 4; ++n)
          acc[m][n] = __builtin_amdgcn_mfma_f32_16x16x32_bf16(af[m], bf[n], acc[m][n], 0, 0, 0);
      __builtin_amdgcn_s_setprio(0);
      __builtin_amdgcn_s_barrier();
      __builtin_amdgcn_sched_barrier(0);

      // ---- P4: tile t+1, rows m4-7 ----
      #pragma unroll
      for (int m = 4; m < 8; ++m) {
        const int lr = wrow + m * 16 + r16;
        af[m] = *(const bf16x8*)&As1[lr * 32 + ((g ^ ((lr >> 1) & 3)) * 8)];
      }
      __builtin_amdgcn_s_barrier();
      asm volatile("s_waitcnt lgkmcnt(0)" ::: "memory");
      __builtin_amdgcn_sched_barrier(0);
      __builtin_amdgcn_s_setprio(1);
      #pragma unroll
      for (int m = 4; m < 8; ++m)
        #pragma unroll
        for (int n = 0; n < 4; ++n)
          acc[m][n] = __builtin_amdgcn_mfma_f32_16x16x32_bf16(af[m], bf[n], acc[m][n], 0, 0, 0);
      __builtin_amdgcn_s_setprio(0);
      // boundary 2: tile t+2 resident for next iteration (t+3 in flight)
      if (t + 2 < NT) {
        if (t + 3 < NT) asm volatile("s_waitcnt vmcnt(4)" ::: "memory");
        else            asm volatile("s_waitcnt vmcnt(0)" ::: "memory");
        __builtin_amdgcn_s_barrier();
        __builtin_amdgcn_sched_barrier(0);
      }
    }
  }

  if constexpr (RAW) {
    if (blockIdx.y) {
      // final split: fuse bias + bf16 residual, write f32
      float* po = (float*)outp_b;
      #pragma unroll
      for (int m = 0; m < 8; ++m) {
        #pragma unroll
        for (int n = 0; n < 4; ++n) {
          const int col = col0 + wcol + n * 16 + r16;
          const float bv = bias[col];
          const int rowb = row0 + wrow + m * 16 + g * 4;
          #pragma unroll
          for (int r = 0; r < 4; ++r) {
            const size_t idx = (size_t)(rowb + r) * N + col;
            po[idx] = acc[m][n][r] + bv + bf2f(resb[idx]);
          }
        }
      }
    } else {
      float* po = (float*)outp;
      #pragma unroll
      for (int m = 0; m < 8; ++m) {
        #pragma unroll
        for (int n = 0; n < 4; ++n) {
          const int col = col0 + wcol + n * 16 + r16;
          const int rowb = row0 + wrow + m * 16 + g * 4;
          #pragma unroll
          for (int r = 0; r < 4; ++r)
            po[(size_t)(rowb + r) * N + col] = acc[m][n][r];
        }
      }
    }
  } else {
    u16* po = (u16*)outp;
    #pragma unroll
    for (int m = 0; m < 8; ++m) {
      #pragma unroll
      for (int n = 0; n < 4; ++n) {
        const int col = col0 + wcol + n * 16 + r16;
        const float bv = bias[col];
        const float sc = (QSCALE && col < 1024) ? 0.04508422003f : 1.f;
        const int rowb = row0 + wrow + m * 16 + g * 4;
        #pragma unroll
        for (int r = 0; r < 4; ++r) {
          float v = acc[m][n][r] + bv;
          if (RELU) v = fmaxf(v, 0.f);
          if (QSCALE) v *= sc;
          po[(size_t)(rowb + r) * N + col] = f2bf(v);
        }
      }
    }
  }
}

// ---------------- FFN2 split-K reduce: out += pA (bias/res fused in gemm) --
__global__ __launch_bounds__(256) void ffn2_reduce(const float* __restrict__ pA,
                                                   float* __restrict__ out) {
  size_t i = ((size_t)blockIdx.x * 256 + threadIdx.x) * 4;
  float4 a = *(const float4*)(pA + i);
  float4 o = *(const float4*)(out + i);
  float4 v;
  v.x = a.x + o.x;
  v.y = a.y + o.y;
  v.z = a.z + o.z;
  v.w = a.w + o.w;
  *(float4*)(out + i) = v;
}

// ---------------- bf16 NT GEMM, pipelined BMxBN tile (narrow N) ------------
template<int BM, int BN, int THREADS, int OUT_F32, int RELU, int RES>
__global__ __launch_bounds__(THREADS, 3)
void gemm_pipe(const u16* __restrict__ A,
               const u16* __restrict__ Bt,
               const float* __restrict__ bias,
               const float* __restrict__ res,
               void* __restrict__ outp,
               int M, int N, int K) {
  constexpr int BK  = 32;
  constexpr int CHA = (BM * 4) / THREADS;
  constexpr int CHB = (BN * 4) / THREADS;
  constexpr int CH  = CHA + CHB;

  __shared__ u16 sA[3][BM * BK];
  __shared__ u16 sB[3][BN * BK];

  const int tid = threadIdx.x;
  const int wave = tid >> 6, lane = tid & 63;
  const int g = lane >> 4, r16 = lane & 15;

  const int nbx = N / BN;
  const int nwg = gridDim.x;
  const int bid = blockIdx.x;
  const int swz = ((bid & 7) * (nwg >> 3)) + (bid >> 3);
  const int bx = swz % nbx, by = swz / nbx;
  const int row0 = by * BM, col0 = bx * BN;

  const u16* aS[CHA];
  const u16* bS[CHB];
  #pragma unroll
  for (int j = 0; j < CHA; ++j) {
    const int ci = tid + THREADS * j, row = ci >> 2, cc = ci & 3;
    aS[j] = A + (size_t)(row0 + row) * K + ((cc ^ ((row >> 1) & 3)) * 8);
  }
  #pragma unroll
  for (int j = 0; j < CHB; ++j) {
    const int ci = tid + THREADS * j, row = ci >> 2, cc = ci & 3;
    bS[j] = Bt + (size_t)(col0 + row) * K + ((cc ^ ((row >> 1) & 3)) * 8);
  }
  const int ldsOff = wave * 512;

  auto stage = [&](int t, int buf) {
    const int ko = t * BK;
    #pragma unroll
    for (int j = 0; j < CHA; ++j)
      GLD_LDS16(aS[j] + ko, &sA[buf][ldsOff + j * (THREADS * 8)]);
    #pragma unroll
    for (int j = 0; j < CHB; ++j)
      GLD_LDS16(bS[j] + ko, &sB[buf][ldsOff + j * (THREADS * 8)]);
  };

  const int wrow = (wave >> 1) * 64;
  const int wcol = (wave & 1) * 64;
  f32x4 acc[4][4] = {};

  const int NT = K / BK;

  stage(0, 0); stage(1, 1);
  if constexpr (CH == 3) asm volatile("s_waitcnt vmcnt(3)" ::: "memory");
  else                   asm volatile("s_waitcnt vmcnt(4)" ::: "memory");
  __builtin_amdgcn_s_barrier();
  __builtin_amdgcn_sched_barrier(0);

  for (int t = 0; t < NT; ++t) {
    if (t + 2 < NT) stage(t + 2, (t + 2) % 3);
    const u16* As = sA[t % 3];
    const u16* Bs = sB[t % 3];
    bf16x8 af[4], bf[4];
    #pragma unroll
    for (int m = 0; m < 4; ++m) {
      const int lr = wrow + m * 16 + r16;
      af[m] = *(const bf16x8*)&As[lr * 32 + ((g ^ ((lr >> 1) & 3)) * 8)];
    }
    #pragma unroll
    for (int n = 0; n < 4; ++n) {
      const int lr = wcol + n * 16 + r16;
      bf[n] = *(const bf16x8*)&Bs[lr * 32 + ((g ^ ((lr >> 1) & 3)) * 8)];
    }
    __builtin_amdgcn_s_setprio(1);
    #pragma unroll
    for (int m = 0; m < 4; ++m)
      #pragma unroll
      for (int n = 0; n < 4; ++n)
        acc[m][n] = __builtin_amdgcn_mfma_f32_16x16x32_bf16(af[m], bf[n], acc[m][n], 0, 0, 0);
    __builtin_amdgcn_s_setprio(0);

    if (t + 1 < NT) {
      if (t + 2 < NT) {
        if constexpr (CH == 3) asm volatile("s_waitcnt vmcnt(3)" ::: "memory");
        else                   asm volatile("s_waitcnt vmcnt(4)" ::: "memory");
      } else {
        asm volatile("s_waitcnt vmcnt(0)" ::: "memory");
      }
      __builtin_amdgcn_s_barrier();
      __builtin_amdgcn_sched_barrier(0);
    }
  }

  #pragma unroll
  for (int m = 0; m < 4; ++m) {
    #pragma unroll
    for (int n = 0; n < 4; ++n) {
      const int col = col0 + wcol + n * 16 + r16;
      const float bv = bias[col];
      const int rowb = row0 + wrow + m * 16 + g * 4;
      #pragma unroll
      for (int r = 0; r < 4; ++r) {
        const size_t idx = (size_t)(rowb + r) * N + col;
        float v = acc[m][n][r] + bv;
        if (RES)  v += res[idx];
        if (RELU) v = fmaxf(v, 0.f);
        if (OUT_F32) ((float*)outp)[idx] = v;
        else         ((u16*)outp)[idx]   = f2bf(v);
      }
    }
  }
}

// ---------------- causal flash attention v9 --------------------------------
// Dual-strip fused tile; raw v_exp_f32 no-max softmax (Q pre-scaled);
// permlane P transport; ones-MFMA row sums.
// v9: 2-deep LDS ring (32 KB) -> 4 blocks/CU, all 1024 blocks co-resident.
__global__ __launch_bounds__(256, 4) void attn_fwd(const u16* __restrict__ qkv,
                                                   const u16* __restrict__ Vt,
                                                   u16* __restrict__ O) {
  __shared__ u16 sK[2][64 * 64];
  __shared__ u16 sV[2][64 * 64];

  const int orig = blockIdx.x;                       // 1024 blocks
  const int work = ((orig & 7) << 7) + (orig >> 3);  // XCD swizzle
  const int i = work & 15;
  const int h = (work >> 4) & 15;
  const int b = work >> 8;
  const int qA = i << 6, qB = (31 - i) << 6;
  const int nA = i + 1,  nB = 32 - i;

  const int tid = threadIdx.x, wave = tid >> 6, lane = tid & 63;
  const int g = lane >> 4, r16 = lane & 15;

  const size_t base = (size_t)b * T_ * 3072 + h * 64;
  const u16* Qp = qkv + base;
  const u16* Kp = qkv + base + 1024;
  const u16* VtP = Vt + (size_t)(b * 16 + h) * 64 * T_;

  const int rowL = lane >> 3;
  const int colL = 8 * ((lane & 7) ^ rowL);
  const u16* kSrc = Kp  + (size_t)(wave * 16 + rowL) * 3072 + colL;
  const u16* vSrc = VtP + (size_t)(wave * 16 + rowL) * T_   + colL;
  u16* kDst0 = &sK[0][(wave * 16 + 0) * 64];
  u16* kDst8 = &sK[0][(wave * 16 + 8) * 64];
  u16* vDst0 = &sV[0][(wave * 16 + 0) * 64];
  u16* vDst8 = &sV[0][(wave * 16 + 8) * 64];

  const int ck0 = (( 0 + g * 16) ^ ((r16 & 7) << 4)) >> 1;
  const int ck1 = ((64 + g * 16) ^ ((r16 & 7) << 4)) >> 1;

  bf16x8 qfA[2], qfB[2];
  #pragma unroll
  for (int kc = 0; kc < 2; ++kc) {
    qfA[kc] = *(const bf16x8*)(Qp + (size_t)(qA + wave * 16 + r16) * 3072 + kc * 32 + g * 8);
    qfB[kc] = *(const bf16x8*)(Qp + (size_t)(qB + wave * 16 + r16) * 3072 + kc * 32 + g * 8);
  }

  f32x4 accA[4] = {}, accB[4] = {};
  f32x4 lA4 = {}, lB4 = {};
  const int qaA = qA + wave * 16 + r16;
  const int qaB = qB + wave * 16 + r16;

  const u32 one2 = 0x3F803F80u;      // bf16 1.0 pair
  const u32x4 onesv = {one2, one2, one2, one2};
  const bf16x8 ONES = __builtin_bit_cast(bf16x8, onesv);

  int sbuf = 0;
  auto stageAdv = [&]() {
    const int o = sbuf * 4096;
    GLD_LDS16(kSrc,            kDst0 + o);
    GLD_LDS16(kSrc + 8 * 3072, kDst8 + o);
    GLD_LDS16(vSrc,            vDst0 + o);
    GLD_LDS16(vSrc + 8 * T_,   vDst8 + o);
    kSrc += 64 * 3072;
    vSrc += 64;
    sbuf ^= 1;
  };

  auto qkt = [&](const bf16x8* kf0, const bf16x8* kf1, const bf16x8* qf, f32x4* s) {
    __builtin_amdgcn_s_setprio(1);
    #pragma unroll
    for (int ni = 0; ni < 4; ++ni) {
      f32x4 t = {};
      t = __builtin_amdgcn_mfma_f32_16x16x32_bf16(kf0[ni], qf[0], t, 0, 0, 0);
      t = __builtin_amdgcn_mfma_f32_16x16x32_bf16(kf1[ni], qf[1], t, 0, 0, 0);
      s[ni] = t;
    }
    __builtin_amdgcn_s_setprio(0);
  };

  auto softmax_pack = [&](f32x4* s, bool diag, int q_abs, int kv0, bf16x8* pa) {
    if (diag) {
      #pragma unroll
      for (int ni = 0; ni < 4; ++ni)
        #pragma unroll
        for (int r = 0; r < 4; ++r) {
          const int kv_abs = kv0 + ni * 16 + g * 4 + r;
          if (kv_abs > q_abs) s[ni][r] = -3e38f;
        }
    }
    #pragma unroll
    for (int ni = 0; ni < 4; ++ni)
      #pragma unroll
      for (int r = 0; r < 4; ++r)
        s[ni][r] = fast_exp2(s[ni][r]);

    u32 pk[4][2];
    #pragma unroll
    for (int ni = 0; ni < 4; ++ni)
      #pragma unroll
      for (int h2 = 0; h2 < 2; ++h2)
        asm("v_cvt_pk_bf16_f32 %0, %1, %2"
            : "=v"(pk[ni][h2]) : "v"(s[ni][2 * h2]), "v"(s[ni][2 * h2 + 1]));

    u32 pa32[2][4];
    #pragma unroll
    for (int kc = 0; kc < 2; ++kc)
      #pragma unroll
      for (int h2 = 0; h2 < 2; ++h2) {
        u32 a = pk[2 * kc][h2], bq_ = pk[2 * kc + 1][h2];
        asm("v_permlane32_swap_b32 %0, %1" : "+v"(a), "+v"(bq_));
        asm("v_permlane16_swap_b32 %0, %1" : "+v"(a), "+v"(bq_));
        pa32[kc][h2] = a;
        pa32[kc][2 + h2] = bq_;
      }
    #pragma unroll
    for (int kc = 0; kc < 2; ++kc) {
      u32x4 tmp = {pa32[kc][0], pa32[kc][1], pa32[kc][2], pa32[kc][3]};
      pa[kc] = __builtin_bit_cast(bf16x8, tmp);
    }
  };

  // prologue: tile 0 only (2-deep ring, prefetch distance 1)
  stageAdv();
  asm volatile("s_waitcnt vmcnt(0)" ::: "memory");
  __builtin_amdgcn_s_barrier();
  __builtin_amdgcn_sched_barrier(0);

  int cbuf = 0;
  for (int t = 0; t < nB; ++t) {
    if (t + 1 < nB) stageAdv();
    const u16* Kb = sK[cbuf];
    const u16* Vb = sV[cbuf];
    const int kv0 = t << 6;
    const bool actA = (t < nA);

    bf16x8 kf0[4], kf1[4];
    #pragma unroll
    for (int ni = 0; ni < 4; ++ni) {
      kf0[ni] = *(const bf16x8*)&Kb[(ni * 16 + r16) * 64 + ck0];
      kf1[ni] = *(const bf16x8*)&Kb[(ni * 16 + r16) * 64 + ck1];
    }

    f32x4 s[4];
    bf16x8 paB[2], paA[2];

    qkt(kf0, kf1, qfB, s);
    softmax_pack(s, t == nB - 1, qaB, kv0, paB);
    if (actA) {
      qkt(kf0, kf1, qfA, s);
      softmax_pack(s, t == nA - 1, qaA, kv0, paA);
    }

    bf16x8 vf0[4], vf1[4];
    #pragma unroll
    for (int hsb = 0; hsb < 4; ++hsb) {
      vf0[hsb] = *(const bf16x8*)&Vb[(hsb * 16 + r16) * 64 + ck0];
      vf1[hsb] = *(const bf16x8*)&Vb[(hsb * 16 + r16) * 64 + ck1];
    }

    __builtin_amdgcn_s_setprio(1);
    lB4 = __builtin_amdgcn_mfma_f32_16x16x32_bf16(paB[0], ONES, lB4, 0, 0, 0);
    lB4 = __builtin_amdgcn_mfma_f32_16x16x32_bf16(paB[1], ONES, lB4, 0, 0, 0);
    #pragma unroll
    for (int hsb = 0; hsb < 4; ++hsb) {
      accB[hsb] = __builtin_amdgcn_mfma_f32_16x16x32_bf16(paB[0], vf0[hsb], accB[hsb], 0, 0, 0);
      accB[hsb] = __builtin_amdgcn_mfma_f32_16x16x32_bf16(paB[1], vf1[hsb], accB[hsb], 0, 0, 0);
    }
    if (actA) {
      lA4 = __builtin_amdgcn_mfma_f32_16x16x32_bf16(paA[0], ONES, lA4, 0, 0, 0);
      lA4 = __builtin_amdgcn_mfma_f32_16x16x32_bf16(paA[1], ONES, lA4, 0, 0, 0);
      #pragma unroll
      for (int hsb = 0; hsb < 4; ++hsb) {
        accA[hsb] = __builtin_amdgcn_mfma_f32_16x16x32_bf16(paA[0], vf0[hsb], accA[hsb], 0, 0, 0);
        accA[hsb] = __builtin_amdgcn_mfma_f32_16x16x32_bf16(paA[1], vf1[hsb], accA[hsb], 0, 0, 0);
      }
    }
    __builtin_amdgcn_s_setprio(0);

    if (t + 1 < nB) {
      asm volatile("s_waitcnt vmcnt(0)" ::: "memory");
      __builtin_amdgcn_s_barrier();
      __builtin_amdgcn_sched_barrier(0);
    }
    cbuf ^= 1;
  }

  float rlA[4], rlB[4];
  #pragma unroll
  for (int r = 0; r < 4; ++r) {
    rlA[r] = fast_rcp(lA4[r]);
    rlB[r] = fast_rcp(lB4[r]);
  }
  #pragma unroll
  for (int hsb = 0; hsb < 4; ++hsb)
    #pragma unroll
    for (int r = 0; r < 4; ++r) {
      const size_t rowA = (size_t)b * T_ + qA + wave * 16 + g * 4 + r;
      const size_t rowB = (size_t)b * T_ + qB + wave * 16 + g * 4 + r;
      O[rowA * C_ + h * 64 + hsb * 16 + r16] = f2bf(accA[hsb][r] * rlA[r]);
      O[rowB * C_ + h * 64 + hsb * 16 + r16] = f2bf(accB[hsb][r] * rlB[r]);
    }
}

// ---------------------------------------------------------------------------
extern "C" void kernel_launch(void* const* d_in, const int* in_sizes, int n_in,
                              void* d_out, int out_size, void* d_ws, size_t ws_size,
                              hipStream_t stream) {
  const float* x    = (const float*)d_in[0];
  const float* ln1g = (const float*)d_in[1];
  const float* ln1b = (const float*)d_in[2];
  const float* ln2g = (const float*)d_in[3];
  const float* ln2b = (const float*)d_in[4];
  const float* Wq   = (const float*)d_in[5];
  const float* bq   = (const float*)d_in[6];
  const float* Wk   = (const float*)d_in[7];
  const float* bk   = (const float*)d_in[8];
  const float* Wv   = (const float*)d_in[9];
  const float* bv   = (const float*)d_in[10];
  const float* Wo   = (const float*)d_in[11];
  const float* bo   = (const float*)d_in[12];
  const float* W1   = (const float*)d_in[13];
  const float* b1   = (const float*)d_in[14];
  const float* W2   = (const float*)d_in[15];
  const float* b2   = (const float*)d_in[16];

  char* w = (char*)d_ws;
  float* ps    = (float*)(w + 0);
  float* psq   = (float*)(w + 262144);
  float* mean  = (float*)(w + 524288);
  float* rstd  = (float*)(w + 540672);
  float* bqkv  = (float*)(w + 557056);
  u16*   h     = (u16*)  (w + 573440);          // 16 MB (dead after FFN1)
  u16*   wqkvT = (u16*)  (w + 17350656);        // 6 MB
  u16*   woT   = (u16*)  (w + 23642112);        // 2 MB
  u16*   w1T   = (u16*)  (w + 25739264);        // 8 MB
  u16*   w2T   = (u16*)  (w + 34127872);        // 8 MB
  u16*   x1b   = (u16*)  (w + 42516480);        // 16 MB bf16 residual stream
  u16*   Vt    = (u16*)  (w + 59293696);        // 16 MB
  u16*   qkv   = (u16*)  (w + 76070912);        // 48 MB
  u16*   Oo    = (u16*)  (w + 126402560);       // 16 MB
  u16*   u     = qkv;                           // alias
  float* pA    = (float*)(w + 573440);          // 32 MB FFN2 partial (over dead h..w1T)

  // pack weights
  transpose_cast<<<dim3(2, 32, 16), 256, 0, stream>>>(Wq, wqkvT,                     64,   1024, (size_t)C_ * 64, (size_t)64 * 1024);
  transpose_cast<<<dim3(2, 32, 16), 256, 0, stream>>>(Wk, wqkvT + (size_t)1024*1024, 64,   1024, (size_t)C_ * 64, (size_t)64 * 1024);
  transpose_cast<<<dim3(2, 32, 16), 256, 0, stream>>>(Wv, wqkvT + (size_t)2048*1024, 64,   1024, (size_t)C_ * 64, (size_t)64 * 1024);
  transpose_cast<<<dim3(32, 32, 1), 256, 0, stream>>>(Wo, woT, 1024, 1024, 0, 0);
  transpose_cast<<<dim3(128, 32, 1), 256, 0, stream>>>(W1, w1T, 4096, 1024, 0, 0);
  transpose_cast<<<dim3(32, 128, 1), 256, 0, stream>>>(W2, w2T, 1024, 4096, 0, 0);
  concat_bias<<<12, 256, 0, stream>>>(bq, bk, bv, bqkv);

  // LN1 -> h (bf16)
  ln_partial<<<dim3(16, 16), 256, 0, stream>>>(x, ps, psq);
  ln_final<<<16, 256, 0, stream>>>(ps, psq, mean, rstd);
  ln_norm<<<8192, 256, 0, stream>>>(x, mean, rstd, ln1g, ln1b, h);

  // QKV projection (Q cols pre-scaled): 64x12 = 768 blocks of 128x256, 2/CU
  gemm_128x256<0, 1><<<768, 256, 0, stream>>>(h, wqkvT, bqkv, qkv, BT_, 3072, 1024);

  // V transpose for attention
  v_transpose<<<dim3(T_ / 32, 2, B_ * H_), 256, 0, stream>>>(qkv, Vt);

  // attention (mirror-paired q-tiles, dual-strip fused, all blocks resident)
  attn_fwd<<<1024, 256, 0, stream>>>(qkv, Vt, Oo);

  // output projection + residual -> x1b (bf16): 512 blocks
  gemm_pipe<128, 128, 256, 0, 0, 1><<<512, 256, 0, stream>>>(Oo, woT, bo, x, x1b, BT_, 1024, 1024);

  // LN2 -> h (from bf16 residual stream)
  ln_partial_bf<<<dim3(16, 16), 256, 0, stream>>>(x1b, ps, psq);
  ln_final<<<16, 256, 0, stream>>>(ps, psq, mean, rstd);
  ln_norm_bf<<<8192, 256, 0, stream>>>(x1b, mean, rstd, ln2g, ln2b, h);

  // FFN1 (M=8192, N=4096): reverted to proven 128x256 ring (78 us, r1)
  gemm_128x256<1, 0><<<1024, 256, 0, stream>>>(h, w1T, b1, u, BT_, 4096, 1024);
  // FFN2 split-K=2 (PHASED experiment): y=0 -> pA raw, y=1 -> d_out fused
  gemm_256<0, 1, 0, 1><<<dim3(128, 2), 512, 0, stream>>>(u, w2T, b2, x1b, pA, d_out, BT_, 1024, 4096);
  // reduce: d_out += pA
  ffn2_reduce<<<8192, 256, 0, stream>>>(pA, (float*)d_out);
}

// Round 4
// 393.379 us; speedup vs baseline: 1.0366x; 1.0366x over previous
//
#include <hip/hip_runtime.h>

#define B_   4
#define T_   2048
#define C_   1024
#define H_   16
#define HS_  64
#define BT_  (B_*T_)
#define EPS_ 1e-5f

typedef unsigned short u16;
typedef unsigned int   u32;
typedef __attribute__((ext_vector_type(8))) __bf16 bf16x8;
typedef __attribute__((ext_vector_type(4))) float  f32x4;
typedef __attribute__((ext_vector_type(8))) u16    u16x8;
typedef __attribute__((ext_vector_type(4))) u16    u16x4;
typedef __attribute__((ext_vector_type(4))) u32    u32x4;

__device__ __forceinline__ u16 f2bf(float f) {
  unsigned x = __builtin_bit_cast(unsigned, f);
  x += 0x7fffu + ((x >> 16) & 1u);
  return (u16)(x >> 16);
}
__device__ __forceinline__ float bf2f(u16 v) {
  return __builtin_bit_cast(float, (u32)v << 16);
}

__device__ __forceinline__ float fast_exp2(float x) {
  float y;
  asm("v_exp_f32 %0, %1" : "=v"(y) : "v"(x));
  return y;
}
__device__ __forceinline__ float fast_rcp(float x) {
  float y;
  asm("v_rcp_f32 %0, %1" : "=v"(y) : "v"(x));
  return y;
}

#define GLD_LDS16(src, dst) \
  __builtin_amdgcn_global_load_lds((__attribute__((address_space(1))) void*)(src), \
                                   (__attribute__((address_space(3))) void*)(dst), 16, 0, 0)

// ---------------- LayerNorm over time axis (axis=1, ddof=1) ----------------
__global__ __launch_bounds__(256) void ln_partial(const float* __restrict__ x,
                                                  float* __restrict__ ps,
                                                  float* __restrict__ psq) {
  int col = blockIdx.x * 256 + threadIdx.x;      // 0..B*C-1
  int b = col >> 10, c = col & (C_ - 1);
  int t0 = blockIdx.y * (T_ / 16);
  const float* p = x + (size_t)b * T_ * C_ + (size_t)t0 * C_ + c;
  float s = 0.f, sq = 0.f;
  #pragma unroll 4
  for (int i = 0; i < T_ / 16; ++i) { float v = p[(size_t)i * C_]; s += v; sq += v * v; }
  ps [blockIdx.y * (B_ * C_) + col] = s;
  psq[blockIdx.y * (B_ * C_) + col] = sq;
}

// bf16-input variant (x1 residual stream)
__global__ __launch_bounds__(256) void ln_partial_bf(const u16* __restrict__ x,
                                                     float* __restrict__ ps,
                                                     float* __restrict__ psq) {
  int col = blockIdx.x * 256 + threadIdx.x;
  int b = col >> 10, c = col & (C_ - 1);
  int t0 = blockIdx.y * (T_ / 16);
  const u16* p = x + (size_t)b * T_ * C_ + (size_t)t0 * C_ + c;
  float s = 0.f, sq = 0.f;
  #pragma unroll 4
  for (int i = 0; i < T_ / 16; ++i) { float v = bf2f(p[(size_t)i * C_]); s += v; sq += v * v; }
  ps [blockIdx.y * (B_ * C_) + col] = s;
  psq[blockIdx.y * (B_ * C_) + col] = sq;
}

__global__ __launch_bounds__(256) void ln_final(const float* __restrict__ ps,
                                                const float* __restrict__ psq,
                                                float* __restrict__ mean,
                                                float* __restrict__ rstd) {
  int col = blockIdx.x * 256 + threadIdx.x;
  float s = 0.f, sq = 0.f;
  #pragma unroll
  for (int i = 0; i < 16; ++i) { s += ps[i * (B_ * C_) + col]; sq += psq[i * (B_ * C_) + col]; }
  float m = s * (1.f / T_);
  float var = (sq - (float)T_ * m * m) * (1.f / (T_ - 1));   // ddof=1
  mean[col] = m;
  rstd[col] = rsqrtf(var + EPS_);
}

__global__ __launch_bounds__(256) void ln_norm(const float* __restrict__ x,
                                               const float* __restrict__ mean,
                                               const float* __restrict__ rstd,
                                               const float* __restrict__ gam,
                                               const float* __restrict__ bet,
                                               u16* __restrict__ out) {
  size_t i = ((size_t)blockIdx.x * 256 + threadIdx.x) * 4;
  int c  = (int)(i & (C_ - 1));
  int b  = (int)(i >> 21);
  int bc = (b << 10) + c;
  float4 v = *(const float4*)(x + i);
  float vv[4] = {v.x, v.y, v.z, v.w};
  u16x4 o;
  #pragma unroll
  for (int j = 0; j < 4; ++j)
    o[j] = f2bf(gam[c + j] * (vv[j] - mean[bc + j]) * rstd[bc + j] + bet[c + j]);
  *(u16x4*)(out + i) = o;
}

// bf16-input variant
__global__ __launch_bounds__(256) void ln_norm_bf(const u16* __restrict__ x,
                                                  const float* __restrict__ mean,
                                                  const float* __restrict__ rstd,
                                                  const float* __restrict__ gam,
                                                  const float* __restrict__ bet,
                                                  u16* __restrict__ out) {
  size_t i = ((size_t)blockIdx.x * 256 + threadIdx.x) * 4;
  int c  = (int)(i & (C_ - 1));
  int b  = (int)(i >> 21);
  int bc = (b << 10) + c;
  u16x4 v = *(const u16x4*)(x + i);
  u16x4 o;
  #pragma unroll
  for (int j = 0; j < 4; ++j)
    o[j] = f2bf(gam[c + j] * (bf2f(v[j]) - mean[bc + j]) * rstd[bc + j] + bet[c + j]);
  *(u16x4*)(out + i) = o;
}

// ---------------- weight pack: transpose + cast f32 -> bf16 ----------------
__global__ __launch_bounds__(256) void transpose_cast(const float* __restrict__ in,
                                                      u16* __restrict__ out,
                                                      int cols_in, int ld_out,
                                                      size_t batch_in, size_t batch_out) {
  __shared__ float tile[32][33];
  const float* I = in + (size_t)blockIdx.z * batch_in;
  u16* Ou = out + (size_t)blockIdx.z * batch_out;
  int r0 = blockIdx.y << 5, c0 = blockIdx.x << 5;
  int tx = threadIdx.x & 31, ty = threadIdx.x >> 5;
  #pragma unroll
  for (int rr = 0; rr < 32; rr += 8)
    tile[ty + rr][tx] = I[(size_t)(r0 + ty + rr) * cols_in + c0 + tx];
  __syncthreads();
  #pragma unroll
  for (int rr = 0; rr < 32; rr += 8)
    Ou[(size_t)(c0 + ty + rr) * ld_out + r0 + tx] = f2bf(tile[tx][ty + rr]);
}

__global__ __launch_bounds__(256) void concat_bias(const float* __restrict__ bq,
                                                   const float* __restrict__ bk,
                                                   const float* __restrict__ bv,
                                                   float* __restrict__ out) {
  int i = blockIdx.x * 256 + threadIdx.x;
  float v = (i < 1024) ? bq[i] : (i < 2048 ? bk[i - 1024] : bv[i - 2048]);
  out[i] = v;
}

// ---------------- V transpose: qkv V block -> Vt[bh][hs][T] bf16 -----------
__global__ __launch_bounds__(256) void v_transpose(const u16* __restrict__ qkv,
                                                   u16* __restrict__ Vt) {
  __shared__ u16 tile[32][33];
  int bh = blockIdx.z; int b = bh >> 4, h = bh & 15;
  int t0 = blockIdx.x << 5, hs0 = blockIdx.y << 5;
  int tx = threadIdx.x & 31, ty = threadIdx.x >> 5;
  const u16* src = qkv + (size_t)(b * T_ + t0) * 3072 + 2048 + h * 64 + hs0;
  #pragma unroll
  for (int rr = 0; rr < 32; rr += 8)
    tile[ty + rr][tx] = src[(size_t)(ty + rr) * 3072 + tx];
  __syncthreads();
  u16* dst = Vt + ((size_t)bh * 64 + hs0) * T_ + t0;
  #pragma unroll
  for (int rr = 0; rr < 32; rr += 8)
    dst[(size_t)(ty + rr) * T_ + tx] = tile[tx][ty + rr];
}

// ---------------- 128xBN bf16 NT GEMM, 4 waves, per-wave 64x(BN/2) ---------
// r12-proven counted ring: depth 3, prefetch distance 2, boundary
// vmcnt(2+CHB) = one stage (CHA+CHB loads) in flight. Conflict-free XOR
// chunk swizzle. BN=256: the proven 881 TF FFN1 config (LDS 72 KB, 2/CU).
// BN=192: QKV config -> grid 64x16 = 1024 blocks = 2 CLEAN rounds at 2/CU
// (was 768 blocks = 1.5 rounds, half-idle tail round). LDS 60 KB, 2/CU.
template<int BN, int RELU, int QSCALE>
__global__ __launch_bounds__(256, 2)
void gemm_128t(const u16* __restrict__ A,
               const u16* __restrict__ Bt,
               const float* __restrict__ bias,
               u16* __restrict__ outp,
               int M, int N, int K) {
  constexpr int BK  = 32;
  constexpr int CHA = 2;            // 128*4/256
  constexpr int CHB = BN / 64;      // BN*4/256
  constexpr int NF  = BN / 32;      // per-wave N fragments

  __shared__ u16 sA[3][128 * BK];
  __shared__ u16 sB[3][BN * BK];

  const int tid = threadIdx.x;
  const int wave = tid >> 6, lane = tid & 63;
  const int g = lane >> 4, r16 = lane & 15;

  const int nbx = N / BN;
  const int nwg = gridDim.x;
  const int bid = blockIdx.x;
  const int swz = ((bid & 7) * (nwg >> 3)) + (bid >> 3);
  const int bx = swz % nbx, by = swz / nbx;
  const int row0 = by << 7, col0 = bx * BN;

  // staging: chunk ci -> (row = ci>>2, cc = ci&3); phys chunk cc holds logical
  // chunk cc^((row>>1)&3) (XOR bits disjoint from row parity; 0 conflicts)
  const u16* aS[CHA];
  const u16* bS[CHB];
  #pragma unroll
  for (int j = 0; j < CHA; ++j) {
    const int ci = tid + 256 * j, row = ci >> 2, cc = ci & 3;
    aS[j] = A + (size_t)(row0 + row) * K + ((cc ^ ((row >> 1) & 3)) * 8);
  }
  #pragma unroll
  for (int j = 0; j < CHB; ++j) {
    const int ci = tid + 256 * j, row = ci >> 2, cc = ci & 3;
    bS[j] = Bt + (size_t)(col0 + row) * K + ((cc ^ ((row >> 1) & 3)) * 8);
  }
  const int ldsOff = wave * 512;   // u16: 64 lanes x 8 u16 per gld_lds call

  auto stage = [&](int t, int buf) {
    const int ko = t * BK;
    #pragma unroll
    for (int j = 0; j < CHA; ++j)
      GLD_LDS16(aS[j] + ko, &sA[buf][ldsOff + j * 2048]);
    #pragma unroll
    for (int j = 0; j < CHB; ++j)
      GLD_LDS16(bS[j] + ko, &sB[buf][ldsOff + j * 2048]);
  };

  auto wait_stage1 = [&]() {   // one stage (CHA+CHB loads) still in flight
    if constexpr (CHB == 4) asm volatile("s_waitcnt vmcnt(6)" ::: "memory");
    else                    asm volatile("s_waitcnt vmcnt(5)" ::: "memory");
  };

  const int wrow = (wave >> 1) * 64;         // 2 waves along M
  const int wcol = (wave & 1) * (BN >> 1);   // 2 waves along N
  f32x4 acc[4][NF] = {};

  const int NT = K / BK;

  stage(0, 0); stage(1, 1);
  wait_stage1();                   // tile 0 resident
  __builtin_amdgcn_s_barrier();
  __builtin_amdgcn_sched_barrier(0);

  for (int t = 0; t < NT; ++t) {
    const u16* As = sA[t % 3];
    const u16* Bs = sB[t % 3];
    bf16x8 af[4], bf[NF];
    #pragma unroll
    for (int m = 0; m < 4; ++m) {
      const int lr = wrow + m * 16 + r16;
      af[m] = *(const bf16x8*)&As[lr * 32 + ((g ^ ((lr >> 1) & 3)) * 8)];
    }
    #pragma unroll
    for (int n = 0; n < NF; ++n) {
      const int lr = wcol + n * 16 + r16;
      bf[n] = *(const bf16x8*)&Bs[lr * 32 + ((g ^ ((lr >> 1) & 3)) * 8)];
    }
    if (t + 2 < NT) stage(t + 2, (t + 2) % 3);

    __builtin_amdgcn_s_setprio(1);
    #pragma unroll
    for (int m = 0; m < 4; ++m)
      #pragma unroll
      for (int n = 0; n < NF; ++n)
        acc[m][n] = __builtin_amdgcn_mfma_f32_16x16x32_bf16(af[m], bf[n], acc[m][n], 0, 0, 0);
    __builtin_amdgcn_s_setprio(0);

    if (t + 1 < NT) {
      if (t + 2 < NT) wait_stage1();
      else            asm volatile("s_waitcnt vmcnt(0)" ::: "memory");
      __builtin_amdgcn_s_barrier();
      __builtin_amdgcn_sched_barrier(0);
    }
  }

  #pragma unroll
  for (int m = 0; m < 4; ++m) {
    #pragma unroll
    for (int n = 0; n < NF; ++n) {
      const int col = col0 + wcol + n * 16 + r16;
      const float bv = bias[col];
      const float sc = (QSCALE && col < 1024) ? 0.04508422003f : 1.f;
      const int rowb = row0 + wrow + m * 16 + g * 4;
      #pragma unroll
      for (int r = 0; r < 4; ++r) {
        float v = acc[m][n][r] + bv;
        if (RELU) v = fmaxf(v, 0.f);
        if (QSCALE) v *= sc;
        outp[(size_t)(rowb + r) * N + col] = f2bf(v);
      }
    }
  }
}

// ---------------- 256x256 bf16 NT GEMM, 8 waves, per-wave 128x64 -----------
// r12-proven counted ring: depth 4, prefetch distance 2, boundary vmcnt(4).
// (Phase-split experiments r2/r3 both regressed -10/-13 us: this loop already
// has counted vmcnt (T4); added phase barriers are pure overhead. Keep.)
// RAW=1: split-K over gridDim.y, raw f32 partials (FFN2 only).
//   y==0 -> raw acc to outp; y==1 -> acc + bias + bf16 residual to outp_b (f32).
template<int RELU, int RAW, int QSCALE>
__global__ __launch_bounds__(512, 2)
void gemm_256(const u16* __restrict__ A,
              const u16* __restrict__ Bt,
              const float* __restrict__ bias,
              const u16* __restrict__ resb,
              void* __restrict__ outp,
              void* __restrict__ outp_b,
              int M, int N, int K) {
  constexpr int BK = 32;
  __shared__ u16 sA[4][256 * BK];   // 64 KB
  __shared__ u16 sB[4][256 * BK];   // 64 KB

  const int tid = threadIdx.x;
  const int wave = tid >> 6, lane = tid & 63;
  const int g = lane >> 4, r16 = lane & 15;

  const int nbx = N >> 8;
  const int nwg = gridDim.x;
  const int bid = blockIdx.x;
  const int swz = ((bid & 7) * (nwg >> 3)) + (bid >> 3);
  const int bx = swz % nbx, by = swz / nbx;
  const int row0 = by << 8, col0 = bx << 8;

  const int kspan = RAW ? (K >> 1) : K;
  const int kbase = RAW ? ((int)blockIdx.y * kspan) : 0;

  const u16* aS[2];
  const u16* bS[2];
  #pragma unroll
  for (int j = 0; j < 2; ++j) {
    const int ci = tid + 512 * j, row = ci >> 2, cc = ci & 3;
    aS[j] = A  + (size_t)(row0 + row) * K + ((cc ^ ((row >> 1) & 3)) * 8) + kbase;
    bS[j] = Bt + (size_t)(col0 + row) * K + ((cc ^ ((row >> 1) & 3)) * 8) + kbase;
  }
  const int ldsOff = wave * 512;

  auto stage = [&](int t, int buf) {
    const int ko = t * BK;
    #pragma unroll
    for (int j = 0; j < 2; ++j)
      GLD_LDS16(aS[j] + ko, &sA[buf][ldsOff + j * 4096]);
    #pragma unroll
    for (int j = 0; j < 2; ++j)
      GLD_LDS16(bS[j] + ko, &sB[buf][ldsOff + j * 4096]);
  };

  const int wrow = (wave >> 2) * 128;
  const int wcol = (wave & 3) * 64;
  f32x4 acc[8][4] = {};

  const int NT = kspan / BK;

  stage(0, 0); stage(1, 1);
  asm volatile("s_waitcnt vmcnt(4)" ::: "memory");
  __builtin_amdgcn_s_barrier();
  __builtin_amdgcn_sched_barrier(0);

  for (int t = 0; t < NT; ++t) {
    const u16* As = sA[t & 3];
    const u16* Bs = sB[t & 3];
    bf16x8 af[8], bf[4];
    #pragma unroll
    for (int m = 0; m < 8; ++m) {
      const int lr = wrow + m * 16 + r16;
      af[m] = *(const bf16x8*)&As[lr * 32 + ((g ^ ((lr >> 1) & 3)) * 8)];
    }
    #pragma unroll
    for (int n = 0; n < 4; ++n) {
      const int lr = wcol + n * 16 + r16;
      bf[n] = *(const bf16x8*)&Bs[lr * 32 + ((g ^ ((lr >> 1) & 3)) * 8)];
    }
    if (t + 2 < NT) stage(t + 2, (t + 2) & 3);

    __builtin_amdgcn_s_setprio(1);
    #pragma unroll
    for (int m = 0; m < 8; ++m)
      #pragma unroll
      for (int n = 0; n < 4; ++n)
        acc[m][n] = __builtin_amdgcn_mfma_f32_16x16x32_bf16(af[m], bf[n], acc[m][n], 0, 0, 0);
    __builtin_amdgcn_s_setprio(0);

    if (t + 1 < NT) {
      if (t + 2 < NT) asm volatile("s_waitcnt vmcnt(4)" ::: "memory");
      else            asm volatile("s_waitcnt vmcnt(0)" ::: "memory");
      __builtin_amdgcn_s_barrier();
      __builtin_amdgcn_sched_barrier(0);
    }
  }

  if constexpr (RAW) {
    if (blockIdx.y) {
      // final split: fuse bias + bf16 residual, write f32
      float* po = (float*)outp_b;
      #pragma unroll
      for (int m = 0; m < 8; ++m) {
        #pragma unroll
        for (int n = 0; n < 4; ++n) {
          const int col = col0 + wcol + n * 16 + r16;
          const float bv = bias[col];
          const int rowb = row0 + wrow + m * 16 + g * 4;
          #pragma unroll
          for (int r = 0; r < 4; ++r) {
            const size_t idx = (size_t)(rowb + r) * N + col;
            po[idx] = acc[m][n][r] + bv + bf2f(resb[idx]);
          }
        }
      }
    } else {
      float* po = (float*)outp;
      #pragma unroll
      for (int m = 0; m < 8; ++m) {
        #pragma unroll
        for (int n = 0; n < 4; ++n) {
          const int col = col0 + wcol + n * 16 + r16;
          const int rowb = row0 + wrow + m * 16 + g * 4;
          #pragma unroll
          for (int r = 0; r < 4; ++r)
            po[(size_t)(rowb + r) * N + col] = acc[m][n][r];
        }
      }
    }
  } else {
    u16* po = (u16*)outp;
    #pragma unroll
    for (int m = 0; m < 8; ++m) {
      #pragma unroll
      for (int n = 0; n < 4; ++n) {
        const int col = col0 + wcol + n * 16 + r16;
        const float bv = bias[col];
        const float sc = (QSCALE && col < 1024) ? 0.04508422003f : 1.f;
        const int rowb = row0 + wrow + m * 16 + g * 4;
        #pragma unroll
        for (int r = 0; r < 4; ++r) {
          float v = acc[m][n][r] + bv;
          if (RELU) v = fmaxf(v, 0.f);
          if (QSCALE) v *= sc;
          po[(size_t)(rowb + r) * N + col] = f2bf(v);
        }
      }
    }
  }
}

// ---------------- FFN2 split-K reduce: out += pA (bias/res fused in gemm) --
__global__ __launch_bounds__(256) void ffn2_reduce(const float* __restrict__ pA,
                                                   float* __restrict__ out) {
  size_t i = ((size_t)blockIdx.x * 256 + threadIdx.x) * 4;
  float4 a = *(const float4*)(pA + i);
  float4 o = *(const float4*)(out + i);
  float4 v;
  v.x = a.x + o.x;
  v.y = a.y + o.y;
  v.z = a.z + o.z;
  v.w = a.w + o.w;
  *(float4*)(out + i) = v;
}

// ---------------- bf16 NT GEMM, pipelined BMxBN tile (narrow N) ------------
template<int BM, int BN, int THREADS, int OUT_F32, int RELU, int RES>
__global__ __launch_bounds__(THREADS, 3)
void gemm_pipe(const u16* __restrict__ A,
               const u16* __restrict__ Bt,
               const float* __restrict__ bias,
               const float* __restrict__ res,
               void* __restrict__ outp,
               int M, int N, int K) {
  constexpr int BK  = 32;
  constexpr int CHA = (BM * 4) / THREADS;
  constexpr int CHB = (BN * 4) / THREADS;
  constexpr int CH  = CHA + CHB;

  __shared__ u16 sA[3][BM * BK];
  __shared__ u16 sB[3][BN * BK];

  const int tid = threadIdx.x;
  const int wave = tid >> 6, lane = tid & 63;
  const int g = lane >> 4, r16 = lane & 15;

  const int nbx = N / BN;
  const int nwg = gridDim.x;
  const int bid = blockIdx.x;
  const int swz = ((bid & 7) * (nwg >> 3)) + (bid >> 3);
  const int bx = swz % nbx, by = swz / nbx;
  const int row0 = by * BM, col0 = bx * BN;

  const u16* aS[CHA];
  const u16* bS[CHB];
  #pragma unroll
  for (int j = 0; j < CHA; ++j) {
    const int ci = tid + THREADS * j, row = ci >> 2, cc = ci & 3;
    aS[j] = A + (size_t)(row0 + row) * K + ((cc ^ ((row >> 1) & 3)) * 8);
  }
  #pragma unroll
  for (int j = 0; j < CHB; ++j) {
    const int ci = tid + THREADS * j, row = ci >> 2, cc = ci & 3;
    bS[j] = Bt + (size_t)(col0 + row) * K + ((cc ^ ((row >> 1) & 3)) * 8);
  }
  const int ldsOff = wave * 512;

  auto stage = [&](int t, int buf) {
    const int ko = t * BK;
    #pragma unroll
    for (int j = 0; j < CHA; ++j)
      GLD_LDS16(aS[j] + ko, &sA[buf][ldsOff + j * (THREADS * 8)]);
    #pragma unroll
    for (int j = 0; j < CHB; ++j)
      GLD_LDS16(bS[j] + ko, &sB[buf][ldsOff + j * (THREADS * 8)]);
  };

  const int wrow = (wave >> 1) * 64;
  const int wcol = (wave & 1) * 64;
  f32x4 acc[4][4] = {};

  const int NT = K / BK;

  stage(0, 0); stage(1, 1);
  if constexpr (CH == 3) asm volatile("s_waitcnt vmcnt(3)" ::: "memory");
  else                   asm volatile("s_waitcnt vmcnt(4)" ::: "memory");
  __builtin_amdgcn_s_barrier();
  __builtin_amdgcn_sched_barrier(0);

  for (int t = 0; t < NT; ++t) {
    if (t + 2 < NT) stage(t + 2, (t + 2) % 3);
    const u16* As = sA[t % 3];
    const u16* Bs = sB[t % 3];
    bf16x8 af[4], bf[4];
    #pragma unroll
    for (int m = 0; m < 4; ++m) {
      const int lr = wrow + m * 16 + r16;
      af[m] = *(const bf16x8*)&As[lr * 32 + ((g ^ ((lr >> 1) & 3)) * 8)];
    }
    #pragma unroll
    for (int n = 0; n < 4; ++n) {
      const int lr = wcol + n * 16 + r16;
      bf[n] = *(const bf16x8*)&Bs[lr * 32 + ((g ^ ((lr >> 1) & 3)) * 8)];
    }
    __builtin_amdgcn_s_setprio(1);
    #pragma unroll
    for (int m = 0; m < 4; ++m)
      #pragma unroll
      for (int n = 0; n < 4; ++n)
        acc[m][n] = __builtin_amdgcn_mfma_f32_16x16x32_bf16(af[m], bf[n], acc[m][n], 0, 0, 0);
    __builtin_amdgcn_s_setprio(0);

    if (t + 1 < NT) {
      if (t + 2 < NT) {
        if constexpr (CH == 3) asm volatile("s_waitcnt vmcnt(3)" ::: "memory");
        else                   asm volatile("s_waitcnt vmcnt(4)" ::: "memory");
      } else {
        asm volatile("s_waitcnt vmcnt(0)" ::: "memory");
      }
      __builtin_amdgcn_s_barrier();
      __builtin_amdgcn_sched_barrier(0);
    }
  }

  #pragma unroll
  for (int m = 0; m < 4; ++m) {
    #pragma unroll
    for (int n = 0; n < 4; ++n) {
      const int col = col0 + wcol + n * 16 + r16;
      const float bv = bias[col];
      const int rowb = row0 + wrow + m * 16 + g * 4;
      #pragma unroll
      for (int r = 0; r < 4; ++r) {
        const size_t idx = (size_t)(rowb + r) * N + col;
        float v = acc[m][n][r] + bv;
        if (RES)  v += res[idx];
        if (RELU) v = fmaxf(v, 0.f);
        if (OUT_F32) ((float*)outp)[idx] = v;
        else         ((u16*)outp)[idx]   = f2bf(v);
      }
    }
  }
}

// ---------------- causal flash attention v9 --------------------------------
// Dual-strip fused tile; raw v_exp_f32 no-max softmax (Q pre-scaled);
// permlane P transport; ones-MFMA row sums.
// v9: 2-deep LDS ring (32 KB) -> 4 blocks/CU, all 1024 blocks co-resident.
__global__ __launch_bounds__(256, 4) void attn_fwd(const u16* __restrict__ qkv,
                                                   const u16* __restrict__ Vt,
                                                   u16* __restrict__ O) {
  __shared__ u16 sK[2][64 * 64];
  __shared__ u16 sV[2][64 * 64];

  const int orig = blockIdx.x;                       // 1024 blocks
  const int work = ((orig & 7) << 7) + (orig >> 3);  // XCD swizzle
  const int i = work & 15;
  const int h = (work >> 4) & 15;
  const int b = work >> 8;
  const int qA = i << 6, qB = (31 - i) << 6;
  const int nA = i + 1,  nB = 32 - i;

  const int tid = threadIdx.x, wave = tid >> 6, lane = tid & 63;
  const int g = lane >> 4, r16 = lane & 15;

  const size_t base = (size_t)b * T_ * 3072 + h * 64;
  const u16* Qp = qkv + base;
  const u16* Kp = qkv + base + 1024;
  const u16* VtP = Vt + (size_t)(b * 16 + h) * 64 * T_;

  const int rowL = lane >> 3;
  const int colL = 8 * ((lane & 7) ^ rowL);
  const u16* kSrc = Kp  + (size_t)(wave * 16 + rowL) * 3072 + colL;
  const u16* vSrc = VtP + (size_t)(wave * 16 + rowL) * T_   + colL;
  u16* kDst0 = &sK[0][(wave * 16 + 0) * 64];
  u16* kDst8 = &sK[0][(wave * 16 + 8) * 64];
  u16* vDst0 = &sV[0][(wave * 16 + 0) * 64];
  u16* vDst8 = &sV[0][(wave * 16 + 8) * 64];

  const int ck0 = (( 0 + g * 16) ^ ((r16 & 7) << 4)) >> 1;
  const int ck1 = ((64 + g * 16) ^ ((r16 & 7) << 4)) >> 1;

  bf16x8 qfA[2], qfB[2];
  #pragma unroll
  for (int kc = 0; kc < 2; ++kc) {
    qfA[kc] = *(const bf16x8*)(Qp + (size_t)(qA + wave * 16 + r16) * 3072 + kc * 32 + g * 8);
    qfB[kc] = *(const bf16x8*)(Qp + (size_t)(qB + wave * 16 + r16) * 3072 + kc * 32 + g * 8);
  }

  f32x4 accA[4] = {}, accB[4] = {};
  f32x4 lA4 = {}, lB4 = {};
  const int qaA = qA + wave * 16 + r16;
  const int qaB = qB + wave * 16 + r16;

  const u32 one2 = 0x3F803F80u;      // bf16 1.0 pair
  const u32x4 onesv = {one2, one2, one2, one2};
  const bf16x8 ONES = __builtin_bit_cast(bf16x8, onesv);

  int sbuf = 0;
  auto stageAdv = [&]() {
    const int o = sbuf * 4096;
    GLD_LDS16(kSrc,            kDst0 + o);
    GLD_LDS16(kSrc + 8 * 3072, kDst8 + o);
    GLD_LDS16(vSrc,            vDst0 + o);
    GLD_LDS16(vSrc + 8 * T_,   vDst8 + o);
    kSrc += 64 * 3072;
    vSrc += 64;
    sbuf ^= 1;
  };

  auto qkt = [&](const bf16x8* kf0, const bf16x8* kf1, const bf16x8* qf, f32x4* s) {
    __builtin_amdgcn_s_setprio(1);
    #pragma unroll
    for (int ni = 0; ni < 4; ++ni) {
      f32x4 t = {};
      t = __builtin_amdgcn_mfma_f32_16x16x32_bf16(kf0[ni], qf[0], t, 0, 0, 0);
      t = __builtin_amdgcn_mfma_f32_16x16x32_bf16(kf1[ni], qf[1], t, 0, 0, 0);
      s[ni] = t;
    }
    __builtin_amdgcn_s_setprio(0);
  };

  auto softmax_pack = [&](f32x4* s, bool diag, int q_abs, int kv0, bf16x8* pa) {
    if (diag) {
      #pragma unroll
      for (int ni = 0; ni < 4; ++ni)
        #pragma unroll
        for (int r = 0; r < 4; ++r) {
          const int kv_abs = kv0 + ni * 16 + g * 4 + r;
          if (kv_abs > q_abs) s[ni][r] = -3e38f;
        }
    }
    #pragma unroll
    for (int ni = 0; ni < 4; ++ni)
      #pragma unroll
      for (int r = 0; r < 4; ++r)
        s[ni][r] = fast_exp2(s[ni][r]);

    u32 pk[4][2];
    #pragma unroll
    for (int ni = 0; ni < 4; ++ni)
      #pragma unroll
      for (int h2 = 0; h2 < 2; ++h2)
        asm("v_cvt_pk_bf16_f32 %0, %1, %2"
            : "=v"(pk[ni][h2]) : "v"(s[ni][2 * h2]), "v"(s[ni][2 * h2 + 1]));

    u32 pa32[2][4];
    #pragma unroll
    for (int kc = 0; kc < 2; ++kc)
      #pragma unroll
      for (int h2 = 0; h2 < 2; ++h2) {
        u32 a = pk[2 * kc][h2], bq_ = pk[2 * kc + 1][h2];
        asm("v_permlane32_swap_b32 %0, %1" : "+v"(a), "+v"(bq_));
        asm("v_permlane16_swap_b32 %0, %1" : "+v"(a), "+v"(bq_));
        pa32[kc][h2] = a;
        pa32[kc][2 + h2] = bq_;
      }
    #pragma unroll
    for (int kc = 0; kc < 2; ++kc) {
      u32x4 tmp = {pa32[kc][0], pa32[kc][1], pa32[kc][2], pa32[kc][3]};
      pa[kc] = __builtin_bit_cast(bf16x8, tmp);
    }
  };

  // prologue: tile 0 only (2-deep ring, prefetch distance 1)
  stageAdv();
  asm volatile("s_waitcnt vmcnt(0)" ::: "memory");
  __builtin_amdgcn_s_barrier();
  __builtin_amdgcn_sched_barrier(0);

  int cbuf = 0;
  for (int t = 0; t < nB; ++t) {
    if (t + 1 < nB) stageAdv();
    const u16* Kb = sK[cbuf];
    const u16* Vb = sV[cbuf];
    const int kv0 = t << 6;
    const bool actA = (t < nA);

    bf16x8 kf0[4], kf1[4];
    #pragma unroll
    for (int ni = 0; ni < 4; ++ni) {
      kf0[ni] = *(const bf16x8*)&Kb[(ni * 16 + r16) * 64 + ck0];
      kf1[ni] = *(const bf16x8*)&Kb[(ni * 16 + r16) * 64 + ck1];
    }

    f32x4 s[4];
    bf16x8 paB[2], paA[2];

    qkt(kf0, kf1, qfB, s);
    softmax_pack(s, t == nB - 1, qaB, kv0, paB);
    if (actA) {
      qkt(kf0, kf1, qfA, s);
      softmax_pack(s, t == nA - 1, qaA, kv0, paA);
    }

    bf16x8 vf0[4], vf1[4];
    #pragma unroll
    for (int hsb = 0; hsb < 4; ++hsb) {
      vf0[hsb] = *(const bf16x8*)&Vb[(hsb * 16 + r16) * 64 + ck0];
      vf1[hsb] = *(const bf16x8*)&Vb[(hsb * 16 + r16) * 64 + ck1];
    }

    __builtin_amdgcn_s_setprio(1);
    lB4 = __builtin_amdgcn_mfma_f32_16x16x32_bf16(paB[0], ONES, lB4, 0, 0, 0);
    lB4 = __builtin_amdgcn_mfma_f32_16x16x32_bf16(paB[1], ONES, lB4, 0, 0, 0);
    #pragma unroll
    for (int hsb = 0; hsb < 4; ++hsb) {
      accB[hsb] = __builtin_amdgcn_mfma_f32_16x16x32_bf16(paB[0], vf0[hsb], accB[hsb], 0, 0, 0);
      accB[hsb] = __builtin_amdgcn_mfma_f32_16x16x32_bf16(paB[1], vf1[hsb], accB[hsb], 0, 0, 0);
    }
    if (actA) {
      lA4 = __builtin_amdgcn_mfma_f32_16x16x32_bf16(paA[0], ONES, lA4, 0, 0, 0);
      lA4 = __builtin_amdgcn_mfma_f32_16x16x32_bf16(paA[1], ONES, lA4, 0, 0, 0);
      #pragma unroll
      for (int hsb = 0; hsb < 4; ++hsb) {
        accA[hsb] = __builtin_amdgcn_mfma_f32_16x16x32_bf16(paA[0], vf0[hsb], accA[hsb], 0, 0, 0);
        accA[hsb] = __builtin_amdgcn_mfma_f32_16x16x32_bf16(paA[1], vf1[hsb], accA[hsb], 0, 0, 0);
      }
    }
    __builtin_amdgcn_s_setprio(0);

    if (t + 1 < nB) {
      asm volatile("s_waitcnt vmcnt(0)" ::: "memory");
      __builtin_amdgcn_s_barrier();
      __builtin_amdgcn_sched_barrier(0);
    }
    cbuf ^= 1;
  }

  float rlA[4], rlB[4];
  #pragma unroll
  for (int r = 0; r < 4; ++r) {
    rlA[r] = fast_rcp(lA4[r]);
    rlB[r] = fast_rcp(lB4[r]);
  }
  #pragma unroll
  for (int hsb = 0; hsb < 4; ++hsb)
    #pragma unroll
    for (int r = 0; r < 4; ++r) {
      const size_t rowA = (size_t)b * T_ + qA + wave * 16 + g * 4 + r;
      const size_t rowB = (size_t)b * T_ + qB + wave * 16 + g * 4 + r;
      O[rowA * C_ + h * 64 + hsb * 16 + r16] = f2bf(accA[hsb][r] * rlA[r]);
      O[rowB * C_ + h * 64 + hsb * 16 + r16] = f2bf(accB[hsb][r] * rlB[r]);
    }
}

// ---------------------------------------------------------------------------
extern "C" void kernel_launch(void* const* d_in, const int* in_sizes, int n_in,
                              void* d_out, int out_size, void* d_ws, size_t ws_size,
                              hipStream_t stream) {
  const float* x    = (const float*)d_in[0];
  const float* ln1g = (const float*)d_in[1];
  const float* ln1b = (const float*)d_in[2];
  const float* ln2g = (const float*)d_in[3];
  const float* ln2b = (const float*)d_in[4];
  const float* Wq   = (const float*)d_in[5];
  const float* bq   = (const float*)d_in[6];
  const float* Wk   = (const float*)d_in[7];
  const float* bk   = (const float*)d_in[8];
  const float* Wv   = (const float*)d_in[9];
  const float* bv   = (const float*)d_in[10];
  const float* Wo   = (const float*)d_in[11];
  const float* bo   = (const float*)d_in[12];
  const float* W1   = (const float*)d_in[13];
  const float* b1   = (const float*)d_in[14];
  const float* W2   = (const float*)d_in[15];
  const float* b2   = (const float*)d_in[16];

  char* w = (char*)d_ws;
  float* ps    = (float*)(w + 0);
  float* psq   = (float*)(w + 262144);
  float* mean  = (float*)(w + 524288);
  float* rstd  = (float*)(w + 540672);
  float* bqkv  = (float*)(w + 557056);
  u16*   h     = (u16*)  (w + 573440);          // 16 MB (dead after FFN1)
  u16*   wqkvT = (u16*)  (w + 17350656);        // 6 MB
  u16*   woT   = (u16*)  (w + 23642112);        // 2 MB
  u16*   w1T   = (u16*)  (w + 25739264);        // 8 MB
  u16*   w2T   = (u16*)  (w + 34127872);        // 8 MB
  u16*   x1b   = (u16*)  (w + 42516480);        // 16 MB bf16 residual stream
  u16*   Vt    = (u16*)  (w + 59293696);        // 16 MB
  u16*   qkv   = (u16*)  (w + 76070912);        // 48 MB
  u16*   Oo    = (u16*)  (w + 126402560);       // 16 MB
  u16*   u     = qkv;                           // alias
  float* pA    = (float*)(w + 573440);          // 32 MB FFN2 partial (over dead h..w1T)

  // pack weights
  transpose_cast<<<dim3(2, 32, 16), 256, 0, stream>>>(Wq, wqkvT,                     64,   1024, (size_t)C_ * 64, (size_t)64 * 1024);
  transpose_cast<<<dim3(2, 32, 16), 256, 0, stream>>>(Wk, wqkvT + (size_t)1024*1024, 64,   1024, (size_t)C_ * 64, (size_t)64 * 1024);
  transpose_cast<<<dim3(2, 32, 16), 256, 0, stream>>>(Wv, wqkvT + (size_t)2048*1024, 64,   1024, (size_t)C_ * 64, (size_t)64 * 1024);
  transpose_cast<<<dim3(32, 32, 1), 256, 0, stream>>>(Wo, woT, 1024, 1024, 0, 0);
  transpose_cast<<<dim3(128, 32, 1), 256, 0, stream>>>(W1, w1T, 4096, 1024, 0, 0);
  transpose_cast<<<dim3(32, 128, 1), 256, 0, stream>>>(W2, w2T, 1024, 4096, 0, 0);
  concat_bias<<<12, 256, 0, stream>>>(bq, bk, bv, bqkv);

  // LN1 -> h (bf16)
  ln_partial<<<dim3(16, 16), 256, 0, stream>>>(x, ps, psq);
  ln_final<<<16, 256, 0, stream>>>(ps, psq, mean, rstd);
  ln_norm<<<8192, 256, 0, stream>>>(x, mean, rstd, ln1g, ln1b, h);

  // QKV projection (Q cols pre-scaled): BN=192 -> 64x16 = 1024 blocks,
  // 2/CU, exactly 2 clean rounds (was 768 = 1.5 rounds, half-idle tail)
  gemm_128t<192, 0, 1><<<1024, 256, 0, stream>>>(h, wqkvT, bqkv, qkv, BT_, 3072, 1024);

  // V transpose for attention
  v_transpose<<<dim3(T_ / 32, 2, B_ * H_), 256, 0, stream>>>(qkv, Vt);

  // attention (mirror-paired q-tiles, dual-strip fused, all blocks resident)
  attn_fwd<<<1024, 256, 0, stream>>>(qkv, Vt, Oo);

  // output projection + residual -> x1b (bf16): 512 blocks
  gemm_pipe<128, 128, 256, 0, 0, 1><<<512, 256, 0, stream>>>(Oo, woT, bo, x, x1b, BT_, 1024, 1024);

  // LN2 -> h (from bf16 residual stream)
  ln_partial_bf<<<dim3(16, 16), 256, 0, stream>>>(x1b, ps, psq);
  ln_final<<<16, 256, 0, stream>>>(ps, psq, mean, rstd);
  ln_norm_bf<<<8192, 256, 0, stream>>>(x1b, mean, rstd, ln2g, ln2b, h);

  // FFN1 (M=8192, N=4096): proven 128x256 ring, 1024 blocks, 2 clean rounds
  gemm_128t<256, 1, 0><<<1024, 256, 0, stream>>>(h, w1T, b1, u, BT_, 4096, 1024);
  // FFN2 split-K=2 (unphased counted ring): y=0 -> pA raw, y=1 -> d_out fused
  gemm_256<0, 1, 0><<<dim3(128, 2), 512, 0, stream>>>(u, w2T, b2, x1b, pA, d_out, BT_, 1024, 4096);
  // reduce: d_out += pA
  ffn2_reduce<<<8192, 256, 0, stream>>>(pA, (float*)d_out);
}

// Round 5
// 382.132 us; speedup vs baseline: 1.0671x; 1.0294x over previous
//
#include <hip/hip_runtime.h>

#define B_   4
#define T_   2048
#define C_   1024
#define H_   16
#define HS_  64
#define BT_  (B_*T_)
#define EPS_ 1e-5f

typedef unsigned short u16;
typedef unsigned int   u32;
typedef __attribute__((ext_vector_type(8))) __bf16 bf16x8;
typedef __attribute__((ext_vector_type(4))) float  f32x4;
typedef __attribute__((ext_vector_type(8))) u16    u16x8;
typedef __attribute__((ext_vector_type(4))) u16    u16x4;
typedef __attribute__((ext_vector_type(4))) u32    u32x4;

__device__ __forceinline__ u16 f2bf(float f) {
  unsigned x = __builtin_bit_cast(unsigned, f);
  x += 0x7fffu + ((x >> 16) & 1u);
  return (u16)(x >> 16);
}
__device__ __forceinline__ float bf2f(u16 v) {
  return __builtin_bit_cast(float, (u32)v << 16);
}

__device__ __forceinline__ float fast_exp2(float x) {
  float y;
  asm("v_exp_f32 %0, %1" : "=v"(y) : "v"(x));
  return y;
}
__device__ __forceinline__ float fast_rcp(float x) {
  float y;
  asm("v_rcp_f32 %0, %1" : "=v"(y) : "v"(x));
  return y;
}

#define GLD_LDS16(src, dst) \
  __builtin_amdgcn_global_load_lds((__attribute__((address_space(1))) void*)(src), \
                                   (__attribute__((address_space(3))) void*)(dst), 16, 0, 0)

// ---------------- LayerNorm over time axis (axis=1, ddof=1) ----------------
__global__ __launch_bounds__(256) void ln_partial(const float* __restrict__ x,
                                                  float* __restrict__ ps,
                                                  float* __restrict__ psq) {
  int col = blockIdx.x * 256 + threadIdx.x;      // 0..B*C-1
  int b = col >> 10, c = col & (C_ - 1);
  int t0 = blockIdx.y * (T_ / 16);
  const float* p = x + (size_t)b * T_ * C_ + (size_t)t0 * C_ + c;
  float s = 0.f, sq = 0.f;
  #pragma unroll 4
  for (int i = 0; i < T_ / 16; ++i) { float v = p[(size_t)i * C_]; s += v; sq += v * v; }
  ps [blockIdx.y * (B_ * C_) + col] = s;
  psq[blockIdx.y * (B_ * C_) + col] = sq;
}

// bf16-input variant (x1 residual stream)
__global__ __launch_bounds__(256) void ln_partial_bf(const u16* __restrict__ x,
                                                     float* __restrict__ ps,
                                                     float* __restrict__ psq) {
  int col = blockIdx.x * 256 + threadIdx.x;
  int b = col >> 10, c = col & (C_ - 1);
  int t0 = blockIdx.y * (T_ / 16);
  const u16* p = x + (size_t)b * T_ * C_ + (size_t)t0 * C_ + c;
  float s = 0.f, sq = 0.f;
  #pragma unroll 4
  for (int i = 0; i < T_ / 16; ++i) { float v = bf2f(p[(size_t)i * C_]); s += v; sq += v * v; }
  ps [blockIdx.y * (B_ * C_) + col] = s;
  psq[blockIdx.y * (B_ * C_) + col] = sq;
}

__global__ __launch_bounds__(256) void ln_final(const float* __restrict__ ps,
                                                const float* __restrict__ psq,
                                                float* __restrict__ mean,
                                                float* __restrict__ rstd) {
  int col = blockIdx.x * 256 + threadIdx.x;
  float s = 0.f, sq = 0.f;
  #pragma unroll
  for (int i = 0; i < 16; ++i) { s += ps[i * (B_ * C_) + col]; sq += psq[i * (B_ * C_) + col]; }
  float m = s * (1.f / T_);
  float var = (sq - (float)T_ * m * m) * (1.f / (T_ - 1));   // ddof=1
  mean[col] = m;
  rstd[col] = rsqrtf(var + EPS_);
}

__global__ __launch_bounds__(256) void ln_norm(const float* __restrict__ x,
                                               const float* __restrict__ mean,
                                               const float* __restrict__ rstd,
                                               const float* __restrict__ gam,
                                               const float* __restrict__ bet,
                                               u16* __restrict__ out) {
  size_t i = ((size_t)blockIdx.x * 256 + threadIdx.x) * 4;
  int c  = (int)(i & (C_ - 1));
  int b  = (int)(i >> 21);
  int bc = (b << 10) + c;
  float4 v = *(const float4*)(x + i);
  float vv[4] = {v.x, v.y, v.z, v.w};
  u16x4 o;
  #pragma unroll
  for (int j = 0; j < 4; ++j)
    o[j] = f2bf(gam[c + j] * (vv[j] - mean[bc + j]) * rstd[bc + j] + bet[c + j]);
  *(u16x4*)(out + i) = o;
}

// bf16-input variant
__global__ __launch_bounds__(256) void ln_norm_bf(const u16* __restrict__ x,
                                                  const float* __restrict__ mean,
                                                  const float* __restrict__ rstd,
                                                  const float* __restrict__ gam,
                                                  const float* __restrict__ bet,
                                                  u16* __restrict__ out) {
  size_t i = ((size_t)blockIdx.x * 256 + threadIdx.x) * 4;
  int c  = (int)(i & (C_ - 1));
  int b  = (int)(i >> 21);
  int bc = (b << 10) + c;
  u16x4 v = *(const u16x4*)(x + i);
  u16x4 o;
  #pragma unroll
  for (int j = 0; j < 4; ++j)
    o[j] = f2bf(gam[c + j] * (bf2f(v[j]) - mean[bc + j]) * rstd[bc + j] + bet[c + j]);
  *(u16x4*)(out + i) = o;
}

// ---------------- weight pack: transpose + cast f32 -> bf16 ----------------
__global__ __launch_bounds__(256) void transpose_cast(const float* __restrict__ in,
                                                      u16* __restrict__ out,
                                                      int cols_in, int ld_out,
                                                      size_t batch_in, size_t batch_out) {
  __shared__ float tile[32][33];
  const float* I = in + (size_t)blockIdx.z * batch_in;
  u16* Ou = out + (size_t)blockIdx.z * batch_out;
  int r0 = blockIdx.y << 5, c0 = blockIdx.x << 5;
  int tx = threadIdx.x & 31, ty = threadIdx.x >> 5;
  #pragma unroll
  for (int rr = 0; rr < 32; rr += 8)
    tile[ty + rr][tx] = I[(size_t)(r0 + ty + rr) * cols_in + c0 + tx];
  __syncthreads();
  #pragma unroll
  for (int rr = 0; rr < 32; rr += 8)
    Ou[(size_t)(c0 + ty + rr) * ld_out + r0 + tx] = f2bf(tile[tx][ty + rr]);
}

__global__ __launch_bounds__(256) void concat_bias(const float* __restrict__ bq,
                                                   const float* __restrict__ bk,
                                                   const float* __restrict__ bv,
                                                   float* __restrict__ out) {
  int i = blockIdx.x * 256 + threadIdx.x;
  float v = (i < 1024) ? bq[i] : (i < 2048 ? bk[i - 1024] : bv[i - 2048]);
  out[i] = v;
}

// ---------------- V transpose: qkv V block -> Vt[bh][hs][T] bf16 -----------
__global__ __launch_bounds__(256) void v_transpose(const u16* __restrict__ qkv,
                                                   u16* __restrict__ Vt) {
  __shared__ u16 tile[32][33];
  int bh = blockIdx.z; int b = bh >> 4, h = bh & 15;
  int t0 = blockIdx.x << 5, hs0 = blockIdx.y << 5;
  int tx = threadIdx.x & 31, ty = threadIdx.x >> 5;
  const u16* src = qkv + (size_t)(b * T_ + t0) * 3072 + 2048 + h * 64 + hs0;
  #pragma unroll
  for (int rr = 0; rr < 32; rr += 8)
    tile[ty + rr][tx] = src[(size_t)(ty + rr) * 3072 + tx];
  __syncthreads();
  u16* dst = Vt + ((size_t)bh * 64 + hs0) * T_ + t0;
  #pragma unroll
  for (int rr = 0; rr < 32; rr += 8)
    dst[(size_t)(ty + rr) * T_ + tx] = tile[tx][ty + rr];
}

// ---------------- 128xBN bf16 NT GEMM, 4 waves, per-wave 64x(BN/2) ---------
// r12-proven counted ring: depth 3, prefetch distance 2, boundary
// vmcnt(2+CHB) = one stage (CHA+CHB loads) in flight. Conflict-free XOR
// chunk swizzle. BN=256: the proven 881 TF FFN1 config (LDS 72 KB, 2/CU).
// BN=192: QKV config -> grid 64x16 = 1024 blocks = 2 CLEAN rounds at 2/CU.
template<int BN, int RELU, int QSCALE>
__global__ __launch_bounds__(256, 2)
void gemm_128t(const u16* __restrict__ A,
               const u16* __restrict__ Bt,
               const float* __restrict__ bias,
               u16* __restrict__ outp,
               int M, int N, int K) {
  constexpr int BK  = 32;
  constexpr int CHA = 2;            // 128*4/256
  constexpr int CHB = BN / 64;      // BN*4/256
  constexpr int NF  = BN / 32;      // per-wave N fragments

  __shared__ u16 sA[3][128 * BK];
  __shared__ u16 sB[3][BN * BK];

  const int tid = threadIdx.x;
  const int wave = tid >> 6, lane = tid & 63;
  const int g = lane >> 4, r16 = lane & 15;

  const int nbx = N / BN;
  const int nwg = gridDim.x;
  const int bid = blockIdx.x;
  const int swz = ((bid & 7) * (nwg >> 3)) + (bid >> 3);
  const int bx = swz % nbx, by = swz / nbx;
  const int row0 = by << 7, col0 = bx * BN;

  // staging: chunk ci -> (row = ci>>2, cc = ci&3); phys chunk cc holds logical
  // chunk cc^((row>>1)&3) (XOR bits disjoint from row parity; 0 conflicts)
  const u16* aS[CHA];
  const u16* bS[CHB];
  #pragma unroll
  for (int j = 0; j < CHA; ++j) {
    const int ci = tid + 256 * j, row = ci >> 2, cc = ci & 3;
    aS[j] = A + (size_t)(row0 + row) * K + ((cc ^ ((row >> 1) & 3)) * 8);
  }
  #pragma unroll
  for (int j = 0; j < CHB; ++j) {
    const int ci = tid + 256 * j, row = ci >> 2, cc = ci & 3;
    bS[j] = Bt + (size_t)(col0 + row) * K + ((cc ^ ((row >> 1) & 3)) * 8);
  }
  const int ldsOff = wave * 512;   // u16: 64 lanes x 8 u16 per gld_lds call

  auto stage = [&](int t, int buf) {
    const int ko = t * BK;
    #pragma unroll
    for (int j = 0; j < CHA; ++j)
      GLD_LDS16(aS[j] + ko, &sA[buf][ldsOff + j * 2048]);
    #pragma unroll
    for (int j = 0; j < CHB; ++j)
      GLD_LDS16(bS[j] + ko, &sB[buf][ldsOff + j * 2048]);
  };

  auto wait_stage1 = [&]() {   // one stage (CHA+CHB loads) still in flight
    if constexpr (CHB == 4) asm volatile("s_waitcnt vmcnt(6)" ::: "memory");
    else                    asm volatile("s_waitcnt vmcnt(5)" ::: "memory");
  };

  const int wrow = (wave >> 1) * 64;         // 2 waves along M
  const int wcol = (wave & 1) * (BN >> 1);   // 2 waves along N
  f32x4 acc[4][NF] = {};

  const int NT = K / BK;

  stage(0, 0); stage(1, 1);
  wait_stage1();                   // tile 0 resident
  __builtin_amdgcn_s_barrier();
  __builtin_amdgcn_sched_barrier(0);

  for (int t = 0; t < NT; ++t) {
    const u16* As = sA[t % 3];
    const u16* Bs = sB[t % 3];
    bf16x8 af[4], bf[NF];
    #pragma unroll
    for (int m = 0; m < 4; ++m) {
      const int lr = wrow + m * 16 + r16;
      af[m] = *(const bf16x8*)&As[lr * 32 + ((g ^ ((lr >> 1) & 3)) * 8)];
    }
    #pragma unroll
    for (int n = 0; n < NF; ++n) {
      const int lr = wcol + n * 16 + r16;
      bf[n] = *(const bf16x8*)&Bs[lr * 32 + ((g ^ ((lr >> 1) & 3)) * 8)];
    }
    if (t + 2 < NT) stage(t + 2, (t + 2) % 3);

    __builtin_amdgcn_s_setprio(1);
    #pragma unroll
    for (int m = 0; m < 4; ++m)
      #pragma unroll
      for (int n = 0; n < NF; ++n)
        acc[m][n] = __builtin_amdgcn_mfma_f32_16x16x32_bf16(af[m], bf[n], acc[m][n], 0, 0, 0);
    __builtin_amdgcn_s_setprio(0);

    if (t + 1 < NT) {
      if (t + 2 < NT) wait_stage1();
      else            asm volatile("s_waitcnt vmcnt(0)" ::: "memory");
      __builtin_amdgcn_s_barrier();
      __builtin_amdgcn_sched_barrier(0);
    }
  }

  #pragma unroll
  for (int m = 0; m < 4; ++m) {
    #pragma unroll
    for (int n = 0; n < NF; ++n) {
      const int col = col0 + wcol + n * 16 + r16;
      const float bv = bias[col];
      const float sc = (QSCALE && col < 1024) ? 0.04508422003f : 1.f;
      const int rowb = row0 + wrow + m * 16 + g * 4;
      #pragma unroll
      for (int r = 0; r < 4; ++r) {
        float v = acc[m][n][r] + bv;
        if (RELU) v = fmaxf(v, 0.f);
        if (QSCALE) v *= sc;
        outp[(size_t)(rowb + r) * N + col] = f2bf(v);
      }
    }
  }
}

// ---------------- 256x256 bf16 NT GEMM, 8 waves, per-wave 128x64 -----------
// r12-proven counted ring: depth 4, prefetch distance 2, boundary vmcnt(4).
// (Phase-split experiments r2/r3 both regressed -10/-13 us: this loop already
// has counted vmcnt (T4); added phase barriers are pure overhead. Keep.)
// RAW=1: split-K over gridDim.y, raw f32 partials (FFN2 only).
//   y==0 -> raw acc to outp; y==1 -> acc + bias + bf16 residual to outp_b (f32).
template<int RELU, int RAW, int QSCALE>
__global__ __launch_bounds__(512, 2)
void gemm_256(const u16* __restrict__ A,
              const u16* __restrict__ Bt,
              const float* __restrict__ bias,
              const u16* __restrict__ resb,
              void* __restrict__ outp,
              void* __restrict__ outp_b,
              int M, int N, int K) {
  constexpr int BK = 32;
  __shared__ u16 sA[4][256 * BK];   // 64 KB
  __shared__ u16 sB[4][256 * BK];   // 64 KB

  const int tid = threadIdx.x;
  const int wave = tid >> 6, lane = tid & 63;
  const int g = lane >> 4, r16 = lane & 15;

  const int nbx = N >> 8;
  const int nwg = gridDim.x;
  const int bid = blockIdx.x;
  const int swz = ((bid & 7) * (nwg >> 3)) + (bid >> 3);
  const int bx = swz % nbx, by = swz / nbx;
  const int row0 = by << 8, col0 = bx << 8;

  const int kspan = RAW ? (K >> 1) : K;
  const int kbase = RAW ? ((int)blockIdx.y * kspan) : 0;

  const u16* aS[2];
  const u16* bS[2];
  #pragma unroll
  for (int j = 0; j < 2; ++j) {
    const int ci = tid + 512 * j, row = ci >> 2, cc = ci & 3;
    aS[j] = A  + (size_t)(row0 + row) * K + ((cc ^ ((row >> 1) & 3)) * 8) + kbase;
    bS[j] = Bt + (size_t)(col0 + row) * K + ((cc ^ ((row >> 1) & 3)) * 8) + kbase;
  }
  const int ldsOff = wave * 512;

  auto stage = [&](int t, int buf) {
    const int ko = t * BK;
    #pragma unroll
    for (int j = 0; j < 2; ++j)
      GLD_LDS16(aS[j] + ko, &sA[buf][ldsOff + j * 4096]);
    #pragma unroll
    for (int j = 0; j < 2; ++j)
      GLD_LDS16(bS[j] + ko, &sB[buf][ldsOff + j * 4096]);
  };

  const int wrow = (wave >> 2) * 128;
  const int wcol = (wave & 3) * 64;
  f32x4 acc[8][4] = {};

  const int NT = kspan / BK;

  stage(0, 0); stage(1, 1);
  asm volatile("s_waitcnt vmcnt(4)" ::: "memory");
  __builtin_amdgcn_s_barrier();
  __builtin_amdgcn_sched_barrier(0);

  for (int t = 0; t < NT; ++t) {
    const u16* As = sA[t & 3];
    const u16* Bs = sB[t & 3];
    bf16x8 af[8], bf[4];
    #pragma unroll
    for (int m = 0; m < 8; ++m) {
      const int lr = wrow + m * 16 + r16;
      af[m] = *(const bf16x8*)&As[lr * 32 + ((g ^ ((lr >> 1) & 3)) * 8)];
    }
    #pragma unroll
    for (int n = 0; n < 4; ++n) {
      const int lr = wcol + n * 16 + r16;
      bf[n] = *(const bf16x8*)&Bs[lr * 32 + ((g ^ ((lr >> 1) & 3)) * 8)];
    }
    if (t + 2 < NT) stage(t + 2, (t + 2) & 3);

    __builtin_amdgcn_s_setprio(1);
    #pragma unroll
    for (int m = 0; m < 8; ++m)
      #pragma unroll
      for (int n = 0; n < 4; ++n)
        acc[m][n] = __builtin_amdgcn_mfma_f32_16x16x32_bf16(af[m], bf[n], acc[m][n], 0, 0, 0);
    __builtin_amdgcn_s_setprio(0);

    if (t + 1 < NT) {
      if (t + 2 < NT) asm volatile("s_waitcnt vmcnt(4)" ::: "memory");
      else            asm volatile("s_waitcnt vmcnt(0)" ::: "memory");
      __builtin_amdgcn_s_barrier();
      __builtin_amdgcn_sched_barrier(0);
    }
  }

  if constexpr (RAW) {
    if (blockIdx.y) {
      // final split: fuse bias + bf16 residual, write f32
      float* po = (float*)outp_b;
      #pragma unroll
      for (int m = 0; m < 8; ++m) {
        #pragma unroll
        for (int n = 0; n < 4; ++n) {
          const int col = col0 + wcol + n * 16 + r16;
          const float bv = bias[col];
          const int rowb = row0 + wrow + m * 16 + g * 4;
          #pragma unroll
          for (int r = 0; r < 4; ++r) {
            const size_t idx = (size_t)(rowb + r) * N + col;
            po[idx] = acc[m][n][r] + bv + bf2f(resb[idx]);
          }
        }
      }
    } else {
      float* po = (float*)outp;
      #pragma unroll
      for (int m = 0; m < 8; ++m) {
        #pragma unroll
        for (int n = 0; n < 4; ++n) {
          const int col = col0 + wcol + n * 16 + r16;
          const int rowb = row0 + wrow + m * 16 + g * 4;
          #pragma unroll
          for (int r = 0; r < 4; ++r)
            po[(size_t)(rowb + r) * N + col] = acc[m][n][r];
        }
      }
    }
  } else {
    u16* po = (u16*)outp;
    #pragma unroll
    for (int m = 0; m < 8; ++m) {
      #pragma unroll
      for (int n = 0; n < 4; ++n) {
        const int col = col0 + wcol + n * 16 + r16;
        const float bv = bias[col];
        const float sc = (QSCALE && col < 1024) ? 0.04508422003f : 1.f;
        const int rowb = row0 + wrow + m * 16 + g * 4;
        #pragma unroll
        for (int r = 0; r < 4; ++r) {
          float v = acc[m][n][r] + bv;
          if (RELU) v = fmaxf(v, 0.f);
          if (QSCALE) v *= sc;
          po[(size_t)(rowb + r) * N + col] = f2bf(v);
        }
      }
    }
  }
}

// ---------------- FFN2 split-K reduce: out += pA (bias/res fused in gemm) --
__global__ __launch_bounds__(256) void ffn2_reduce(const float* __restrict__ pA,
                                                   float* __restrict__ out) {
  size_t i = ((size_t)blockIdx.x * 256 + threadIdx.x) * 4;
  float4 a = *(const float4*)(pA + i);
  float4 o = *(const float4*)(out + i);
  float4 v;
  v.x = a.x + o.x;
  v.y = a.y + o.y;
  v.z = a.z + o.z;
  v.w = a.w + o.w;
  *(float4*)(out + i) = v;
}

// ---------------- bf16 NT GEMM, pipelined BMxBN tile (narrow N) ------------
template<int BM, int BN, int THREADS, int OUT_F32, int RELU, int RES>
__global__ __launch_bounds__(THREADS, 3)
void gemm_pipe(const u16* __restrict__ A,
               const u16* __restrict__ Bt,
               const float* __restrict__ bias,
               const float* __restrict__ res,
               void* __restrict__ outp,
               int M, int N, int K) {
  constexpr int BK  = 32;
  constexpr int CHA = (BM * 4) / THREADS;
  constexpr int CHB = (BN * 4) / THREADS;
  constexpr int CH  = CHA + CHB;

  __shared__ u16 sA[3][BM * BK];
  __shared__ u16 sB[3][BN * BK];

  const int tid = threadIdx.x;
  const int wave = tid >> 6, lane = tid & 63;
  const int g = lane >> 4, r16 = lane & 15;

  const int nbx = N / BN;
  const int nwg = gridDim.x;
  const int bid = blockIdx.x;
  const int swz = ((bid & 7) * (nwg >> 3)) + (bid >> 3);
  const int bx = swz % nbx, by = swz / nbx;
  const int row0 = by * BM, col0 = bx * BN;

  const u16* aS[CHA];
  const u16* bS[CHB];
  #pragma unroll
  for (int j = 0; j < CHA; ++j) {
    const int ci = tid + THREADS * j, row = ci >> 2, cc = ci & 3;
    aS[j] = A + (size_t)(row0 + row) * K + ((cc ^ ((row >> 1) & 3)) * 8);
  }
  #pragma unroll
  for (int j = 0; j < CHB; ++j) {
    const int ci = tid + THREADS * j, row = ci >> 2, cc = ci & 3;
    bS[j] = Bt + (size_t)(col0 + row) * K + ((cc ^ ((row >> 1) & 3)) * 8);
  }
  const int ldsOff = wave * 512;

  auto stage = [&](int t, int buf) {
    const int ko = t * BK;
    #pragma unroll
    for (int j = 0; j < CHA; ++j)
      GLD_LDS16(aS[j] + ko, &sA[buf][ldsOff + j * (THREADS * 8)]);
    #pragma unroll
    for (int j = 0; j < CHB; ++j)
      GLD_LDS16(bS[j] + ko, &sB[buf][ldsOff + j * (THREADS * 8)]);
  };

  const int wrow = (wave >> 1) * 64;
  const int wcol = (wave & 1) * 64;
  f32x4 acc[4][4] = {};

  const int NT = K / BK;

  stage(0, 0); stage(1, 1);
  if constexpr (CH == 3) asm volatile("s_waitcnt vmcnt(3)" ::: "memory");
  else                   asm volatile("s_waitcnt vmcnt(4)" ::: "memory");
  __builtin_amdgcn_s_barrier();
  __builtin_amdgcn_sched_barrier(0);

  for (int t = 0; t < NT; ++t) {
    if (t + 2 < NT) stage(t + 2, (t + 2) % 3);
    const u16* As = sA[t % 3];
    const u16* Bs = sB[t % 3];
    bf16x8 af[4], bf[4];
    #pragma unroll
    for (int m = 0; m < 4; ++m) {
      const int lr = wrow + m * 16 + r16;
      af[m] = *(const bf16x8*)&As[lr * 32 + ((g ^ ((lr >> 1) & 3)) * 8)];
    }
    #pragma unroll
    for (int n = 0; n < 4; ++n) {
      const int lr = wcol + n * 16 + r16;
      bf[n] = *(const bf16x8*)&Bs[lr * 32 + ((g ^ ((lr >> 1) & 3)) * 8)];
    }
    __builtin_amdgcn_s_setprio(1);
    #pragma unroll
    for (int m = 0; m < 4; ++m)
      #pragma unroll
      for (int n = 0; n < 4; ++n)
        acc[m][n] = __builtin_amdgcn_mfma_f32_16x16x32_bf16(af[m], bf[n], acc[m][n], 0, 0, 0);
    __builtin_amdgcn_s_setprio(0);

    if (t + 1 < NT) {
      if (t + 2 < NT) {
        if constexpr (CH == 3) asm volatile("s_waitcnt vmcnt(3)" ::: "memory");
        else                   asm volatile("s_waitcnt vmcnt(4)" ::: "memory");
      } else {
        asm volatile("s_waitcnt vmcnt(0)" ::: "memory");
      }
      __builtin_amdgcn_s_barrier();
      __builtin_amdgcn_sched_barrier(0);
    }
  }

  #pragma unroll
  for (int m = 0; m < 4; ++m) {
    #pragma unroll
    for (int n = 0; n < 4; ++n) {
      const int col = col0 + wcol + n * 16 + r16;
      const float bv = bias[col];
      const int rowb = row0 + wrow + m * 16 + g * 4;
      #pragma unroll
      for (int r = 0; r < 4; ++r) {
        const size_t idx = (size_t)(rowb + r) * N + col;
        float v = acc[m][n][r] + bv;
        if (RES)  v += res[idx];
        if (RELU) v = fmaxf(v, 0.f);
        if (OUT_F32) ((float*)outp)[idx] = v;
        else         ((u16*)outp)[idx]   = f2bf(v);
      }
    }
  }
}

// ---------------- causal flash attention v10 -------------------------------
// v10: 32 Q-rows per wave (2x 16-row fragments qp=0,1), 128-row strips,
// 512 blocks. Per-Q-row LDS reads / barriers / boundary drains HALVE vs v9
// (each wave's 16 K/V ds_reads now feed 2x the MFMAs). Mirror-paired strips
// qA=i*128, qB=(15-i)*128 keep per-block MFMA work uniform (nA+nB=34).
// Causal masking applies on the last TWO tiles of each strip (128-row strip
// spans 2 diagonal KV tiles); elementwise kv>q check makes it exact.
// 2-deep ring unchanged. ~230 VGPR -> 2 blocks/CU, all 512 co-resident.
__global__ __launch_bounds__(256, 2) void attn_fwd(const u16* __restrict__ qkv,
                                                   const u16* __restrict__ Vt,
                                                   u16* __restrict__ O) {
  __shared__ u16 sK[2][64 * 64];
  __shared__ u16 sV[2][64 * 64];

  const int orig = blockIdx.x;                       // 512 blocks
  const int work = ((orig & 7) << 6) + (orig >> 3);  // XCD swizzle
  const int i = work & 7;
  const int h = (work >> 3) & 15;
  const int b = work >> 7;
  const int qA = i << 7, qB = (15 - i) << 7;
  const int nA = 2 * i + 2, nB = 32 - 2 * i;

  const int tid = threadIdx.x, wave = tid >> 6, lane = tid & 63;
  const int g = lane >> 4, r16 = lane & 15;

  const size_t base = (size_t)b * T_ * 3072 + h * 64;
  const u16* Qp = qkv + base;
  const u16* Kp = qkv + base + 1024;
  const u16* VtP = Vt + (size_t)(b * 16 + h) * 64 * T_;

  const int rowL = lane >> 3;
  const int colL = 8 * ((lane & 7) ^ rowL);
  const u16* kSrc = Kp  + (size_t)(wave * 16 + rowL) * 3072 + colL;
  const u16* vSrc = VtP + (size_t)(wave * 16 + rowL) * T_   + colL;
  u16* kDst0 = &sK[0][(wave * 16 + 0) * 64];
  u16* kDst8 = &sK[0][(wave * 16 + 8) * 64];
  u16* vDst0 = &sV[0][(wave * 16 + 0) * 64];
  u16* vDst8 = &sV[0][(wave * 16 + 8) * 64];

  const int ck0 = (( 0 + g * 16) ^ ((r16 & 7) << 4)) >> 1;
  const int ck1 = ((64 + g * 16) ^ ((r16 & 7) << 4)) >> 1;

  bf16x8 qfA[2][2], qfB[2][2];      // [qp][kc]
  #pragma unroll
  for (int qp = 0; qp < 2; ++qp)
    #pragma unroll
    for (int kc = 0; kc < 2; ++kc) {
      qfA[qp][kc] = *(const bf16x8*)(Qp + (size_t)(qA + wave * 32 + qp * 16 + r16) * 3072 + kc * 32 + g * 8);
      qfB[qp][kc] = *(const bf16x8*)(Qp + (size_t)(qB + wave * 32 + qp * 16 + r16) * 3072 + kc * 32 + g * 8);
    }

  f32x4 accA[2][4] = {}, accB[2][4] = {};   // [qp][hsb]
  f32x4 lA[2] = {}, lB[2] = {};
  int qaA[2], qaB[2];
  #pragma unroll
  for (int qp = 0; qp < 2; ++qp) {
    qaA[qp] = qA + wave * 32 + qp * 16 + r16;
    qaB[qp] = qB + wave * 32 + qp * 16 + r16;
  }

  const u32 one2 = 0x3F803F80u;      // bf16 1.0 pair
  const u32x4 onesv = {one2, one2, one2, one2};
  const bf16x8 ONES = __builtin_bit_cast(bf16x8, onesv);

  int sbuf = 0;
  auto stageAdv = [&]() {
    const int o = sbuf * 4096;
    GLD_LDS16(kSrc,            kDst0 + o);
    GLD_LDS16(kSrc + 8 * 3072, kDst8 + o);
    GLD_LDS16(vSrc,            vDst0 + o);
    GLD_LDS16(vSrc + 8 * T_,   vDst8 + o);
    kSrc += 64 * 3072;
    vSrc += 64;
    sbuf ^= 1;
  };

  auto qkt = [&](const bf16x8* kf0, const bf16x8* kf1, const bf16x8* qf, f32x4* s) {
    __builtin_amdgcn_s_setprio(1);
    #pragma unroll
    for (int ni = 0; ni < 4; ++ni) {
      f32x4 t = {};
      t = __builtin_amdgcn_mfma_f32_16x16x32_bf16(kf0[ni], qf[0], t, 0, 0, 0);
      t = __builtin_amdgcn_mfma_f32_16x16x32_bf16(kf1[ni], qf[1], t, 0, 0, 0);
      s[ni] = t;
    }
    __builtin_amdgcn_s_setprio(0);
  };

  auto softmax_pack = [&](f32x4* s, bool diag, int q_abs, int kv0, bf16x8* pa) {
    if (diag) {
      #pragma unroll
      for (int ni = 0; ni < 4; ++ni)
        #pragma unroll
        for (int r = 0; r < 4; ++r) {
          const int kv_abs = kv0 + ni * 16 + g * 4 + r;
          if (kv_abs > q_abs) s[ni][r] = -3e38f;
        }
    }
    #pragma unroll
    for (int ni = 0; ni < 4; ++ni)
      #pragma unroll
      for (int r = 0; r < 4; ++r)
        s[ni][r] = fast_exp2(s[ni][r]);

    u32 pk[4][2];
    #pragma unroll
    for (int ni = 0; ni < 4; ++ni)
      #pragma unroll
      for (int h2 = 0; h2 < 2; ++h2)
        asm("v_cvt_pk_bf16_f32 %0, %1, %2"
            : "=v"(pk[ni][h2]) : "v"(s[ni][2 * h2]), "v"(s[ni][2 * h2 + 1]));

    u32 pa32[2][4];
    #pragma unroll
    for (int kc = 0; kc < 2; ++kc)
      #pragma unroll
      for (int h2 = 0; h2 < 2; ++h2) {
        u32 a = pk[2 * kc][h2], bq_ = pk[2 * kc + 1][h2];
        asm("v_permlane32_swap_b32 %0, %1" : "+v"(a), "+v"(bq_));
        asm("v_permlane16_swap_b32 %0, %1" : "+v"(a), "+v"(bq_));
        pa32[kc][h2] = a;
        pa32[kc][2 + h2] = bq_;
      }
    #pragma unroll
    for (int kc = 0; kc < 2; ++kc) {
      u32x4 tmp = {pa32[kc][0], pa32[kc][1], pa32[kc][2], pa32[kc][3]};
      pa[kc] = __builtin_bit_cast(bf16x8, tmp);
    }
  };

  // prologue: tile 0 only (2-deep ring, prefetch distance 1)
  stageAdv();
  asm volatile("s_waitcnt vmcnt(0)" ::: "memory");
  __builtin_amdgcn_s_barrier();
  __builtin_amdgcn_sched_barrier(0);

  int cbuf = 0;
  for (int t = 0; t < nB; ++t) {
    if (t + 1 < nB) stageAdv();
    const u16* Kb = sK[cbuf];
    const u16* Vb = sV[cbuf];
    const int kv0 = t << 6;
    const bool actA = (t < nA);
    const bool mB = (t + 2 >= nB);
    const bool mA = (t + 2 >= nA);

    bf16x8 kf0[4], kf1[4], vf0[4], vf1[4];
    #pragma unroll
    for (int ni = 0; ni < 4; ++ni) {
      kf0[ni] = *(const bf16x8*)&Kb[(ni * 16 + r16) * 64 + ck0];
      kf1[ni] = *(const bf16x8*)&Kb[(ni * 16 + r16) * 64 + ck1];
      vf0[ni] = *(const bf16x8*)&Vb[(ni * 16 + r16) * 64 + ck0];
      vf1[ni] = *(const bf16x8*)&Vb[(ni * 16 + r16) * 64 + ck1];
    }

    #pragma unroll
    for (int qp = 0; qp < 2; ++qp) {
      f32x4 s[4];
      bf16x8 pa[2];
      qkt(kf0, kf1, qfB[qp], s);
      softmax_pack(s, mB, qaB[qp], kv0, pa);
      __builtin_amdgcn_s_setprio(1);
      lB[qp] = __builtin_amdgcn_mfma_f32_16x16x32_bf16(pa[0], ONES, lB[qp], 0, 0, 0);
      lB[qp] = __builtin_amdgcn_mfma_f32_16x16x32_bf16(pa[1], ONES, lB[qp], 0, 0, 0);
      #pragma unroll
      for (int hsb = 0; hsb < 4; ++hsb) {
        accB[qp][hsb] = __builtin_amdgcn_mfma_f32_16x16x32_bf16(pa[0], vf0[hsb], accB[qp][hsb], 0, 0, 0);
        accB[qp][hsb] = __builtin_amdgcn_mfma_f32_16x16x32_bf16(pa[1], vf1[hsb], accB[qp][hsb], 0, 0, 0);
      }
      __builtin_amdgcn_s_setprio(0);
    }

    if (actA) {
      #pragma unroll
      for (int qp = 0; qp < 2; ++qp) {
        f32x4 s[4];
        bf16x8 pa[2];
        qkt(kf0, kf1, qfA[qp], s);
        softmax_pack(s, mA, qaA[qp], kv0, pa);
        __builtin_amdgcn_s_setprio(1);
        lA[qp] = __builtin_amdgcn_mfma_f32_16x16x32_bf16(pa[0], ONES, lA[qp], 0, 0, 0);
        lA[qp] = __builtin_amdgcn_mfma_f32_16x16x32_bf16(pa[1], ONES, lA[qp], 0, 0, 0);
        #pragma unroll
        for (int hsb = 0; hsb < 4; ++hsb) {
          accA[qp][hsb] = __builtin_amdgcn_mfma_f32_16x16x32_bf16(pa[0], vf0[hsb], accA[qp][hsb], 0, 0, 0);
          accA[qp][hsb] = __builtin_amdgcn_mfma_f32_16x16x32_bf16(pa[1], vf1[hsb], accA[qp][hsb], 0, 0, 0);
        }
        __builtin_amdgcn_s_setprio(0);
      }
    }

    if (t + 1 < nB) {
      asm volatile("s_waitcnt vmcnt(0)" ::: "memory");
      __builtin_amdgcn_s_barrier();
      __builtin_amdgcn_sched_barrier(0);
    }
    cbuf ^= 1;
  }

  #pragma unroll
  for (int qp = 0; qp < 2; ++qp) {
    float rlA[4], rlB[4];
    #pragma unroll
    for (int r = 0; r < 4; ++r) {
      rlA[r] = fast_rcp(lA[qp][r]);
      rlB[r] = fast_rcp(lB[qp][r]);
    }
    #pragma unroll
    for (int hsb = 0; hsb < 4; ++hsb)
      #pragma unroll
      for (int r = 0; r < 4; ++r) {
        const size_t rowA = (size_t)b * T_ + qA + wave * 32 + qp * 16 + g * 4 + r;
        const size_t rowB = (size_t)b * T_ + qB + wave * 32 + qp * 16 + g * 4 + r;
        O[rowA * C_ + h * 64 + hsb * 16 + r16] = f2bf(accA[qp][hsb][r] * rlA[r]);
        O[rowB * C_ + h * 64 + hsb * 16 + r16] = f2bf(accB[qp][hsb][r] * rlB[r]);
      }
  }
}

// ---------------------------------------------------------------------------
extern "C" void kernel_launch(void* const* d_in, const int* in_sizes, int n_in,
                              void* d_out, int out_size, void* d_ws, size_t ws_size,
                              hipStream_t stream) {
  const float* x    = (const float*)d_in[0];
  const float* ln1g = (const float*)d_in[1];
  const float* ln1b = (const float*)d_in[2];
  const float* ln2g = (const float*)d_in[3];
  const float* ln2b = (const float*)d_in[4];
  const float* Wq   = (const float*)d_in[5];
  const float* bq   = (const float*)d_in[6];
  const float* Wk   = (const float*)d_in[7];
  const float* bk   = (const float*)d_in[8];
  const float* Wv   = (const float*)d_in[9];
  const float* bv   = (const float*)d_in[10];
  const float* Wo   = (const float*)d_in[11];
  const float* bo   = (const float*)d_in[12];
  const float* W1   = (const float*)d_in[13];
  const float* b1   = (const float*)d_in[14];
  const float* W2   = (const float*)d_in[15];
  const float* b2   = (const float*)d_in[16];

  char* w = (char*)d_ws;
  float* ps    = (float*)(w + 0);
  float* psq   = (float*)(w + 262144);
  float* mean  = (float*)(w + 524288);
  float* rstd  = (float*)(w + 540672);
  float* bqkv  = (float*)(w + 557056);
  u16*   h     = (u16*)  (w + 573440);          // 16 MB (dead after FFN1)
  u16*   wqkvT = (u16*)  (w + 17350656);        // 6 MB
  u16*   woT   = (u16*)  (w + 23642112);        // 2 MB
  u16*   w1T   = (u16*)  (w + 25739264);        // 8 MB
  u16*   w2T   = (u16*)  (w + 34127872);        // 8 MB
  u16*   x1b   = (u16*)  (w + 42516480);        // 16 MB bf16 residual stream
  u16*   Vt    = (u16*)  (w + 59293696);        // 16 MB
  u16*   qkv   = (u16*)  (w + 76070912);        // 48 MB
  u16*   Oo    = (u16*)  (w + 126402560);       // 16 MB
  u16*   u     = qkv;                           // alias
  float* pA    = (float*)(w + 573440);          // 32 MB FFN2 partial (over dead h..w1T)

  // pack weights
  transpose_cast<<<dim3(2, 32, 16), 256, 0, stream>>>(Wq, wqkvT,                     64,   1024, (size_t)C_ * 64, (size_t)64 * 1024);
  transpose_cast<<<dim3(2, 32, 16), 256, 0, stream>>>(Wk, wqkvT + (size_t)1024*1024, 64,   1024, (size_t)C_ * 64, (size_t)64 * 1024);
  transpose_cast<<<dim3(2, 32, 16), 256, 0, stream>>>(Wv, wqkvT + (size_t)2048*1024, 64,   1024, (size_t)C_ * 64, (size_t)64 * 1024);
  transpose_cast<<<dim3(32, 32, 1), 256, 0, stream>>>(Wo, woT, 1024, 1024, 0, 0);
  transpose_cast<<<dim3(128, 32, 1), 256, 0, stream>>>(W1, w1T, 4096, 1024, 0, 0);
  transpose_cast<<<dim3(32, 128, 1), 256, 0, stream>>>(W2, w2T, 1024, 4096, 0, 0);
  concat_bias<<<12, 256, 0, stream>>>(bq, bk, bv, bqkv);

  // LN1 -> h (bf16)
  ln_partial<<<dim3(16, 16), 256, 0, stream>>>(x, ps, psq);
  ln_final<<<16, 256, 0, stream>>>(ps, psq, mean, rstd);
  ln_norm<<<8192, 256, 0, stream>>>(x, mean, rstd, ln1g, ln1b, h);

  // QKV projection (Q cols pre-scaled): BN=192 -> 64x16 = 1024 blocks,
  // 2/CU, exactly 2 clean rounds
  gemm_128t<192, 0, 1><<<1024, 256, 0, stream>>>(h, wqkvT, bqkv, qkv, BT_, 3072, 1024);

  // V transpose for attention
  v_transpose<<<dim3(T_ / 32, 2, B_ * H_), 256, 0, stream>>>(qkv, Vt);

  // attention v10: 512 blocks, 128-row mirror-paired strips, 32 rows/wave
  attn_fwd<<<512, 256, 0, stream>>>(qkv, Vt, Oo);

  // output projection + residual -> x1b (bf16): 512 blocks
  gemm_pipe<128, 128, 256, 0, 0, 1><<<512, 256, 0, stream>>>(Oo, woT, bo, x, x1b, BT_, 1024, 1024);

  // LN2 -> h (from bf16 residual stream)
  ln_partial_bf<<<dim3(16, 16), 256, 0, stream>>>(x1b, ps, psq);
  ln_final<<<16, 256, 0, stream>>>(ps, psq, mean, rstd);
  ln_norm_bf<<<8192, 256, 0, stream>>>(x1b, mean, rstd, ln2g, ln2b, h);

  // FFN1 (M=8192, N=4096): proven 128x256 ring, 1024 blocks, 2 clean rounds
  gemm_128t<256, 1, 0><<<1024, 256, 0, stream>>>(h, w1T, b1, u, BT_, 4096, 1024);
  // FFN2 split-K=2 (unphased counted ring): y=0 -> pA raw, y=1 -> d_out fused
  gemm_256<0, 1, 0><<<dim3(128, 2), 512, 0, stream>>>(u, w2T, b2, x1b, pA, d_out, BT_, 1024, 4096);
  // reduce: d_out += pA
  ffn2_reduce<<<8192, 256, 0, stream>>>(pA, (float*)d_out);
}

// Round 6
// 365.801 us; speedup vs baseline: 1.1147x; 1.0446x over previous
//
#include <hip/hip_runtime.h>

#define B_   4
#define T_   2048
#define C_   1024
#define H_   16
#define HS_  64
#define BT_  (B_*T_)
#define EPS_ 1e-5f

typedef unsigned short u16;
typedef unsigned int   u32;
typedef __attribute__((ext_vector_type(8))) __bf16 bf16x8;
typedef __attribute__((ext_vector_type(4))) float  f32x4;
typedef __attribute__((ext_vector_type(8))) u16    u16x8;
typedef __attribute__((ext_vector_type(4))) u16    u16x4;
typedef __attribute__((ext_vector_type(4))) u32    u32x4;

__device__ __forceinline__ u16 f2bf(float f) {
  unsigned x = __builtin_bit_cast(unsigned, f);
  x += 0x7fffu + ((x >> 16) & 1u);
  return (u16)(x >> 16);
}
__device__ __forceinline__ float bf2f(u16 v) {
  return __builtin_bit_cast(float, (u32)v << 16);
}

__device__ __forceinline__ float fast_exp2(float x) {
  float y;
  asm("v_exp_f32 %0, %1" : "=v"(y) : "v"(x));
  return y;
}
__device__ __forceinline__ float fast_rcp(float x) {
  float y;
  asm("v_rcp_f32 %0, %1" : "=v"(y) : "v"(x));
  return y;
}

#define GLD_LDS16(src, dst) \
  __builtin_amdgcn_global_load_lds((__attribute__((address_space(1))) void*)(src), \
                                   (__attribute__((address_space(3))) void*)(dst), 16, 0, 0)

// ---------------- LayerNorm over time axis (axis=1, ddof=1) ----------------
__global__ __launch_bounds__(256) void ln_partial(const float* __restrict__ x,
                                                  float* __restrict__ ps,
                                                  float* __restrict__ psq) {
  int col = blockIdx.x * 256 + threadIdx.x;      // 0..B*C-1
  int b = col >> 10, c = col & (C_ - 1);
  int t0 = blockIdx.y * (T_ / 16);
  const float* p = x + (size_t)b * T_ * C_ + (size_t)t0 * C_ + c;
  float s = 0.f, sq = 0.f;
  #pragma unroll 4
  for (int i = 0; i < T_ / 16; ++i) { float v = p[(size_t)i * C_]; s += v; sq += v * v; }
  ps [blockIdx.y * (B_ * C_) + col] = s;
  psq[blockIdx.y * (B_ * C_) + col] = sq;
}

// bf16-input variant (x1 residual stream)
__global__ __launch_bounds__(256) void ln_partial_bf(const u16* __restrict__ x,
                                                     float* __restrict__ ps,
                                                     float* __restrict__ psq) {
  int col = blockIdx.x * 256 + threadIdx.x;
  int b = col >> 10, c = col & (C_ - 1);
  int t0 = blockIdx.y * (T_ / 16);
  const u16* p = x + (size_t)b * T_ * C_ + (size_t)t0 * C_ + c;
  float s = 0.f, sq = 0.f;
  #pragma unroll 4
  for (int i = 0; i < T_ / 16; ++i) { float v = bf2f(p[(size_t)i * C_]); s += v; sq += v * v; }
  ps [blockIdx.y * (B_ * C_) + col] = s;
  psq[blockIdx.y * (B_ * C_) + col] = sq;
}

__global__ __launch_bounds__(256) void ln_final(const float* __restrict__ ps,
                                                const float* __restrict__ psq,
                                                float* __restrict__ mean,
                                                float* __restrict__ rstd) {
  int col = blockIdx.x * 256 + threadIdx.x;
  float s = 0.f, sq = 0.f;
  #pragma unroll
  for (int i = 0; i < 16; ++i) { s += ps[i * (B_ * C_) + col]; sq += psq[i * (B_ * C_) + col]; }
  float m = s * (1.f / T_);
  float var = (sq - (float)T_ * m * m) * (1.f / (T_ - 1));   // ddof=1
  mean[col] = m;
  rstd[col] = rsqrtf(var + EPS_);
}

__global__ __launch_bounds__(256) void ln_norm(const float* __restrict__ x,
                                               const float* __restrict__ mean,
                                               const float* __restrict__ rstd,
                                               const float* __restrict__ gam,
                                               const float* __restrict__ bet,
                                               u16* __restrict__ out) {
  size_t i = ((size_t)blockIdx.x * 256 + threadIdx.x) * 4;
  int c  = (int)(i & (C_ - 1));
  int b  = (int)(i >> 21);
  int bc = (b << 10) + c;
  float4 v = *(const float4*)(x + i);
  float vv[4] = {v.x, v.y, v.z, v.w};
  u16x4 o;
  #pragma unroll
  for (int j = 0; j < 4; ++j)
    o[j] = f2bf(gam[c + j] * (vv[j] - mean[bc + j]) * rstd[bc + j] + bet[c + j]);
  *(u16x4*)(out + i) = o;
}

// bf16-input variant
__global__ __launch_bounds__(256) void ln_norm_bf(const u16* __restrict__ x,
                                                  const float* __restrict__ mean,
                                                  const float* __restrict__ rstd,
                                                  const float* __restrict__ gam,
                                                  const float* __restrict__ bet,
                                                  u16* __restrict__ out) {
  size_t i = ((size_t)blockIdx.x * 256 + threadIdx.x) * 4;
  int c  = (int)(i & (C_ - 1));
  int b  = (int)(i >> 21);
  int bc = (b << 10) + c;
  u16x4 v = *(const u16x4*)(x + i);
  u16x4 o;
  #pragma unroll
  for (int j = 0; j < 4; ++j)
    o[j] = f2bf(gam[c + j] * (bf2f(v[j]) - mean[bc + j]) * rstd[bc + j] + bet[c + j]);
  *(u16x4*)(out + i) = o;
}

// ---------------- fused weight pack: all transposes + bias concat ----------
// Segmented flat grid (block-uniform branches), replaces 7 launches:
//   [0,3072)      Wq/Wk/Wv per-head [1024,64] -> wqkvT [64,1024] (48 z, 2x32 tiles)
//   [3072,4096)   Wo [1024,1024] -> woT, 32x32 tiles
//   [4096,8192)   W1 [1024,4096] -> w1T, 128x32 tiles
//   [8192,12288)  W2 [4096,1024] -> w2T, 32x128 tiles
//   [12288,12300) bias concat bq|bk|bv -> bqkv (12 blocks x 256)
__global__ __launch_bounds__(256) void pack_all(
    const float* __restrict__ Wq, const float* __restrict__ Wk,
    const float* __restrict__ Wv, const float* __restrict__ Wo,
    const float* __restrict__ W1, const float* __restrict__ W2,
    const float* __restrict__ bq, const float* __restrict__ bk,
    const float* __restrict__ bv,
    u16* __restrict__ wqkvT, u16* __restrict__ woT,
    u16* __restrict__ w1T,   u16* __restrict__ w2T,
    float* __restrict__ bqkv) {
  __shared__ float tile[32][33];
  const int bid = blockIdx.x;
  const int tid = threadIdx.x;

  if (bid >= 12288) {                      // bias concat
    int i = (bid - 12288) * 256 + tid;
    float v = (i < 1024) ? bq[i] : (i < 2048 ? bk[i - 1024] : bv[i - 2048]);
    bqkv[i] = v;
    return;
  }

  const float* I; u16* Ou; int cols_in, ld_out, bx, by;
  if (bid < 3072) {
    const int z = bid >> 6, t6 = bid & 63;   // z = w*16+head, 64 tiles each
    bx = t6 & 1; by = t6 >> 1;
    const int wsel = z >> 4, head = z & 15;
    I  = (wsel == 0 ? Wq : (wsel == 1 ? Wk : Wv)) + (size_t)head * (C_ * 64);
    Ou = wqkvT + (size_t)wsel * 1024 * 1024 + (size_t)head * 64 * 1024;
    cols_in = 64; ld_out = 1024;
  } else if (bid < 4096) {
    const int rel = bid - 3072;
    bx = rel & 31; by = rel >> 5;
    I = Wo; Ou = woT; cols_in = 1024; ld_out = 1024;
  } else if (bid < 8192) {
    const int rel = bid - 4096;
    bx = rel & 127; by = rel >> 7;
    I = W1; Ou = w1T; cols_in = 4096; ld_out = 1024;
  } else {
    const int rel = bid - 8192;
    bx = rel & 31; by = rel >> 5;
    I = W2; Ou = w2T; cols_in = 1024; ld_out = 4096;
  }

  const int r0 = by << 5, c0 = bx << 5;
  const int tx = tid & 31, ty = tid >> 5;
  #pragma unroll
  for (int rr = 0; rr < 32; rr += 8)
    tile[ty + rr][tx] = I[(size_t)(r0 + ty + rr) * cols_in + c0 + tx];
  __syncthreads();
  #pragma unroll
  for (int rr = 0; rr < 32; rr += 8)
    Ou[(size_t)(c0 + ty + rr) * ld_out + r0 + tx] = f2bf(tile[tx][ty + rr]);
}

// ---------------- V transpose: qkv V block -> Vt[bh][hs][T] bf16 -----------
__global__ __launch_bounds__(256) void v_transpose(const u16* __restrict__ qkv,
                                                   u16* __restrict__ Vt) {
  __shared__ u16 tile[32][33];
  int bh = blockIdx.z; int b = bh >> 4, h = bh & 15;
  int t0 = blockIdx.x << 5, hs0 = blockIdx.y << 5;
  int tx = threadIdx.x & 31, ty = threadIdx.x >> 5;
  const u16* src = qkv + (size_t)(b * T_ + t0) * 3072 + 2048 + h * 64 + hs0;
  #pragma unroll
  for (int rr = 0; rr < 32; rr += 8)
    tile[ty + rr][tx] = src[(size_t)(ty + rr) * 3072 + tx];
  __syncthreads();
  u16* dst = Vt + ((size_t)bh * 64 + hs0) * T_ + t0;
  #pragma unroll
  for (int rr = 0; rr < 32; rr += 8)
    dst[(size_t)(ty + rr) * T_ + tx] = tile[tx][ty + rr];
}

// ---------------- 128xBN bf16 NT GEMM, 4 waves, per-wave 64x(BN/2) ---------
// r12-proven counted ring: depth 3, prefetch distance 2, boundary
// vmcnt(2+CHB) = one stage (CHA+CHB loads) in flight. Conflict-free XOR
// chunk swizzle. BN=256: proven FFN1 config (72 KB, 2/CU). BN=192: QKV,
// 1024 blocks = 2 clean rounds at 2/CU.
template<int BN, int RELU, int QSCALE>
__global__ __launch_bounds__(256, 2)
void gemm_128t(const u16* __restrict__ A,
               const u16* __restrict__ Bt,
               const float* __restrict__ bias,
               u16* __restrict__ outp,
               int M, int N, int K) {
  constexpr int BK  = 32;
  constexpr int CHA = 2;            // 128*4/256
  constexpr int CHB = BN / 64;      // BN*4/256
  constexpr int NF  = BN / 32;      // per-wave N fragments

  __shared__ u16 sA[3][128 * BK];
  __shared__ u16 sB[3][BN * BK];

  const int tid = threadIdx.x;
  const int wave = tid >> 6, lane = tid & 63;
  const int g = lane >> 4, r16 = lane & 15;

  const int nbx = N / BN;
  const int nwg = gridDim.x;
  const int bid = blockIdx.x;
  const int swz = ((bid & 7) * (nwg >> 3)) + (bid >> 3);
  const int bx = swz % nbx, by = swz / nbx;
  const int row0 = by << 7, col0 = bx * BN;

  const u16* aS[CHA];
  const u16* bS[CHB];
  #pragma unroll
  for (int j = 0; j < CHA; ++j) {
    const int ci = tid + 256 * j, row = ci >> 2, cc = ci & 3;
    aS[j] = A + (size_t)(row0 + row) * K + ((cc ^ ((row >> 1) & 3)) * 8);
  }
  #pragma unroll
  for (int j = 0; j < CHB; ++j) {
    const int ci = tid + 256 * j, row = ci >> 2, cc = ci & 3;
    bS[j] = Bt + (size_t)(col0 + row) * K + ((cc ^ ((row >> 1) & 3)) * 8);
  }
  const int ldsOff = wave * 512;   // u16: 64 lanes x 8 u16 per gld_lds call

  auto stage = [&](int t, int buf) {
    const int ko = t * BK;
    #pragma unroll
    for (int j = 0; j < CHA; ++j)
      GLD_LDS16(aS[j] + ko, &sA[buf][ldsOff + j * 2048]);
    #pragma unroll
    for (int j = 0; j < CHB; ++j)
      GLD_LDS16(bS[j] + ko, &sB[buf][ldsOff + j * 2048]);
  };

  auto wait_stage1 = [&]() {   // one stage (CHA+CHB loads) still in flight
    if constexpr (CHB == 4) asm volatile("s_waitcnt vmcnt(6)" ::: "memory");
    else                    asm volatile("s_waitcnt vmcnt(5)" ::: "memory");
  };

  const int wrow = (wave >> 1) * 64;         // 2 waves along M
  const int wcol = (wave & 1) * (BN >> 1);   // 2 waves along N
  f32x4 acc[4][NF] = {};

  const int NT = K / BK;

  stage(0, 0); stage(1, 1);
  wait_stage1();                   // tile 0 resident
  __builtin_amdgcn_s_barrier();
  __builtin_amdgcn_sched_barrier(0);

  for (int t = 0; t < NT; ++t) {
    const u16* As = sA[t % 3];
    const u16* Bs = sB[t % 3];
    bf16x8 af[4], bf[NF];
    #pragma unroll
    for (int m = 0; m < 4; ++m) {
      const int lr = wrow + m * 16 + r16;
      af[m] = *(const bf16x8*)&As[lr * 32 + ((g ^ ((lr >> 1) & 3)) * 8)];
    }
    #pragma unroll
    for (int n = 0; n < NF; ++n) {
      const int lr = wcol + n * 16 + r16;
      bf[n] = *(const bf16x8*)&Bs[lr * 32 + ((g ^ ((lr >> 1) & 3)) * 8)];
    }
    if (t + 2 < NT) stage(t + 2, (t + 2) % 3);

    __builtin_amdgcn_s_setprio(1);
    #pragma unroll
    for (int m = 0; m < 4; ++m)
      #pragma unroll
      for (int n = 0; n < NF; ++n)
        acc[m][n] = __builtin_amdgcn_mfma_f32_16x16x32_bf16(af[m], bf[n], acc[m][n], 0, 0, 0);
    __builtin_amdgcn_s_setprio(0);

    if (t + 1 < NT) {
      if (t + 2 < NT) wait_stage1();
      else            asm volatile("s_waitcnt vmcnt(0)" ::: "memory");
      __builtin_amdgcn_s_barrier();
      __builtin_amdgcn_sched_barrier(0);
    }
  }

  #pragma unroll
  for (int m = 0; m < 4; ++m) {
    #pragma unroll
    for (int n = 0; n < NF; ++n) {
      const int col = col0 + wcol + n * 16 + r16;
      const float bv = bias[col];
      const float sc = (QSCALE && col < 1024) ? 0.04508422003f : 1.f;
      const int rowb = row0 + wrow + m * 16 + g * 4;
      #pragma unroll
      for (int r = 0; r < 4; ++r) {
        float v = acc[m][n][r] + bv;
        if (RELU) v = fmaxf(v, 0.f);
        if (QSCALE) v *= sc;
        outp[(size_t)(rowb + r) * N + col] = f2bf(v);
      }
    }
  }
}

// ---------------- 256x256 bf16 NT GEMM, 8 waves, per-wave 128x64 -----------
// r12-proven counted ring: depth 4, prefetch distance 2, boundary vmcnt(4).
// RAW=1: split-K over gridDim.y (FFN2 only).
//   y==0 -> bf16 raw partial to outp (half-K dot ~0.3 magnitude; bf16 err
//           ~1e-3 << 0.031 absmax); y==1 -> acc + bias + bf16 residual, f32.
template<int RELU, int RAW, int QSCALE>
__global__ __launch_bounds__(512, 2)
void gemm_256(const u16* __restrict__ A,
              const u16* __restrict__ Bt,
              const float* __restrict__ bias,
              const u16* __restrict__ resb,
              void* __restrict__ outp,
              void* __restrict__ outp_b,
              int M, int N, int K) {
  constexpr int BK = 32;
  __shared__ u16 sA[4][256 * BK];   // 64 KB
  __shared__ u16 sB[4][256 * BK];   // 64 KB

  const int tid = threadIdx.x;
  const int wave = tid >> 6, lane = tid & 63;
  const int g = lane >> 4, r16 = lane & 15;

  const int nbx = N >> 8;
  const int nwg = gridDim.x;
  const int bid = blockIdx.x;
  const int swz = ((bid & 7) * (nwg >> 3)) + (bid >> 3);
  const int bx = swz % nbx, by = swz / nbx;
  const int row0 = by << 8, col0 = bx << 8;

  const int kspan = RAW ? (K >> 1) : K;
  const int kbase = RAW ? ((int)blockIdx.y * kspan) : 0;

  const u16* aS[2];
  const u16* bS[2];
  #pragma unroll
  for (int j = 0; j < 2; ++j) {
    const int ci = tid + 512 * j, row = ci >> 2, cc = ci & 3;
    aS[j] = A  + (size_t)(row0 + row) * K + ((cc ^ ((row >> 1) & 3)) * 8) + kbase;
    bS[j] = Bt + (size_t)(col0 + row) * K + ((cc ^ ((row >> 1) & 3)) * 8) + kbase;
  }
  const int ldsOff = wave * 512;

  auto stage = [&](int t, int buf) {
    const int ko = t * BK;
    #pragma unroll
    for (int j = 0; j < 2; ++j)
      GLD_LDS16(aS[j] + ko, &sA[buf][ldsOff + j * 4096]);
    #pragma unroll
    for (int j = 0; j < 2; ++j)
      GLD_LDS16(bS[j] + ko, &sB[buf][ldsOff + j * 4096]);
  };

  const int wrow = (wave >> 2) * 128;
  const int wcol = (wave & 3) * 64;
  f32x4 acc[8][4] = {};

  const int NT = kspan / BK;

  stage(0, 0); stage(1, 1);
  asm volatile("s_waitcnt vmcnt(4)" ::: "memory");
  __builtin_amdgcn_s_barrier();
  __builtin_amdgcn_sched_barrier(0);

  for (int t = 0; t < NT; ++t) {
    const u16* As = sA[t & 3];
    const u16* Bs = sB[t & 3];
    bf16x8 af[8], bf[4];
    #pragma unroll
    for (int m = 0; m < 8; ++m) {
      const int lr = wrow + m * 16 + r16;
      af[m] = *(const bf16x8*)&As[lr * 32 + ((g ^ ((lr >> 1) & 3)) * 8)];
    }
    #pragma unroll
    for (int n = 0; n < 4; ++n) {
      const int lr = wcol + n * 16 + r16;
      bf[n] = *(const bf16x8*)&Bs[lr * 32 + ((g ^ ((lr >> 1) & 3)) * 8)];
    }
    if (t + 2 < NT) stage(t + 2, (t + 2) & 3);

    __builtin_amdgcn_s_setprio(1);
    #pragma unroll
    for (int m = 0; m < 8; ++m)
      #pragma unroll
      for (int n = 0; n < 4; ++n)
        acc[m][n] = __builtin_amdgcn_mfma_f32_16x16x32_bf16(af[m], bf[n], acc[m][n], 0, 0, 0);
    __builtin_amdgcn_s_setprio(0);

    if (t + 1 < NT) {
      if (t + 2 < NT) asm volatile("s_waitcnt vmcnt(4)" ::: "memory");
      else            asm volatile("s_waitcnt vmcnt(0)" ::: "memory");
      __builtin_amdgcn_s_barrier();
      __builtin_amdgcn_sched_barrier(0);
    }
  }

  if constexpr (RAW) {
    if (blockIdx.y) {
      // final split: fuse bias + bf16 residual, write f32
      float* po = (float*)outp_b;
      #pragma unroll
      for (int m = 0; m < 8; ++m) {
        #pragma unroll
        for (int n = 0; n < 4; ++n) {
          const int col = col0 + wcol + n * 16 + r16;
          const float bv = bias[col];
          const int rowb = row0 + wrow + m * 16 + g * 4;
          #pragma unroll
          for (int r = 0; r < 4; ++r) {
            const size_t idx = (size_t)(rowb + r) * N + col;
            po[idx] = acc[m][n][r] + bv + bf2f(resb[idx]);
          }
        }
      }
    } else {
      u16* po = (u16*)outp;    // bf16 raw partial (traffic halved)
      #pragma unroll
      for (int m = 0; m < 8; ++m) {
        #pragma unroll
        for (int n = 0; n < 4; ++n) {
          const int col = col0 + wcol + n * 16 + r16;
          const int rowb = row0 + wrow + m * 16 + g * 4;
          #pragma unroll
          for (int r = 0; r < 4; ++r)
            po[(size_t)(rowb + r) * N + col] = f2bf(acc[m][n][r]);
        }
      }
    }
  } else {
    u16* po = (u16*)outp;
    #pragma unroll
    for (int m = 0; m < 8; ++m) {
      #pragma unroll
      for (int n = 0; n < 4; ++n) {
        const int col = col0 + wcol + n * 16 + r16;
        const float bv = bias[col];
        const float sc = (QSCALE && col < 1024) ? 0.04508422003f : 1.f;
        const int rowb = row0 + wrow + m * 16 + g * 4;
        #pragma unroll
        for (int r = 0; r < 4; ++r) {
          float v = acc[m][n][r] + bv;
          if (RELU) v = fmaxf(v, 0.f);
          if (QSCALE) v *= sc;
          po[(size_t)(rowb + r) * N + col] = f2bf(v);
        }
      }
    }
  }
}

// ---------------- FFN2 split-K reduce: out += pA(bf16) ---------------------
__global__ __launch_bounds__(256) void ffn2_reduce(const u16* __restrict__ pA,
                                                   float* __restrict__ out) {
  size_t i = ((size_t)blockIdx.x * 256 + threadIdx.x) * 4;
  u16x4 a = *(const u16x4*)(pA + i);
  float4 o = *(const float4*)(out + i);
  float4 v;
  v.x = o.x + bf2f(a[0]);
  v.y = o.y + bf2f(a[1]);
  v.z = o.z + bf2f(a[2]);
  v.w = o.w + bf2f(a[3]);
  *(float4*)(out + i) = v;
}

// ---------------- bf16 NT GEMM, pipelined BMxBN tile (narrow N) ------------
template<int BM, int BN, int THREADS, int OUT_F32, int RELU, int RES>
__global__ __launch_bounds__(THREADS, 3)
void gemm_pipe(const u16* __restrict__ A,
               const u16* __restrict__ Bt,
               const float* __restrict__ bias,
               const float* __restrict__ res,
               void* __restrict__ outp,
               int M, int N, int K) {
  constexpr int BK  = 32;
  constexpr int CHA = (BM * 4) / THREADS;
  constexpr int CHB = (BN * 4) / THREADS;
  constexpr int CH  = CHA + CHB;

  __shared__ u16 sA[3][BM * BK];
  __shared__ u16 sB[3][BN * BK];

  const int tid = threadIdx.x;
  const int wave = tid >> 6, lane = tid & 63;
  const int g = lane >> 4, r16 = lane & 15;

  const int nbx = N / BN;
  const int nwg = gridDim.x;
  const int bid = blockIdx.x;
  const int swz = ((bid & 7) * (nwg >> 3)) + (bid >> 3);
  const int bx = swz % nbx, by = swz / nbx;
  const int row0 = by * BM, col0 = bx * BN;

  const u16* aS[CHA];
  const u16* bS[CHB];
  #pragma unroll
  for (int j = 0; j < CHA; ++j) {
    const int ci = tid + THREADS * j, row = ci >> 2, cc = ci & 3;
    aS[j] = A + (size_t)(row0 + row) * K + ((cc ^ ((row >> 1) & 3)) * 8);
  }
  #pragma unroll
  for (int j = 0; j < CHB; ++j) {
    const int ci = tid + THREADS * j, row = ci >> 2, cc = ci & 3;
    bS[j] = Bt + (size_t)(col0 + row) * K + ((cc ^ ((row >> 1) & 3)) * 8);
  }
  const int ldsOff = wave * 512;

  auto stage = [&](int t, int buf) {
    const int ko = t * BK;
    #pragma unroll
    for (int j = 0; j < CHA; ++j)
      GLD_LDS16(aS[j] + ko, &sA[buf][ldsOff + j * (THREADS * 8)]);
    #pragma unroll
    for (int j = 0; j < CHB; ++j)
      GLD_LDS16(bS[j] + ko, &sB[buf][ldsOff + j * (THREADS * 8)]);
  };

  const int wrow = (wave >> 1) * 64;
  const int wcol = (wave & 1) * 64;
  f32x4 acc[4][4] = {};

  const int NT = K / BK;

  stage(0, 0); stage(1, 1);
  if constexpr (CH == 3) asm volatile("s_waitcnt vmcnt(3)" ::: "memory");
  else                   asm volatile("s_waitcnt vmcnt(4)" ::: "memory");
  __builtin_amdgcn_s_barrier();
  __builtin_amdgcn_sched_barrier(0);

  for (int t = 0; t < NT; ++t) {
    if (t + 2 < NT) stage(t + 2, (t + 2) % 3);
    const u16* As = sA[t % 3];
    const u16* Bs = sB[t % 3];
    bf16x8 af[4], bf[4];
    #pragma unroll
    for (int m = 0; m < 4; ++m) {
      const int lr = wrow + m * 16 + r16;
      af[m] = *(const bf16x8*)&As[lr * 32 + ((g ^ ((lr >> 1) & 3)) * 8)];
    }
    #pragma unroll
    for (int n = 0; n < 4; ++n) {
      const int lr = wcol + n * 16 + r16;
      bf[n] = *(const bf16x8*)&Bs[lr * 32 + ((g ^ ((lr >> 1) & 3)) * 8)];
    }
    __builtin_amdgcn_s_setprio(1);
    #pragma unroll
    for (int m = 0; m < 4; ++m)
      #pragma unroll
      for (int n = 0; n < 4; ++n)
        acc[m][n] = __builtin_amdgcn_mfma_f32_16x16x32_bf16(af[m], bf[n], acc[m][n], 0, 0, 0);
    __builtin_amdgcn_s_setprio(0);

    if (t + 1 < NT) {
      if (t + 2 < NT) {
        if constexpr (CH == 3) asm volatile("s_waitcnt vmcnt(3)" ::: "memory");
        else                   asm volatile("s_waitcnt vmcnt(4)" ::: "memory");
      } else {
        asm volatile("s_waitcnt vmcnt(0)" ::: "memory");
      }
      __builtin_amdgcn_s_barrier();
      __builtin_amdgcn_sched_barrier(0);
    }
  }

  #pragma unroll
  for (int m = 0; m < 4; ++m) {
    #pragma unroll
    for (int n = 0; n < 4; ++n) {
      const int col = col0 + wcol + n * 16 + r16;
      const float bv = bias[col];
      const int rowb = row0 + wrow + m * 16 + g * 4;
      #pragma unroll
      for (int r = 0; r < 4; ++r) {
        const size_t idx = (size_t)(rowb + r) * N + col;
        float v = acc[m][n][r] + bv;
        if (RES)  v += res[idx];
        if (RELU) v = fmaxf(v, 0.f);
        if (OUT_F32) ((float*)outp)[idx] = v;
        else         ((u16*)outp)[idx]   = f2bf(v);
      }
    }
  }
}

// ---------------- causal flash attention v10 -------------------------------
// 32 Q-rows per wave (2x 16-row fragments), 128-row mirror-paired strips,
// 512 blocks, 2-deep ring. Proven r5: -11 us vs v9.
__global__ __launch_bounds__(256, 2) void attn_fwd(const u16* __restrict__ qkv,
                                                   const u16* __restrict__ Vt,
                                                   u16* __restrict__ O) {
  __shared__ u16 sK[2][64 * 64];
  __shared__ u16 sV[2][64 * 64];

  const int orig = blockIdx.x;                       // 512 blocks
  const int work = ((orig & 7) << 6) + (orig >> 3);  // XCD swizzle
  const int i = work & 7;
  const int h = (work >> 3) & 15;
  const int b = work >> 7;
  const int qA = i << 7, qB = (15 - i) << 7;
  const int nA = 2 * i + 2, nB = 32 - 2 * i;

  const int tid = threadIdx.x, wave = tid >> 6, lane = tid & 63;
  const int g = lane >> 4, r16 = lane & 15;

  const size_t base = (size_t)b * T_ * 3072 + h * 64;
  const u16* Qp = qkv + base;
  const u16* Kp = qkv + base + 1024;
  const u16* VtP = Vt + (size_t)(b * 16 + h) * 64 * T_;

  const int rowL = lane >> 3;
  const int colL = 8 * ((lane & 7) ^ rowL);
  const u16* kSrc = Kp  + (size_t)(wave * 16 + rowL) * 3072 + colL;
  const u16* vSrc = VtP + (size_t)(wave * 16 + rowL) * T_   + colL;
  u16* kDst0 = &sK[0][(wave * 16 + 0) * 64];
  u16* kDst8 = &sK[0][(wave * 16 + 8) * 64];
  u16* vDst0 = &sV[0][(wave * 16 + 0) * 64];
  u16* vDst8 = &sV[0][(wave * 16 + 8) * 64];

  const int ck0 = (( 0 + g * 16) ^ ((r16 & 7) << 4)) >> 1;
  const int ck1 = ((64 + g * 16) ^ ((r16 & 7) << 4)) >> 1;

  bf16x8 qfA[2][2], qfB[2][2];      // [qp][kc]
  #pragma unroll
  for (int qp = 0; qp < 2; ++qp)
    #pragma unroll
    for (int kc = 0; kc < 2; ++kc) {
      qfA[qp][kc] = *(const bf16x8*)(Qp + (size_t)(qA + wave * 32 + qp * 16 + r16) * 3072 + kc * 32 + g * 8);
      qfB[qp][kc] = *(const bf16x8*)(Qp + (size_t)(qB + wave * 32 + qp * 16 + r16) * 3072 + kc * 32 + g * 8);
    }

  f32x4 accA[2][4] = {}, accB[2][4] = {};   // [qp][hsb]
  f32x4 lA[2] = {}, lB[2] = {};
  int qaA[2], qaB[2];
  #pragma unroll
  for (int qp = 0; qp < 2; ++qp) {
    qaA[qp] = qA + wave * 32 + qp * 16 + r16;
    qaB[qp] = qB + wave * 32 + qp * 16 + r16;
  }

  const u32 one2 = 0x3F803F80u;      // bf16 1.0 pair
  const u32x4 onesv = {one2, one2, one2, one2};
  const bf16x8 ONES = __builtin_bit_cast(bf16x8, onesv);

  int sbuf = 0;
  auto stageAdv = [&]() {
    const int o = sbuf * 4096;
    GLD_LDS16(kSrc,            kDst0 + o);
    GLD_LDS16(kSrc + 8 * 3072, kDst8 + o);
    GLD_LDS16(vSrc,            vDst0 + o);
    GLD_LDS16(vSrc + 8 * T_,   vDst8 + o);
    kSrc += 64 * 3072;
    vSrc += 64;
    sbuf ^= 1;
  };

  auto qkt = [&](const bf16x8* kf0, const bf16x8* kf1, const bf16x8* qf, f32x4* s) {
    __builtin_amdgcn_s_setprio(1);
    #pragma unroll
    for (int ni = 0; ni < 4; ++ni) {
      f32x4 t = {};
      t = __builtin_amdgcn_mfma_f32_16x16x32_bf16(kf0[ni], qf[0], t, 0, 0, 0);
      t = __builtin_amdgcn_mfma_f32_16x16x32_bf16(kf1[ni], qf[1], t, 0, 0, 0);
      s[ni] = t;
    }
    __builtin_amdgcn_s_setprio(0);
  };

  auto softmax_pack = [&](f32x4* s, bool diag, int q_abs, int kv0, bf16x8* pa) {
    if (diag) {
      #pragma unroll
      for (int ni = 0; ni < 4; ++ni)
        #pragma unroll
        for (int r = 0; r < 4; ++r) {
          const int kv_abs = kv0 + ni * 16 + g * 4 + r;
          if (kv_abs > q_abs) s[ni][r] = -3e38f;
        }
    }
    #pragma unroll
    for (int ni = 0; ni < 4; ++ni)
      #pragma unroll
      for (int r = 0; r < 4; ++r)
        s[ni][r] = fast_exp2(s[ni][r]);

    u32 pk[4][2];
    #pragma unroll
    for (int ni = 0; ni < 4; ++ni)
      #pragma unroll
      for (int h2 = 0; h2 < 2; ++h2)
        asm("v_cvt_pk_bf16_f32 %0, %1, %2"
            : "=v"(pk[ni][h2]) : "v"(s[ni][2 * h2]), "v"(s[ni][2 * h2 + 1]));

    u32 pa32[2][4];
    #pragma unroll
    for (int kc = 0; kc < 2; ++kc)
      #pragma unroll
      for (int h2 = 0; h2 < 2; ++h2) {
        u32 a = pk[2 * kc][h2], bq_ = pk[2 * kc + 1][h2];
        asm("v_permlane32_swap_b32 %0, %1" : "+v"(a), "+v"(bq_));
        asm("v_permlane16_swap_b32 %0, %1" : "+v"(a), "+v"(bq_));
        pa32[kc][h2] = a;
        pa32[kc][2 + h2] = bq_;
      }
    #pragma unroll
    for (int kc = 0; kc < 2; ++kc) {
      u32x4 tmp = {pa32[kc][0], pa32[kc][1], pa32[kc][2], pa32[kc][3]};
      pa[kc] = __builtin_bit_cast(bf16x8, tmp);
    }
  };

  // prologue: tile 0 only (2-deep ring, prefetch distance 1)
  stageAdv();
  asm volatile("s_waitcnt vmcnt(0)" ::: "memory");
  __builtin_amdgcn_s_barrier();
  __builtin_amdgcn_sched_barrier(0);

  int cbuf = 0;
  for (int t = 0; t < nB; ++t) {
    if (t + 1 < nB) stageAdv();
    const u16* Kb = sK[cbuf];
    const u16* Vb = sV[cbuf];
    const int kv0 = t << 6;
    const bool actA = (t < nA);
    const bool mB = (t + 2 >= nB);
    const bool mA = (t + 2 >= nA);

    bf16x8 kf0[4], kf1[4], vf0[4], vf1[4];
    #pragma unroll
    for (int ni = 0; ni < 4; ++ni) {
      kf0[ni] = *(const bf16x8*)&Kb[(ni * 16 + r16) * 64 + ck0];
      kf1[ni] = *(const bf16x8*)&Kb[(ni * 16 + r16) * 64 + ck1];
      vf0[ni] = *(const bf16x8*)&Vb[(ni * 16 + r16) * 64 + ck0];
      vf1[ni] = *(const bf16x8*)&Vb[(ni * 16 + r16) * 64 + ck1];
    }

    #pragma unroll
    for (int qp = 0; qp < 2; ++qp) {
      f32x4 s[4];
      bf16x8 pa[2];
      qkt(kf0, kf1, qfB[qp], s);
      softmax_pack(s, mB, qaB[qp], kv0, pa);
      __builtin_amdgcn_s_setprio(1);
      lB[qp] = __builtin_amdgcn_mfma_f32_16x16x32_bf16(pa[0], ONES, lB[qp], 0, 0, 0);
      lB[qp] = __builtin_amdgcn_mfma_f32_16x16x32_bf16(pa[1], ONES, lB[qp], 0, 0, 0);
      #pragma unroll
      for (int hsb = 0; hsb < 4; ++hsb) {
        accB[qp][hsb] = __builtin_amdgcn_mfma_f32_16x16x32_bf16(pa[0], vf0[hsb], accB[qp][hsb], 0, 0, 0);
        accB[qp][hsb] = __builtin_amdgcn_mfma_f32_16x16x32_bf16(pa[1], vf1[hsb], accB[qp][hsb], 0, 0, 0);
      }
      __builtin_amdgcn_s_setprio(0);
    }

    if (actA) {
      #pragma unroll
      for (int qp = 0; qp < 2; ++qp) {
        f32x4 s[4];
        bf16x8 pa[2];
        qkt(kf0, kf1, qfA[qp], s);
        softmax_pack(s, mA, qaA[qp], kv0, pa);
        __builtin_amdgcn_s_setprio(1);
        lA[qp] = __builtin_amdgcn_mfma_f32_16x16x32_bf16(pa[0], ONES, lA[qp], 0, 0, 0);
        lA[qp] = __builtin_amdgcn_mfma_f32_16x16x32_bf16(pa[1], ONES, lA[qp], 0, 0, 0);
        #pragma unroll
        for (int hsb = 0; hsb < 4; ++hsb) {
          accA[qp][hsb] = __builtin_amdgcn_mfma_f32_16x16x32_bf16(pa[0], vf0[hsb], accA[qp][hsb], 0, 0, 0);
          accA[qp][hsb] = __builtin_amdgcn_mfma_f32_16x16x32_bf16(pa[1], vf1[hsb], accA[qp][hsb], 0, 0, 0);
        }
        __builtin_amdgcn_s_setprio(0);
      }
    }

    if (t + 1 < nB) {
      asm volatile("s_waitcnt vmcnt(0)" ::: "memory");
      __builtin_amdgcn_s_barrier();
      __builtin_amdgcn_sched_barrier(0);
    }
    cbuf ^= 1;
  }

  #pragma unroll
  for (int qp = 0; qp < 2; ++qp) {
    float rlA[4], rlB[4];
    #pragma unroll
    for (int r = 0; r < 4; ++r) {
      rlA[r] = fast_rcp(lA[qp][r]);
      rlB[r] = fast_rcp(lB[qp][r]);
    }
    #pragma unroll
    for (int hsb = 0; hsb < 4; ++hsb)
      #pragma unroll
      for (int r = 0; r < 4; ++r) {
        const size_t rowA = (size_t)b * T_ + qA + wave * 32 + qp * 16 + g * 4 + r;
        const size_t rowB = (size_t)b * T_ + qB + wave * 32 + qp * 16 + g * 4 + r;
        O[rowA * C_ + h * 64 + hsb * 16 + r16] = f2bf(accA[qp][hsb][r] * rlA[r]);
        O[rowB * C_ + h * 64 + hsb * 16 + r16] = f2bf(accB[qp][hsb][r] * rlB[r]);
      }
  }
}

// ---------------------------------------------------------------------------
extern "C" void kernel_launch(void* const* d_in, const int* in_sizes, int n_in,
                              void* d_out, int out_size, void* d_ws, size_t ws_size,
                              hipStream_t stream) {
  const float* x    = (const float*)d_in[0];
  const float* ln1g = (const float*)d_in[1];
  const float* ln1b = (const float*)d_in[2];
  const float* ln2g = (const float*)d_in[3];
  const float* ln2b = (const float*)d_in[4];
  const float* Wq   = (const float*)d_in[5];
  const float* bq   = (const float*)d_in[6];
  const float* Wk   = (const float*)d_in[7];
  const float* bk   = (const float*)d_in[8];
  const float* Wv   = (const float*)d_in[9];
  const float* bv   = (const float*)d_in[10];
  const float* Wo   = (const float*)d_in[11];
  const float* bo   = (const float*)d_in[12];
  const float* W1   = (const float*)d_in[13];
  const float* b1   = (const float*)d_in[14];
  const float* W2   = (const float*)d_in[15];
  const float* b2   = (const float*)d_in[16];

  char* w = (char*)d_ws;
  float* ps    = (float*)(w + 0);
  float* psq   = (float*)(w + 262144);
  float* mean  = (float*)(w + 524288);
  float* rstd  = (float*)(w + 540672);
  float* bqkv  = (float*)(w + 557056);
  u16*   h     = (u16*)  (w + 573440);          // 16 MB (dead after FFN1)
  u16*   wqkvT = (u16*)  (w + 17350656);        // 6 MB
  u16*   woT   = (u16*)  (w + 23642112);        // 2 MB
  u16*   w1T   = (u16*)  (w + 25739264);        // 8 MB
  u16*   w2T   = (u16*)  (w + 34127872);        // 8 MB
  u16*   x1b   = (u16*)  (w + 42516480);        // 16 MB bf16 residual stream
  u16*   Vt    = (u16*)  (w + 59293696);        // 16 MB
  u16*   qkv   = (u16*)  (w + 76070912);        // 48 MB
  u16*   Oo    = (u16*)  (w + 126402560);       // 16 MB
  u16*   u     = qkv;                           // alias
  u16*   pA    = (u16*)  (w + 573440);          // 16 MB bf16 FFN2 partial (over dead h)

  // fused weight pack + bias concat (was 7 launches)
  pack_all<<<12300, 256, 0, stream>>>(Wq, Wk, Wv, Wo, W1, W2, bq, bk, bv,
                                      wqkvT, woT, w1T, w2T, bqkv);

  // LN1 -> h (bf16)
  ln_partial<<<dim3(16, 16), 256, 0, stream>>>(x, ps, psq);
  ln_final<<<16, 256, 0, stream>>>(ps, psq, mean, rstd);
  ln_norm<<<8192, 256, 0, stream>>>(x, mean, rstd, ln1g, ln1b, h);

  // QKV projection (Q cols pre-scaled): BN=192 -> 1024 blocks, 2 clean rounds
  gemm_128t<192, 0, 1><<<1024, 256, 0, stream>>>(h, wqkvT, bqkv, qkv, BT_, 3072, 1024);

  // V transpose for attention
  v_transpose<<<dim3(T_ / 32, 2, B_ * H_), 256, 0, stream>>>(qkv, Vt);

  // attention v10: 512 blocks, 128-row mirror-paired strips, 32 rows/wave
  attn_fwd<<<512, 256, 0, stream>>>(qkv, Vt, Oo);

  // output projection + residual -> x1b (bf16): 512 blocks
  gemm_pipe<128, 128, 256, 0, 0, 1><<<512, 256, 0, stream>>>(Oo, woT, bo, x, x1b, BT_, 1024, 1024);

  // LN2 -> h (from bf16 residual stream)
  ln_partial_bf<<<dim3(16, 16), 256, 0, stream>>>(x1b, ps, psq);
  ln_final<<<16, 256, 0, stream>>>(ps, psq, mean, rstd);
  ln_norm_bf<<<8192, 256, 0, stream>>>(x1b, mean, rstd, ln2g, ln2b, h);

  // FFN1 (M=8192, N=4096): proven 128x256 ring, 1024 blocks, 2 clean rounds
  gemm_128t<256, 1, 0><<<1024, 256, 0, stream>>>(h, w1T, b1, u, BT_, 4096, 1024);
  // FFN2 split-K=2: y=0 -> pA (bf16 raw), y=1 -> d_out (acc + b2 + x1b, f32)
  gemm_256<0, 1, 0><<<dim3(128, 2), 512, 0, stream>>>(u, w2T, b2, x1b, pA, d_out, BT_, 1024, 4096);
  // reduce: d_out += pA (bf16)
  ffn2_reduce<<<8192, 256, 0, stream>>>(pA, (float*)d_out);
}

// Round 7
// 360.487 us; speedup vs baseline: 1.1312x; 1.0147x over previous
//
#include <hip/hip_runtime.h>

#define B_   4
#define T_   2048
#define C_   1024
#define H_   16
#define HS_  64
#define BT_  (B_*T_)
#define EPS_ 1e-5f

typedef unsigned short u16;
typedef unsigned int   u32;
typedef __attribute__((ext_vector_type(8))) __bf16 bf16x8;
typedef __attribute__((ext_vector_type(4))) float  f32x4;
typedef __attribute__((ext_vector_type(8))) u16    u16x8;
typedef __attribute__((ext_vector_type(4))) u16    u16x4;
typedef __attribute__((ext_vector_type(4))) u32    u32x4;

__device__ __forceinline__ u16 f2bf(float f) {
  unsigned x = __builtin_bit_cast(unsigned, f);
  x += 0x7fffu + ((x >> 16) & 1u);
  return (u16)(x >> 16);
}
__device__ __forceinline__ float bf2f(u16 v) {
  return __builtin_bit_cast(float, (u32)v << 16);
}

__device__ __forceinline__ float fast_exp2(float x) {
  float y;
  asm("v_exp_f32 %0, %1" : "=v"(y) : "v"(x));
  return y;
}
__device__ __forceinline__ float fast_rcp(float x) {
  float y;
  asm("v_rcp_f32 %0, %1" : "=v"(y) : "v"(x));
  return y;
}

#define GLD_LDS16(src, dst) \
  __builtin_amdgcn_global_load_lds((__attribute__((address_space(1))) void*)(src), \
                                   (__attribute__((address_space(3))) void*)(dst), 16, 0, 0)

// ---------------- LayerNorm over time axis (axis=1, ddof=1) ----------------
// bf16-input partial (x1 residual stream); f32-input partial lives in pack_all.
__global__ __launch_bounds__(256) void ln_partial_bf(const u16* __restrict__ x,
                                                     float* __restrict__ ps,
                                                     float* __restrict__ psq) {
  int col = blockIdx.x * 256 + threadIdx.x;
  int b = col >> 10, c = col & (C_ - 1);
  int t0 = blockIdx.y * (T_ / 16);
  const u16* p = x + (size_t)b * T_ * C_ + (size_t)t0 * C_ + c;
  float s = 0.f, sq = 0.f;
  #pragma unroll 4
  for (int i = 0; i < T_ / 16; ++i) { float v = bf2f(p[(size_t)i * C_]); s += v; sq += v * v; }
  ps [blockIdx.y * (B_ * C_) + col] = s;
  psq[blockIdx.y * (B_ * C_) + col] = sq;
}

__global__ __launch_bounds__(256) void ln_final(const float* __restrict__ ps,
                                                const float* __restrict__ psq,
                                                float* __restrict__ mean,
                                                float* __restrict__ rstd) {
  int col = blockIdx.x * 256 + threadIdx.x;
  float s = 0.f, sq = 0.f;
  #pragma unroll
  for (int i = 0; i < 16; ++i) { s += ps[i * (B_ * C_) + col]; sq += psq[i * (B_ * C_) + col]; }
  float m = s * (1.f / T_);
  float var = (sq - (float)T_ * m * m) * (1.f / (T_ - 1));   // ddof=1
  mean[col] = m;
  rstd[col] = rsqrtf(var + EPS_);
}

__global__ __launch_bounds__(256) void ln_norm(const float* __restrict__ x,
                                               const float* __restrict__ mean,
                                               const float* __restrict__ rstd,
                                               const float* __restrict__ gam,
                                               const float* __restrict__ bet,
                                               u16* __restrict__ out) {
  size_t i = ((size_t)blockIdx.x * 256 + threadIdx.x) * 4;
  int c  = (int)(i & (C_ - 1));
  int b  = (int)(i >> 21);
  int bc = (b << 10) + c;
  float4 v = *(const float4*)(x + i);
  float vv[4] = {v.x, v.y, v.z, v.w};
  u16x4 o;
  #pragma unroll
  for (int j = 0; j < 4; ++j)
    o[j] = f2bf(gam[c + j] * (vv[j] - mean[bc + j]) * rstd[bc + j] + bet[c + j]);
  *(u16x4*)(out + i) = o;
}

// bf16-input variant
__global__ __launch_bounds__(256) void ln_norm_bf(const u16* __restrict__ x,
                                                  const float* __restrict__ mean,
                                                  const float* __restrict__ rstd,
                                                  const float* __restrict__ gam,
                                                  const float* __restrict__ bet,
                                                  u16* __restrict__ out) {
  size_t i = ((size_t)blockIdx.x * 256 + threadIdx.x) * 4;
  int c  = (int)(i & (C_ - 1));
  int b  = (int)(i >> 21);
  int bc = (b << 10) + c;
  u16x4 v = *(const u16x4*)(x + i);
  u16x4 o;
  #pragma unroll
  for (int j = 0; j < 4; ++j)
    o[j] = f2bf(gam[c + j] * (bf2f(v[j]) - mean[bc + j]) * rstd[bc + j] + bet[c + j]);
  *(u16x4*)(out + i) = o;
}

// ---------------- fused input-stage: weight pack + bias concat + LN1 partial
// Segmented flat grid (block-uniform branches), replaces 8 launches:
//   [0,3072)       Wq/Wk/Wv per-head [1024,64] -> wqkvT [64,1024]
//   [3072,4096)    Wo [1024,1024] -> woT, 32x32 tiles
//   [4096,8192)    W1 [1024,4096] -> w1T
//   [8192,12288)   W2 [4096,1024] -> w2T
//   [12288,12300)  bias concat bq|bk|bv -> bqkv
//   [12300,12556)  LN1 partial sums over x (f32): 16 col-chunks x 16 t-slabs
__global__ __launch_bounds__(256) void pack_all(
    const float* __restrict__ Wq, const float* __restrict__ Wk,
    const float* __restrict__ Wv, const float* __restrict__ Wo,
    const float* __restrict__ W1, const float* __restrict__ W2,
    const float* __restrict__ bq, const float* __restrict__ bk,
    const float* __restrict__ bv, const float* __restrict__ x,
    u16* __restrict__ wqkvT, u16* __restrict__ woT,
    u16* __restrict__ w1T,   u16* __restrict__ w2T,
    float* __restrict__ bqkv,
    float* __restrict__ ps,  float* __restrict__ psq) {
  __shared__ float tile[32][33];
  const int bid = blockIdx.x;
  const int tid = threadIdx.x;

  if (bid >= 12300) {                      // LN1 partial (f32 x)
    const int rel = bid - 12300;
    const int bx = rel & 15, by = rel >> 4;
    int col = bx * 256 + tid;
    int b = col >> 10, c = col & (C_ - 1);
    int t0 = by * (T_ / 16);
    const float* p = x + (size_t)b * T_ * C_ + (size_t)t0 * C_ + c;
    float s = 0.f, sq = 0.f;
    #pragma unroll 4
    for (int i = 0; i < T_ / 16; ++i) { float v = p[(size_t)i * C_]; s += v; sq += v * v; }
    ps [by * (B_ * C_) + col] = s;
    psq[by * (B_ * C_) + col] = sq;
    return;
  }
  if (bid >= 12288) {                      // bias concat
    int i = (bid - 12288) * 256 + tid;
    float v = (i < 1024) ? bq[i] : (i < 2048 ? bk[i - 1024] : bv[i - 2048]);
    bqkv[i] = v;
    return;
  }

  const float* I; u16* Ou; int cols_in, ld_out, bx, by;
  if (bid < 3072) {
    const int z = bid >> 6, t6 = bid & 63;
    bx = t6 & 1; by = t6 >> 1;
    const int wsel = z >> 4, head = z & 15;
    I  = (wsel == 0 ? Wq : (wsel == 1 ? Wk : Wv)) + (size_t)head * (C_ * 64);
    Ou = wqkvT + (size_t)wsel * 1024 * 1024 + (size_t)head * 64 * 1024;
    cols_in = 64; ld_out = 1024;
  } else if (bid < 4096) {
    const int rel = bid - 3072;
    bx = rel & 31; by = rel >> 5;
    I = Wo; Ou = woT; cols_in = 1024; ld_out = 1024;
  } else if (bid < 8192) {
    const int rel = bid - 4096;
    bx = rel & 127; by = rel >> 7;
    I = W1; Ou = w1T; cols_in = 4096; ld_out = 1024;
  } else {
    const int rel = bid - 8192;
    bx = rel & 31; by = rel >> 5;
    I = W2; Ou = w2T; cols_in = 1024; ld_out = 4096;
  }

  const int r0 = by << 5, c0 = bx << 5;
  const int tx = tid & 31, ty = tid >> 5;
  #pragma unroll
  for (int rr = 0; rr < 32; rr += 8)
    tile[ty + rr][tx] = I[(size_t)(r0 + ty + rr) * cols_in + c0 + tx];
  __syncthreads();
  #pragma unroll
  for (int rr = 0; rr < 32; rr += 8)
    Ou[(size_t)(c0 + ty + rr) * ld_out + r0 + tx] = f2bf(tile[tx][ty + rr]);
}

// ---------------- V transpose: qkv V block -> Vt[bh][hs][T] bf16 -----------
__global__ __launch_bounds__(256) void v_transpose(const u16* __restrict__ qkv,
                                                   u16* __restrict__ Vt) {
  __shared__ u16 tile[32][33];
  int bh = blockIdx.z; int b = bh >> 4, h = bh & 15;
  int t0 = blockIdx.x << 5, hs0 = blockIdx.y << 5;
  int tx = threadIdx.x & 31, ty = threadIdx.x >> 5;
  const u16* src = qkv + (size_t)(b * T_ + t0) * 3072 + 2048 + h * 64 + hs0;
  #pragma unroll
  for (int rr = 0; rr < 32; rr += 8)
    tile[ty + rr][tx] = src[(size_t)(ty + rr) * 3072 + tx];
  __syncthreads();
  u16* dst = Vt + ((size_t)bh * 64 + hs0) * T_ + t0;
  #pragma unroll
  for (int rr = 0; rr < 32; rr += 8)
    dst[(size_t)(ty + rr) * T_ + tx] = tile[tx][ty + rr];
}

// ---------------- 128xBN bf16 NT GEMM, 4 waves, per-wave 64x(BN/2) ---------
// r12-proven counted ring: depth 3, prefetch distance 2, boundary
// vmcnt(2+CHB). Conflict-free XOR chunk swizzle. BN=192: QKV config,
// 1024 blocks = 2 clean rounds at 2/CU.
template<int BN, int RELU, int QSCALE>
__global__ __launch_bounds__(256, 2)
void gemm_128t(const u16* __restrict__ A,
               const u16* __restrict__ Bt,
               const float* __restrict__ bias,
               u16* __restrict__ outp,
               int M, int N, int K) {
  constexpr int BK  = 32;
  constexpr int CHA = 2;            // 128*4/256
  constexpr int CHB = BN / 64;      // BN*4/256
  constexpr int NF  = BN / 32;      // per-wave N fragments

  __shared__ u16 sA[3][128 * BK];
  __shared__ u16 sB[3][BN * BK];

  const int tid = threadIdx.x;
  const int wave = tid >> 6, lane = tid & 63;
  const int g = lane >> 4, r16 = lane & 15;

  const int nbx = N / BN;
  const int nwg = gridDim.x;
  const int bid = blockIdx.x;
  const int swz = ((bid & 7) * (nwg >> 3)) + (bid >> 3);
  const int bx = swz % nbx, by = swz / nbx;
  const int row0 = by << 7, col0 = bx * BN;

  const u16* aS[CHA];
  const u16* bS[CHB];
  #pragma unroll
  for (int j = 0; j < CHA; ++j) {
    const int ci = tid + 256 * j, row = ci >> 2, cc = ci & 3;
    aS[j] = A + (size_t)(row0 + row) * K + ((cc ^ ((row >> 1) & 3)) * 8);
  }
  #pragma unroll
  for (int j = 0; j < CHB; ++j) {
    const int ci = tid + 256 * j, row = ci >> 2, cc = ci & 3;
    bS[j] = Bt + (size_t)(col0 + row) * K + ((cc ^ ((row >> 1) & 3)) * 8);
  }
  const int ldsOff = wave * 512;   // u16: 64 lanes x 8 u16 per gld_lds call

  auto stage = [&](int t, int buf) {
    const int ko = t * BK;
    #pragma unroll
    for (int j = 0; j < CHA; ++j)
      GLD_LDS16(aS[j] + ko, &sA[buf][ldsOff + j * 2048]);
    #pragma unroll
    for (int j = 0; j < CHB; ++j)
      GLD_LDS16(bS[j] + ko, &sB[buf][ldsOff + j * 2048]);
  };

  auto wait_stage1 = [&]() {   // one stage (CHA+CHB loads) still in flight
    if constexpr (CHB == 4) asm volatile("s_waitcnt vmcnt(6)" ::: "memory");
    else                    asm volatile("s_waitcnt vmcnt(5)" ::: "memory");
  };

  const int wrow = (wave >> 1) * 64;         // 2 waves along M
  const int wcol = (wave & 1) * (BN >> 1);   // 2 waves along N
  f32x4 acc[4][NF] = {};

  const int NT = K / BK;

  stage(0, 0); stage(1, 1);
  wait_stage1();                   // tile 0 resident
  __builtin_amdgcn_s_barrier();
  __builtin_amdgcn_sched_barrier(0);

  for (int t = 0; t < NT; ++t) {
    const u16* As = sA[t % 3];
    const u16* Bs = sB[t % 3];
    bf16x8 af[4], bf[NF];
    #pragma unroll
    for (int m = 0; m < 4; ++m) {
      const int lr = wrow + m * 16 + r16;
      af[m] = *(const bf16x8*)&As[lr * 32 + ((g ^ ((lr >> 1) & 3)) * 8)];
    }
    #pragma unroll
    for (int n = 0; n < NF; ++n) {
      const int lr = wcol + n * 16 + r16;
      bf[n] = *(const bf16x8*)&Bs[lr * 32 + ((g ^ ((lr >> 1) & 3)) * 8)];
    }
    if (t + 2 < NT) stage(t + 2, (t + 2) % 3);

    __builtin_amdgcn_s_setprio(1);
    #pragma unroll
    for (int m = 0; m < 4; ++m)
      #pragma unroll
      for (int n = 0; n < NF; ++n)
        acc[m][n] = __builtin_amdgcn_mfma_f32_16x16x32_bf16(af[m], bf[n], acc[m][n], 0, 0, 0);
    __builtin_amdgcn_s_setprio(0);

    if (t + 1 < NT) {
      if (t + 2 < NT) wait_stage1();
      else            asm volatile("s_waitcnt vmcnt(0)" ::: "memory");
      __builtin_amdgcn_s_barrier();
      __builtin_amdgcn_sched_barrier(0);
    }
  }

  #pragma unroll
  for (int m = 0; m < 4; ++m) {
    #pragma unroll
    for (int n = 0; n < NF; ++n) {
      const int col = col0 + wcol + n * 16 + r16;
      const float bv = bias[col];
      const float sc = (QSCALE && col < 1024) ? 0.04508422003f : 1.f;
      const int rowb = row0 + wrow + m * 16 + g * 4;
      #pragma unroll
      for (int r = 0; r < 4; ++r) {
        float v = acc[m][n][r] + bv;
        if (RELU) v = fmaxf(v, 0.f);
        if (QSCALE) v *= sc;
        outp[(size_t)(rowb + r) * N + col] = f2bf(v);
      }
    }
  }
}

// ---------------- 256x256 bf16 NT GEMM, 8 waves, per-wave 128x64 -----------
// r12-proven counted ring: depth 4, prefetch distance 2, boundary vmcnt(4).
// Per-CU rate inferred (r3 ledger): ~6-8% faster than gemm_128t at equal
// per-CU work -> now hosts FFN1 (RAW=0) as well as FFN2 (RAW=1).
// RAW=1: split-K over gridDim.y.
//   y==0 -> bf16 raw partial to outp; y==1 -> acc + bias + bf16 residual, f32.
template<int RELU, int RAW, int QSCALE>
__global__ __launch_bounds__(512, 2)
void gemm_256(const u16* __restrict__ A,
              const u16* __restrict__ Bt,
              const float* __restrict__ bias,
              const u16* __restrict__ resb,
              void* __restrict__ outp,
              void* __restrict__ outp_b,
              int M, int N, int K) {
  constexpr int BK = 32;
  __shared__ u16 sA[4][256 * BK];   // 64 KB
  __shared__ u16 sB[4][256 * BK];   // 64 KB

  const int tid = threadIdx.x;
  const int wave = tid >> 6, lane = tid & 63;
  const int g = lane >> 4, r16 = lane & 15;

  const int nbx = N >> 8;
  const int nwg = gridDim.x;
  const int bid = blockIdx.x;
  const int swz = ((bid & 7) * (nwg >> 3)) + (bid >> 3);
  const int bx = swz % nbx, by = swz / nbx;
  const int row0 = by << 8, col0 = bx << 8;

  const int kspan = RAW ? (K >> 1) : K;
  const int kbase = RAW ? ((int)blockIdx.y * kspan) : 0;

  const u16* aS[2];
  const u16* bS[2];
  #pragma unroll
  for (int j = 0; j < 2; ++j) {
    const int ci = tid + 512 * j, row = ci >> 2, cc = ci & 3;
    aS[j] = A  + (size_t)(row0 + row) * K + ((cc ^ ((row >> 1) & 3)) * 8) + kbase;
    bS[j] = Bt + (size_t)(col0 + row) * K + ((cc ^ ((row >> 1) & 3)) * 8) + kbase;
  }
  const int ldsOff = wave * 512;

  auto stage = [&](int t, int buf) {
    const int ko = t * BK;
    #pragma unroll
    for (int j = 0; j < 2; ++j)
      GLD_LDS16(aS[j] + ko, &sA[buf][ldsOff + j * 4096]);
    #pragma unroll
    for (int j = 0; j < 2; ++j)
      GLD_LDS16(bS[j] + ko, &sB[buf][ldsOff + j * 4096]);
  };

  const int wrow = (wave >> 2) * 128;
  const int wcol = (wave & 3) * 64;
  f32x4 acc[8][4] = {};

  const int NT = kspan / BK;

  stage(0, 0); stage(1, 1);
  asm volatile("s_waitcnt vmcnt(4)" ::: "memory");
  __builtin_amdgcn_s_barrier();
  __builtin_amdgcn_sched_barrier(0);

  for (int t = 0; t < NT; ++t) {
    const u16* As = sA[t & 3];
    const u16* Bs = sB[t & 3];
    bf16x8 af[8], bf[4];
    #pragma unroll
    for (int m = 0; m < 8; ++m) {
      const int lr = wrow + m * 16 + r16;
      af[m] = *(const bf16x8*)&As[lr * 32 + ((g ^ ((lr >> 1) & 3)) * 8)];
    }
    #pragma unroll
    for (int n = 0; n < 4; ++n) {
      const int lr = wcol + n * 16 + r16;
      bf[n] = *(const bf16x8*)&Bs[lr * 32 + ((g ^ ((lr >> 1) & 3)) * 8)];
    }
    if (t + 2 < NT) stage(t + 2, (t + 2) & 3);

    __builtin_amdgcn_s_setprio(1);
    #pragma unroll
    for (int m = 0; m < 8; ++m)
      #pragma unroll
      for (int n = 0; n < 4; ++n)
        acc[m][n] = __builtin_amdgcn_mfma_f32_16x16x32_bf16(af[m], bf[n], acc[m][n], 0, 0, 0);
    __builtin_amdgcn_s_setprio(0);

    if (t + 1 < NT) {
      if (t + 2 < NT) asm volatile("s_waitcnt vmcnt(4)" ::: "memory");
      else            asm volatile("s_waitcnt vmcnt(0)" ::: "memory");
      __builtin_amdgcn_s_barrier();
      __builtin_amdgcn_sched_barrier(0);
    }
  }

  if constexpr (RAW) {
    if (blockIdx.y) {
      // final split: fuse bias + bf16 residual, write f32
      float* po = (float*)outp_b;
      #pragma unroll
      for (int m = 0; m < 8; ++m) {
        #pragma unroll
        for (int n = 0; n < 4; ++n) {
          const int col = col0 + wcol + n * 16 + r16;
          const float bv = bias[col];
          const int rowb = row0 + wrow + m * 16 + g * 4;
          #pragma unroll
          for (int r = 0; r < 4; ++r) {
            const size_t idx = (size_t)(rowb + r) * N + col;
            po[idx] = acc[m][n][r] + bv + bf2f(resb[idx]);
          }
        }
      }
    } else {
      u16* po = (u16*)outp;    // bf16 raw partial (traffic halved)
      #pragma unroll
      for (int m = 0; m < 8; ++m) {
        #pragma unroll
        for (int n = 0; n < 4; ++n) {
          const int col = col0 + wcol + n * 16 + r16;
          const int rowb = row0 + wrow + m * 16 + g * 4;
          #pragma unroll
          for (int r = 0; r < 4; ++r)
            po[(size_t)(rowb + r) * N + col] = f2bf(acc[m][n][r]);
        }
      }
    }
  } else {
    u16* po = (u16*)outp;
    #pragma unroll
    for (int m = 0; m < 8; ++m) {
      #pragma unroll
      for (int n = 0; n < 4; ++n) {
        const int col = col0 + wcol + n * 16 + r16;
        const float bv = bias[col];
        const float sc = (QSCALE && col < 1024) ? 0.04508422003f : 1.f;
        const int rowb = row0 + wrow + m * 16 + g * 4;
        #pragma unroll
        for (int r = 0; r < 4; ++r) {
          float v = acc[m][n][r] + bv;
          if (RELU) v = fmaxf(v, 0.f);
          if (QSCALE) v *= sc;
          po[(size_t)(rowb + r) * N + col] = f2bf(v);
        }
      }
    }
  }
}

// ---------------- FFN2 split-K reduce: out += pA(bf16) ---------------------
__global__ __launch_bounds__(256) void ffn2_reduce(const u16* __restrict__ pA,
                                                   float* __restrict__ out) {
  size_t i = ((size_t)blockIdx.x * 256 + threadIdx.x) * 4;
  u16x4 a = *(const u16x4*)(pA + i);
  float4 o = *(const float4*)(out + i);
  float4 v;
  v.x = o.x + bf2f(a[0]);
  v.y = o.y + bf2f(a[1]);
  v.z = o.z + bf2f(a[2]);
  v.w = o.w + bf2f(a[3]);
  *(float4*)(out + i) = v;
}

// ---------------- bf16 NT GEMM, pipelined BMxBN tile (narrow N) ------------
template<int BM, int BN, int THREADS, int OUT_F32, int RELU, int RES>
__global__ __launch_bounds__(THREADS, 3)
void gemm_pipe(const u16* __restrict__ A,
               const u16* __restrict__ Bt,
               const float* __restrict__ bias,
               const float* __restrict__ res,
               void* __restrict__ outp,
               int M, int N, int K) {
  constexpr int BK  = 32;
  constexpr int CHA = (BM * 4) / THREADS;
  constexpr int CHB = (BN * 4) / THREADS;
  constexpr int CH  = CHA + CHB;

  __shared__ u16 sA[3][BM * BK];
  __shared__ u16 sB[3][BN * BK];

  const int tid = threadIdx.x;
  const int wave = tid >> 6, lane = tid & 63;
  const int g = lane >> 4, r16 = lane & 15;

  const int nbx = N / BN;
  const int nwg = gridDim.x;
  const int bid = blockIdx.x;
  const int swz = ((bid & 7) * (nwg >> 3)) + (bid >> 3);
  const int bx = swz % nbx, by = swz / nbx;
  const int row0 = by * BM, col0 = bx * BN;

  const u16* aS[CHA];
  const u16* bS[CHB];
  #pragma unroll
  for (int j = 0; j < CHA; ++j) {
    const int ci = tid + THREADS * j, row = ci >> 2, cc = ci & 3;
    aS[j] = A + (size_t)(row0 + row) * K + ((cc ^ ((row >> 1) & 3)) * 8);
  }
  #pragma unroll
  for (int j = 0; j < CHB; ++j) {
    const int ci = tid + THREADS * j, row = ci >> 2, cc = ci & 3;
    bS[j] = Bt + (size_t)(col0 + row) * K + ((cc ^ ((row >> 1) & 3)) * 8);
  }
  const int ldsOff = wave * 512;

  auto stage = [&](int t, int buf) {
    const int ko = t * BK;
    #pragma unroll
    for (int j = 0; j < CHA; ++j)
      GLD_LDS16(aS[j] + ko, &sA[buf][ldsOff + j * (THREADS * 8)]);
    #pragma unroll
    for (int j = 0; j < CHB; ++j)
      GLD_LDS16(bS[j] + ko, &sB[buf][ldsOff + j * (THREADS * 8)]);
  };

  const int wrow = (wave >> 1) * 64;
  const int wcol = (wave & 1) * 64;
  f32x4 acc[4][4] = {};

  const int NT = K / BK;

  stage(0, 0); stage(1, 1);
  if constexpr (CH == 3) asm volatile("s_waitcnt vmcnt(3)" ::: "memory");
  else                   asm volatile("s_waitcnt vmcnt(4)" ::: "memory");
  __builtin_amdgcn_s_barrier();
  __builtin_amdgcn_sched_barrier(0);

  for (int t = 0; t < NT; ++t) {
    if (t + 2 < NT) stage(t + 2, (t + 2) % 3);
    const u16* As = sA[t % 3];
    const u16* Bs = sB[t % 3];
    bf16x8 af[4], bf[4];
    #pragma unroll
    for (int m = 0; m < 4; ++m) {
      const int lr = wrow + m * 16 + r16;
      af[m] = *(const bf16x8*)&As[lr * 32 + ((g ^ ((lr >> 1) & 3)) * 8)];
    }
    #pragma unroll
    for (int n = 0; n < 4; ++n) {
      const int lr = wcol + n * 16 + r16;
      bf[n] = *(const bf16x8*)&Bs[lr * 32 + ((g ^ ((lr >> 1) & 3)) * 8)];
    }
    __builtin_amdgcn_s_setprio(1);
    #pragma unroll
    for (int m = 0; m < 4; ++m)
      #pragma unroll
      for (int n = 0; n < 4; ++n)
        acc[m][n] = __builtin_amdgcn_mfma_f32_16x16x32_bf16(af[m], bf[n], acc[m][n], 0, 0, 0);
    __builtin_amdgcn_s_setprio(0);

    if (t + 1 < NT) {
      if (t + 2 < NT) {
        if constexpr (CH == 3) asm volatile("s_waitcnt vmcnt(3)" ::: "memory");
        else                   asm volatile("s_waitcnt vmcnt(4)" ::: "memory");
      } else {
        asm volatile("s_waitcnt vmcnt(0)" ::: "memory");
      }
      __builtin_amdgcn_s_barrier();
      __builtin_amdgcn_sched_barrier(0);
    }
  }

  #pragma unroll
  for (int m = 0; m < 4; ++m) {
    #pragma unroll
    for (int n = 0; n < 4; ++n) {
      const int col = col0 + wcol + n * 16 + r16;
      const float bv = bias[col];
      const int rowb = row0 + wrow + m * 16 + g * 4;
      #pragma unroll
      for (int r = 0; r < 4; ++r) {
        const size_t idx = (size_t)(rowb + r) * N + col;
        float v = acc[m][n][r] + bv;
        if (RES)  v += res[idx];
        if (RELU) v = fmaxf(v, 0.f);
        if (OUT_F32) ((float*)outp)[idx] = v;
        else         ((u16*)outp)[idx]   = f2bf(v);
      }
    }
  }
}

// ---------------- causal flash attention v10 -------------------------------
// 32 Q-rows per wave (2x 16-row fragments), 128-row mirror-paired strips,
// 512 blocks, 2-deep ring. Proven r5: -11 us vs v9.
__global__ __launch_bounds__(256, 2) void attn_fwd(const u16* __restrict__ qkv,
                                                   const u16* __restrict__ Vt,
                                                   u16* __restrict__ O) {
  __shared__ u16 sK[2][64 * 64];
  __shared__ u16 sV[2][64 * 64];

  const int orig = blockIdx.x;                       // 512 blocks
  const int work = ((orig & 7) << 6) + (orig >> 3);  // XCD swizzle
  const int i = work & 7;
  const int h = (work >> 3) & 15;
  const int b = work >> 7;
  const int qA = i << 7, qB = (15 - i) << 7;
  const int nA = 2 * i + 2, nB = 32 - 2 * i;

  const int tid = threadIdx.x, wave = tid >> 6, lane = tid & 63;
  const int g = lane >> 4, r16 = lane & 15;

  const size_t base = (size_t)b * T_ * 3072 + h * 64;
  const u16* Qp = qkv + base;
  const u16* Kp = qkv + base + 1024;
  const u16* VtP = Vt + (size_t)(b * 16 + h) * 64 * T_;

  const int rowL = lane >> 3;
  const int colL = 8 * ((lane & 7) ^ rowL);
  const u16* kSrc = Kp  + (size_t)(wave * 16 + rowL) * 3072 + colL;
  const u16* vSrc = VtP + (size_t)(wave * 16 + rowL) * T_   + colL;
  u16* kDst0 = &sK[0][(wave * 16 + 0) * 64];
  u16* kDst8 = &sK[0][(wave * 16 + 8) * 64];
  u16* vDst0 = &sV[0][(wave * 16 + 0) * 64];
  u16* vDst8 = &sV[0][(wave * 16 + 8) * 64];

  const int ck0 = (( 0 + g * 16) ^ ((r16 & 7) << 4)) >> 1;
  const int ck1 = ((64 + g * 16) ^ ((r16 & 7) << 4)) >> 1;

  bf16x8 qfA[2][2], qfB[2][2];      // [qp][kc]
  #pragma unroll
  for (int qp = 0; qp < 2; ++qp)
    #pragma unroll
    for (int kc = 0; kc < 2; ++kc) {
      qfA[qp][kc] = *(const bf16x8*)(Qp + (size_t)(qA + wave * 32 + qp * 16 + r16) * 3072 + kc * 32 + g * 8);
      qfB[qp][kc] = *(const bf16x8*)(Qp + (size_t)(qB + wave * 32 + qp * 16 + r16) * 3072 + kc * 32 + g * 8);
    }

  f32x4 accA[2][4] = {}, accB[2][4] = {};   // [qp][hsb]
  f32x4 lA[2] = {}, lB[2] = {};
  int qaA[2], qaB[2];
  #pragma unroll
  for (int qp = 0; qp < 2; ++qp) {
    qaA[qp] = qA + wave * 32 + qp * 16 + r16;
    qaB[qp] = qB + wave * 32 + qp * 16 + r16;
  }

  const u32 one2 = 0x3F803F80u;      // bf16 1.0 pair
  const u32x4 onesv = {one2, one2, one2, one2};
  const bf16x8 ONES = __builtin_bit_cast(bf16x8, onesv);

  int sbuf = 0;
  auto stageAdv = [&]() {
    const int o = sbuf * 4096;
    GLD_LDS16(kSrc,            kDst0 + o);
    GLD_LDS16(kSrc + 8 * 3072, kDst8 + o);
    GLD_LDS16(vSrc,            vDst0 + o);
    GLD_LDS16(vSrc + 8 * T_,   vDst8 + o);
    kSrc += 64 * 3072;
    vSrc += 64;
    sbuf ^= 1;
  };

  auto qkt = [&](const bf16x8* kf0, const bf16x8* kf1, const bf16x8* qf, f32x4* s) {
    __builtin_amdgcn_s_setprio(1);
    #pragma unroll
    for (int ni = 0; ni < 4; ++ni) {
      f32x4 t = {};
      t = __builtin_amdgcn_mfma_f32_16x16x32_bf16(kf0[ni], qf[0], t, 0, 0, 0);
      t = __builtin_amdgcn_mfma_f32_16x16x32_bf16(kf1[ni], qf[1], t, 0, 0, 0);
      s[ni] = t;
    }
    __builtin_amdgcn_s_setprio(0);
  };

  auto softmax_pack = [&](f32x4* s, bool diag, int q_abs, int kv0, bf16x8* pa) {
    if (diag) {
      #pragma unroll
      for (int ni = 0; ni < 4; ++ni)
        #pragma unroll
        for (int r = 0; r < 4; ++r) {
          const int kv_abs = kv0 + ni * 16 + g * 4 + r;
          if (kv_abs > q_abs) s[ni][r] = -3e38f;
        }
    }
    #pragma unroll
    for (int ni = 0; ni < 4; ++ni)
      #pragma unroll
      for (int r = 0; r < 4; ++r)
        s[ni][r] = fast_exp2(s[ni][r]);

    u32 pk[4][2];
    #pragma unroll
    for (int ni = 0; ni < 4; ++ni)
      #pragma unroll
      for (int h2 = 0; h2 < 2; ++h2)
        asm("v_cvt_pk_bf16_f32 %0, %1, %2"
            : "=v"(pk[ni][h2]) : "v"(s[ni][2 * h2]), "v"(s[ni][2 * h2 + 1]));

    u32 pa32[2][4];
    #pragma unroll
    for (int kc = 0; kc < 2; ++kc)
      #pragma unroll
      for (int h2 = 0; h2 < 2; ++h2) {
        u32 a = pk[2 * kc][h2], bq_ = pk[2 * kc + 1][h2];
        asm("v_permlane32_swap_b32 %0, %1" : "+v"(a), "+v"(bq_));
        asm("v_permlane16_swap_b32 %0, %1" : "+v"(a), "+v"(bq_));
        pa32[kc][h2] = a;
        pa32[kc][2 + h2] = bq_;
      }
    #pragma unroll
    for (int kc = 0; kc < 2; ++kc) {
      u32x4 tmp = {pa32[kc][0], pa32[kc][1], pa32[kc][2], pa32[kc][3]};
      pa[kc] = __builtin_bit_cast(bf16x8, tmp);
    }
  };

  // prologue: tile 0 only (2-deep ring, prefetch distance 1)
  stageAdv();
  asm volatile("s_waitcnt vmcnt(0)" ::: "memory");
  __builtin_amdgcn_s_barrier();
  __builtin_amdgcn_sched_barrier(0);

  int cbuf = 0;
  for (int t = 0; t < nB; ++t) {
    if (t + 1 < nB) stageAdv();
    const u16* Kb = sK[cbuf];
    const u16* Vb = sV[cbuf];
    const int kv0 = t << 6;
    const bool actA = (t < nA);
    const bool mB = (t + 2 >= nB);
    const bool mA = (t + 2 >= nA);

    bf16x8 kf0[4], kf1[4], vf0[4], vf1[4];
    #pragma unroll
    for (int ni = 0; ni < 4; ++ni) {
      kf0[ni] = *(const bf16x8*)&Kb[(ni * 16 + r16) * 64 + ck0];
      kf1[ni] = *(const bf16x8*)&Kb[(ni * 16 + r16) * 64 + ck1];
      vf0[ni] = *(const bf16x8*)&Vb[(ni * 16 + r16) * 64 + ck0];
      vf1[ni] = *(const bf16x8*)&Vb[(ni * 16 + r16) * 64 + ck1];
    }

    #pragma unroll
    for (int qp = 0; qp < 2; ++qp) {
      f32x4 s[4];
      bf16x8 pa[2];
      qkt(kf0, kf1, qfB[qp], s);
      softmax_pack(s, mB, qaB[qp], kv0, pa);
      __builtin_amdgcn_s_setprio(1);
      lB[qp] = __builtin_amdgcn_mfma_f32_16x16x32_bf16(pa[0], ONES, lB[qp], 0, 0, 0);
      lB[qp] = __builtin_amdgcn_mfma_f32_16x16x32_bf16(pa[1], ONES, lB[qp], 0, 0, 0);
      #pragma unroll
      for (int hsb = 0; hsb < 4; ++hsb) {
        accB[qp][hsb] = __builtin_amdgcn_mfma_f32_16x16x32_bf16(pa[0], vf0[hsb], accB[qp][hsb], 0, 0, 0);
        accB[qp][hsb] = __builtin_amdgcn_mfma_f32_16x16x32_bf16(pa[1], vf1[hsb], accB[qp][hsb], 0, 0, 0);
      }
      __builtin_amdgcn_s_setprio(0);
    }

    if (actA) {
      #pragma unroll
      for (int qp = 0; qp < 2; ++qp) {
        f32x4 s[4];
        bf16x8 pa[2];
        qkt(kf0, kf1, qfA[qp], s);
        softmax_pack(s, mA, qaA[qp], kv0, pa);
        __builtin_amdgcn_s_setprio(1);
        lA[qp] = __builtin_amdgcn_mfma_f32_16x16x32_bf16(pa[0], ONES, lA[qp], 0, 0, 0);
        lA[qp] = __builtin_amdgcn_mfma_f32_16x16x32_bf16(pa[1], ONES, lA[qp], 0, 0, 0);
        #pragma unroll
        for (int hsb = 0; hsb < 4; ++hsb) {
          accA[qp][hsb] = __builtin_amdgcn_mfma_f32_16x16x32_bf16(pa[0], vf0[hsb], accA[qp][hsb], 0, 0, 0);
          accA[qp][hsb] = __builtin_amdgcn_mfma_f32_16x16x32_bf16(pa[1], vf1[hsb], accA[qp][hsb], 0, 0, 0);
        }
        __builtin_amdgcn_s_setprio(0);
      }
    }

    if (t + 1 < nB) {
      asm volatile("s_waitcnt vmcnt(0)" ::: "memory");
      __builtin_amdgcn_s_barrier();
      __builtin_amdgcn_sched_barrier(0);
    }
    cbuf ^= 1;
  }

  #pragma unroll
  for (int qp = 0; qp < 2; ++qp) {
    float rlA[4], rlB[4];
    #pragma unroll
    for (int r = 0; r < 4; ++r) {
      rlA[r] = fast_rcp(lA[qp][r]);
      rlB[r] = fast_rcp(lB[qp][r]);
    }
    #pragma unroll
    for (int hsb = 0; hsb < 4; ++hsb)
      #pragma unroll
      for (int r = 0; r < 4; ++r) {
        const size_t rowA = (size_t)b * T_ + qA + wave * 32 + qp * 16 + g * 4 + r;
        const size_t rowB = (size_t)b * T_ + qB + wave * 32 + qp * 16 + g * 4 + r;
        O[rowA * C_ + h * 64 + hsb * 16 + r16] = f2bf(accA[qp][hsb][r] * rlA[r]);
        O[rowB * C_ + h * 64 + hsb * 16 + r16] = f2bf(accB[qp][hsb][r] * rlB[r]);
      }
  }
}

// ---------------------------------------------------------------------------
extern "C" void kernel_launch(void* const* d_in, const int* in_sizes, int n_in,
                              void* d_out, int out_size, void* d_ws, size_t ws_size,
                              hipStream_t stream) {
  const float* x    = (const float*)d_in[0];
  const float* ln1g = (const float*)d_in[1];
  const float* ln1b = (const float*)d_in[2];
  const float* ln2g = (const float*)d_in[3];
  const float* ln2b = (const float*)d_in[4];
  const float* Wq   = (const float*)d_in[5];
  const float* bq   = (const float*)d_in[6];
  const float* Wk   = (const float*)d_in[7];
  const float* bk   = (const float*)d_in[8];
  const float* Wv   = (const float*)d_in[9];
  const float* bv   = (const float*)d_in[10];
  const float* Wo   = (const float*)d_in[11];
  const float* bo   = (const float*)d_in[12];
  const float* W1   = (const float*)d_in[13];
  const float* b1   = (const float*)d_in[14];
  const float* W2   = (const float*)d_in[15];
  const float* b2   = (const float*)d_in[16];

  char* w = (char*)d_ws;
  float* ps    = (float*)(w + 0);
  float* psq   = (float*)(w + 262144);
  float* mean  = (float*)(w + 524288);
  float* rstd  = (float*)(w + 540672);
  float* bqkv  = (float*)(w + 557056);
  u16*   h     = (u16*)  (w + 573440);          // 16 MB (dead after FFN1)
  u16*   wqkvT = (u16*)  (w + 17350656);        // 6 MB
  u16*   woT   = (u16*)  (w + 23642112);        // 2 MB
  u16*   w1T   = (u16*)  (w + 25739264);        // 8 MB
  u16*   w2T   = (u16*)  (w + 34127872);        // 8 MB
  u16*   x1b   = (u16*)  (w + 42516480);        // 16 MB bf16 residual stream
  u16*   Vt    = (u16*)  (w + 59293696);        // 16 MB
  u16*   qkv   = (u16*)  (w + 76070912);        // 48 MB
  u16*   Oo    = (u16*)  (w + 126402560);       // 16 MB
  u16*   u     = qkv;                           // alias
  u16*   pA    = (u16*)  (w + 573440);          // 16 MB bf16 FFN2 partial (over dead h)

  // fused weight pack + bias concat + LN1 partial (was 8 launches)
  pack_all<<<12556, 256, 0, stream>>>(Wq, Wk, Wv, Wo, W1, W2, bq, bk, bv, x,
                                      wqkvT, woT, w1T, w2T, bqkv, ps, psq);

  // LN1 finish -> h (bf16)
  ln_final<<<16, 256, 0, stream>>>(ps, psq, mean, rstd);
  ln_norm<<<8192, 256, 0, stream>>>(x, mean, rstd, ln1g, ln1b, h);

  // QKV projection (Q cols pre-scaled): BN=192 -> 1024 blocks, 2 clean rounds
  gemm_128t<192, 0, 1><<<1024, 256, 0, stream>>>(h, wqkvT, bqkv, qkv, BT_, 3072, 1024);

  // V transpose for attention
  v_transpose<<<dim3(T_ / 32, 2, B_ * H_), 256, 0, stream>>>(qkv, Vt);

  // attention v10: 512 blocks, 128-row mirror-paired strips, 32 rows/wave
  attn_fwd<<<512, 256, 0, stream>>>(qkv, Vt, Oo);

  // output projection + residual -> x1b (bf16): 512 blocks
  gemm_pipe<128, 128, 256, 0, 0, 1><<<512, 256, 0, stream>>>(Oo, woT, bo, x, x1b, BT_, 1024, 1024);

  // LN2 -> h (from bf16 residual stream)
  ln_partial_bf<<<dim3(16, 16), 256, 0, stream>>>(x1b, ps, psq);
  ln_final<<<16, 256, 0, stream>>>(ps, psq, mean, rstd);
  ln_norm_bf<<<8192, 256, 0, stream>>>(x1b, mean, rstd, ln2g, ln2b, h);

  // FFN1 (M=8192, N=4096): 256x256 unphased counted ring, 512 blocks
  // (r3-ledger inference: gemm_256 per-CU rate ~6-8% better than gemm_128t)
  gemm_256<1, 0, 0><<<512, 512, 0, stream>>>(h, w1T, b1, nullptr, u, nullptr, BT_, 4096, 1024);
  // FFN2 split-K=2: y=0 -> pA (bf16 raw), y=1 -> d_out (acc + b2 + x1b, f32)
  gemm_256<0, 1, 0><<<dim3(128, 2), 512, 0, stream>>>(u, w2T, b2, x1b, pA, d_out, BT_, 1024, 4096);
  // reduce: d_out += pA (bf16)
  ffn2_reduce<<<8192, 256, 0, stream>>>(pA, (float*)d_out);
}